// Round 8
// baseline (199.181 us; speedup 1.0000x reference)
//
#include <hip/hip_runtime.h>
#include <stdint.h>

// ONNX NonMaxSuppression: B=8, N=16384, C=80, MAX_OUT=50
// Split-phase pipeline (per-dispatch rocprof rows = phase timing):
//   memset  : zero cnt/total (+flags) in d_ws
//   nms_scan: 4 blocks per (b,c) stream scores; candidates >= OPT_THR push
//             unique keys (score<<32|invidx<<18) to ws via global atomics;
//             per-lane total count accumulated. Unique keys => final sorted
//             order deterministic despite nondeterministic atomic order.
//   nms_sortwalk: 1 block per (b,c): load keys, pad, bitonic sort (desc),
//             gather boxes BY RANK into LDS SoA, wave-0 walk with replicated
//             alive bitmask + register IoU + __ballot (r6-proven).
//   nms_slow: gated exact fallback (overflow / exhaustion-with-remainder).
// Fallbacks when ws is small: monolithic r6 fast kernel (ws >= 2560B) or
// slow-for-all (flags == nullptr).

#define NMS_B 8
#define NMS_N 16384
#define NMS_C 80
#define NMS_MAX_OUT 50
#define NTHREADS 256
#define NLANES (NMS_B * NMS_C)

#define OPT_THR 0.9765625f   // E[cnt]=384, sigma~19.4; FCAP=512 -> +6.6 sigma
#define FCAP 512
#define WMAX (FCAP / 64)
#define SPLIT 4              // scan blocks per (b,c)

// slow (fallback) kernel
#define NBUCK 256
#define SCAP 1024
#define T_MIN 320

typedef unsigned long long u64;
typedef unsigned int u32;

// ws layout
#define WS_FLAGS 0
#define WS_CNT   (NLANES * 4)
#define WS_TOTAL (NLANES * 8)
#define WS_KEYS  (NLANES * 12)
#define WS_NEED  ((size_t)(NLANES * 12) + (size_t)NLANES * FCAP * 8)

__device__ __forceinline__ float iou_exact(float4 A, float areaA, float4 Bx) {
    float x1 = fmaxf(A.x, Bx.x);
    float y1 = fmaxf(A.y, Bx.y);
    float x2 = fminf(A.z, Bx.z);
    float y2 = fminf(A.w, Bx.w);
    float dx = fmaxf(__fsub_rn(x2, x1), 0.0f);
    float dy = fmaxf(__fsub_rn(y2, y1), 0.0f);
    if (!(dx > 0.0f && dy > 0.0f)) return 0.0f;   // inter==0 -> iou==0 exactly
    float inter = __fmul_rn(dx, dy);
    float areaB = __fmul_rn(__fsub_rn(Bx.z, Bx.x), __fsub_rn(Bx.w, Bx.y));
    float uni   = __fsub_rn(__fadd_rn(areaA, areaB), inter);
    return __fdiv_rn(inter, fmaxf(uni, 1e-9f));
}

__device__ __forceinline__ float iou_pre(float4 A, float areaA, float4 Bx, float areaB) {
    float x1 = fmaxf(A.x, Bx.x);
    float y1 = fmaxf(A.y, Bx.y);
    float x2 = fminf(A.z, Bx.z);
    float y2 = fminf(A.w, Bx.w);
    float dx = fmaxf(__fsub_rn(x2, x1), 0.0f);
    float dy = fmaxf(__fsub_rn(y2, y1), 0.0f);
    if (!(dx > 0.0f && dy > 0.0f)) return 0.0f;
    float inter = __fmul_rn(dx, dy);
    float uni   = __fsub_rn(__fadd_rn(areaA, areaB), inter);
    return __fdiv_rn(inter, fmaxf(uni, 1e-9f));
}

// ---------------- phase 1: parallel scan ----------------
__global__ __launch_bounds__(NTHREADS) void nms_scan(
    const float* __restrict__ scores,
    const float* __restrict__ p_sthr,
    int* __restrict__ cnt,
    int* __restrict__ total,
    u64* __restrict__ keys)
{
    __shared__ int s_tot;
    const int bid  = blockIdx.x;
    const int bc   = bid / SPLIT;
    const int part = bid % SPLIT;
    const int tid  = threadIdx.x;
    if (tid == 0) s_tot = 0;
    __syncthreads();

    const float sthr = p_sthr[0];
    const int   n0   = part * (NMS_N / SPLIT);
    const float4* sc4 = (const float4*)(scores + (size_t)bc * NMS_N + n0);
    u64* kbase = keys + (size_t)bc * FCAP;

    float4 av[4];
    #pragma unroll
    for (int u = 0; u < 4; ++u) av[u] = sc4[u * NTHREADS + tid];

    int lt = 0;
    #pragma unroll
    for (int u = 0; u < 4; ++u) {
        const int i = u * NTHREADS + tid;
        float ss[4] = {av[u].x, av[u].y, av[u].z, av[u].w};
        #pragma unroll
        for (int j = 0; j < 4; ++j) {
            float s = ss[j];
            bool cand = (s > sthr);
            lt += cand ? 1 : 0;
            if (cand && s >= OPT_THR) {
                int n = n0 + i * 4 + j;
                int p = atomicAdd(&cnt[bc], 1);
                if (p < FCAP)
                    kbase[p] = ((u64)__float_as_uint(s) << 32)
                             | ((u64)(NMS_N - 1 - n) << 18);
            }
        }
    }
    atomicAdd(&s_tot, lt);
    __syncthreads();
    if (tid == 0) atomicAdd(&total[bc], s_tot);
}

// ---------------- phase 2: sort + walk ----------------
template <bool OUT64>
__global__ __launch_bounds__(NTHREADS) void nms_sortwalk(
    const float* __restrict__ boxes,
    const int* __restrict__ p_maxout,
    const float* __restrict__ p_iou,
    void* __restrict__ out_raw,
    int* __restrict__ flags,
    const int* __restrict__ cnt,
    const int* __restrict__ total,
    const u64* __restrict__ keys)
{
    __shared__ u64   skey[FCAP];
    __shared__ float sx[FCAP], sy[FCAP], sz[FCAP], sw[FCAP];

    const int tid = threadIdx.x;
    const int bc  = blockIdx.x;
    const int b   = bc / NMS_C;
    const int c   = bc % NMS_C;

    const float iou_thr = p_iou[0];
    int maxo = p_maxout[0];
    if (maxo > NMS_MAX_OUT) maxo = NMS_MAX_OUT;
    if (maxo < 0) maxo = 0;

    int*       out32 = (int*)out_raw       + (size_t)bc * NMS_MAX_OUT * 3;
    long long* out64 = (long long*)out_raw + (size_t)bc * NMS_MAX_OUT * 3;
    for (int i = tid; i < NMS_MAX_OUT * 3; i += NTHREADS) {
        if (OUT64) out64[i] = -1LL; else out32[i] = -1;
    }

    const int  cn  = cnt[bc];
    const int  m   = (cn < FCAP) ? cn : FCAP;
    const bool ovf = (cn > FCAP);
    const int  rem = total[bc] - cn;

    if (ovf) {
        if (tid == 0) flags[bc] = 1;
        return;
    }

    const u64* kbase = keys + (size_t)bc * FCAP;
    skey[tid]       = (tid < m)       ? kbase[tid]       : 0ull;
    skey[tid + 256] = (tid + 256 < m) ? kbase[tid + 256] : 0ull;
    __syncthreads();

    // bitonic sort descending (r6-proven, barrier per stage)
    for (int kk = 2; kk <= FCAP; kk <<= 1) {
        for (int jj = kk >> 1; jj > 0; jj >>= 1) {
            int i  = 2 * jj * (tid / jj) + (tid % jj);
            int p2 = i + jj;
            bool dirDesc = ((i & kk) == 0);
            u64 a = skey[i], bkey = skey[p2];
            bool swapq = dirDesc ? (a < bkey) : (a > bkey);
            if (swapq) { skey[i] = bkey; skey[p2] = a; }
            __syncthreads();
        }
    }

    // gather boxes by rank into SoA LDS
    const float4* boxes_b = (const float4*)(boxes + (size_t)b * NMS_N * 4);
    #pragma unroll
    for (int q = 0; q < 2; ++q) {
        const int r = tid + q * 256;
        const int n = NMS_N - 1 - (int)((skey[r] >> 18) & 0x3FFFull);  // pad-safe
        float4 bb = boxes_b[n];
        sx[r] = bb.x; sy[r] = bb.y; sz[r] = bb.z; sw[r] = bb.w;
    }
    __syncthreads();

    if (tid >= 64) return;                   // waves 1..3 retire
    const int lane = tid;

    // walk: alive mask replicated per lane; column boxes in registers
    float4 bxc[WMAX];
    float  areaBc[WMAX];
    #pragma unroll
    for (int w2 = 0; w2 < WMAX; ++w2) {
        const int j = w2 * 64 + lane;
        bxc[w2] = make_float4(sx[j], sy[j], sz[j], sw[j]);
        areaBc[w2] = __fmul_rn(__fsub_rn(bxc[w2].z, bxc[w2].x),
                               __fsub_rn(bxc[w2].w, bxc[w2].y));
    }

    u64 aliveW[WMAX];
    #pragma unroll
    for (int w2 = 0; w2 < WMAX; ++w2) {
        const int base = w2 * 64;
        aliveW[w2] = (m > base)
                   ? ((m - base >= 64) ? ~0ull : ((1ull << (m - base)) - 1ull))
                   : 0ull;
    }

    int need_slow = 0;
    for (int t = 0; t < maxo; ++t) {
        int w = WMAX; u64 cw = 0ull;
        #pragma unroll
        for (int q = WMAX - 1; q >= 0; --q)
            if (aliveW[q] != 0ull) { w = q; cw = aliveW[q]; }
        if (w == WMAX) {
            if (rem > 0) need_slow = 1;
            break;
        }
        const int bit = __builtin_ctzll(cw);
        const int r   = w * 64 + bit;

        const u64 kr = skey[r];              // uniform -> broadcast
        const int n  = NMS_N - 1 - (int)((kr >> 18) & 0x3FFFull);
        if (lane == 0) {
            if (OUT64) {
                out64[t * 3 + 0] = (long long)b;
                out64[t * 3 + 1] = (long long)c;
                out64[t * 3 + 2] = (long long)n;
            } else {
                out32[t * 3 + 0] = b;
                out32[t * 3 + 1] = c;
                out32[t * 3 + 2] = n;
            }
        }
        const float4 A = make_float4(sx[r], sy[r], sz[r], sw[r]);  // uniform
        const float areaA = __fmul_rn(__fsub_rn(A.z, A.x), __fsub_rn(A.w, A.y));

        #pragma unroll
        for (int w2 = 0; w2 < WMAX; ++w2) {
            const bool valid = (w2 * 64 + lane) < m;
            const bool sup = valid &&
                (iou_pre(A, areaA, bxc[w2], areaBc[w2]) > iou_thr);
            u64 kill = __ballot(sup);
            if (w2 == w) kill |= (1ull << bit);   // self (zero-area safe)
            aliveW[w2] &= ~kill;
        }
    }
    if (lane == 0) flags[bc] = need_slow;
}

// ---------------- monolithic r6 fast kernel (medium-ws fallback) ----------------
template <bool OUT64>
__global__ __launch_bounds__(NTHREADS) void nms_fast_mono(
    const float* __restrict__ boxes,
    const float* __restrict__ scores,
    const int* __restrict__ p_maxout,
    const float* __restrict__ p_iou,
    const float* __restrict__ p_sthr,
    void* __restrict__ out_raw,
    int* __restrict__ flags)
{
    __shared__ u64   skey[FCAP];
    __shared__ float sx[FCAP], sy[FCAP], sz[FCAP], sw[FCAP];
    __shared__ int   s_cnt, s_total;

    const int tid = threadIdx.x;
    const int bc  = blockIdx.x;
    const int b   = bc / NMS_C;
    const int c   = bc % NMS_C;

    const float score_thr = p_sthr[0];
    const float iou_thr   = p_iou[0];
    int maxo = p_maxout[0];
    if (maxo > NMS_MAX_OUT) maxo = NMS_MAX_OUT;
    if (maxo < 0) maxo = 0;

    int*       out32 = (int*)out_raw       + (size_t)bc * NMS_MAX_OUT * 3;
    long long* out64 = (long long*)out_raw + (size_t)bc * NMS_MAX_OUT * 3;
    for (int i = tid; i < NMS_MAX_OUT * 3; i += NTHREADS) {
        if (OUT64) out64[i] = -1LL; else out32[i] = -1;
    }

    skey[tid] = 0ull;
    skey[tid + 256] = 0ull;
    if (tid == 0) { s_cnt = 0; s_total = 0; }
    __syncthreads();

    const float4* sc4     = (const float4*)(scores + ((size_t)b * NMS_C + c) * NMS_N);
    const float4* boxes_b = (const float4*)(boxes + (size_t)b * NMS_N * 4);

    float4 av[16];
    #pragma unroll
    for (int u = 0; u < 16; ++u) av[u] = sc4[u * NTHREADS + tid];

    int local_total = 0;
    #pragma unroll
    for (int u = 0; u < 16; ++u) {
        const int i = u * NTHREADS + tid;
        float ss[4] = {av[u].x, av[u].y, av[u].z, av[u].w};
        #pragma unroll
        for (int j = 0; j < 4; ++j) {
            float s = ss[j];
            bool cand = (s > score_thr);
            local_total += cand ? 1 : 0;
            if (cand && s >= OPT_THR) {
                int n = i * 4 + j;
                int p = atomicAdd(&s_cnt, 1);
                if (p < FCAP) {
                    skey[p] = ((u64)__float_as_uint(s) << 32)
                            | ((u64)(NMS_N - 1 - n) << 18);
                }
            }
        }
    }
    atomicAdd(&s_total, local_total);
    __syncthreads();

    const int  m        = (s_cnt < FCAP) ? s_cnt : FCAP;
    const bool overflow = (s_cnt > FCAP);
    const int  rem      = s_total - s_cnt;

    if (overflow) {
        if (tid == 0) flags[bc] = 1;
        return;
    }
    if (tid < 256) {
        if (tid >= m) skey[tid] = (tid < FCAP) ? skey[tid] : 0ull;
    }
    __syncthreads();

    for (int kk = 2; kk <= FCAP; kk <<= 1) {
        for (int jj = kk >> 1; jj > 0; jj >>= 1) {
            int i  = 2 * jj * (tid / jj) + (tid % jj);
            int p2 = i + jj;
            bool dirDesc = ((i & kk) == 0);
            u64 a = skey[i], bkey = skey[p2];
            bool swapq = dirDesc ? (a < bkey) : (a > bkey);
            if (swapq) { skey[i] = bkey; skey[p2] = a; }
            __syncthreads();
        }
    }

    #pragma unroll
    for (int q = 0; q < 2; ++q) {
        const int r = tid + q * 256;
        const int n = NMS_N - 1 - (int)((skey[r] >> 18) & 0x3FFFull);
        float4 bb = boxes_b[n];
        sx[r] = bb.x; sy[r] = bb.y; sz[r] = bb.z; sw[r] = bb.w;
    }
    __syncthreads();

    if (tid >= 64) return;
    const int lane = tid;

    float4 bxc[WMAX];
    float  areaBc[WMAX];
    #pragma unroll
    for (int w2 = 0; w2 < WMAX; ++w2) {
        const int j = w2 * 64 + lane;
        bxc[w2] = make_float4(sx[j], sy[j], sz[j], sw[j]);
        areaBc[w2] = __fmul_rn(__fsub_rn(bxc[w2].z, bxc[w2].x),
                               __fsub_rn(bxc[w2].w, bxc[w2].y));
    }

    u64 aliveW[WMAX];
    #pragma unroll
    for (int w2 = 0; w2 < WMAX; ++w2) {
        const int base = w2 * 64;
        aliveW[w2] = (m > base)
                   ? ((m - base >= 64) ? ~0ull : ((1ull << (m - base)) - 1ull))
                   : 0ull;
    }

    int need_slow = 0;
    for (int t = 0; t < maxo; ++t) {
        int w = WMAX; u64 cw = 0ull;
        #pragma unroll
        for (int q = WMAX - 1; q >= 0; --q)
            if (aliveW[q] != 0ull) { w = q; cw = aliveW[q]; }
        if (w == WMAX) {
            if (rem > 0) need_slow = 1;
            break;
        }
        const int bit = __builtin_ctzll(cw);
        const int r   = w * 64 + bit;
        const u64 kr = skey[r];
        const int n  = NMS_N - 1 - (int)((kr >> 18) & 0x3FFFull);
        if (lane == 0) {
            if (OUT64) {
                out64[t * 3 + 0] = (long long)b;
                out64[t * 3 + 1] = (long long)c;
                out64[t * 3 + 2] = (long long)n;
            } else {
                out32[t * 3 + 0] = b;
                out32[t * 3 + 1] = c;
                out32[t * 3 + 2] = n;
            }
        }
        const float4 A = make_float4(sx[r], sy[r], sz[r], sw[r]);
        const float areaA = __fmul_rn(__fsub_rn(A.z, A.x), __fsub_rn(A.w, A.y));
        #pragma unroll
        for (int w2 = 0; w2 < WMAX; ++w2) {
            const bool valid = (w2 * 64 + lane) < m;
            const bool sup = valid &&
                (iou_pre(A, areaA, bxc[w2], areaBc[w2]) > iou_thr);
            u64 kill = __ballot(sup);
            if (w2 == w) kill |= (1ull << bit);
            aliveW[w2] &= ~kill;
        }
    }
    if (lane == 0) flags[bc] = need_slow;
}

// ---------------- slow exact fallback (verified, flag-gated) ----------------
__device__ __forceinline__ int bucketf(float s) {
    int v = (int)__float_as_uint(s) - 0x3F000000;
    v >>= 15;
    return v < 0 ? 0 : (v > 255 ? 255 : v);
}

template <bool OUT64>
__global__ __launch_bounds__(NTHREADS) void nms_slow(
    const float* __restrict__ boxes,
    const float* __restrict__ scores,
    const int* __restrict__ p_maxout,
    const float* __restrict__ p_iou,
    const float* __restrict__ p_sthr,
    void* __restrict__ out_raw,
    const int* __restrict__ flags)
{
    __shared__ int    hist[NBUCK];
    __shared__ u64    key[SCAP];
    __shared__ float4 cbox[SCAP];
    __shared__ float4 selbox[NMS_MAX_OUT];
    __shared__ u64    s_wmax[NTHREADS / 64];
    __shared__ u64    s_best;
    __shared__ int    s_cnt, s_cutLo, s_cutHi, s_rem, s_state;

    const int tid = threadIdx.x;
    const int bc  = blockIdx.x;
    if (flags && flags[bc] == 0) return;
    const int b   = bc / NMS_C;
    const int c   = bc % NMS_C;

    const float score_thr = p_sthr[0];
    const float iou_thr   = p_iou[0];
    int maxo = p_maxout[0];
    if (maxo > NMS_MAX_OUT) maxo = NMS_MAX_OUT;
    if (maxo < 0) maxo = 0;

    int*       out32 = (int*)out_raw       + (size_t)bc * NMS_MAX_OUT * 3;
    long long* out64 = (long long*)out_raw + (size_t)bc * NMS_MAX_OUT * 3;
    for (int i = tid; i < NMS_MAX_OUT * 3; i += NTHREADS) {
        if (OUT64) out64[i] = -1LL; else out32[i] = -1;
    }

    const float*  sc      = scores + ((size_t)b * NMS_C + c) * NMS_N;
    const float4* sc4     = (const float4*)sc;
    const float4* boxes_b = (const float4*)(boxes + (size_t)b * NMS_N * 4);

    for (int i = tid; i < NBUCK; i += NTHREADS) hist[i] = 0;
    if (tid == 0) s_cnt = 0;
    __syncthreads();
    for (int i = tid; i < NMS_N / 4; i += NTHREADS) {
        float4 s4 = sc4[i];
        float ss[4] = {s4.x, s4.y, s4.z, s4.w};
        #pragma unroll
        for (int j = 0; j < 4; ++j)
            if (ss[j] > score_thr) atomicAdd(&hist[bucketf(ss[j])], 1);
    }
    __syncthreads();

    if (tid == 0) {
        int cum = 0, cut = NBUCK;
        for (int bk = NBUCK - 1; bk >= 0; --bk) {
            int h = hist[bk];
            if (cum > 0 && cum + h > SCAP) break;
            cum += h; cut = bk;
            if (cum >= T_MIN) break;
        }
        s_cutLo = cut; s_cutHi = NBUCK - 1;
        int rem = 0;
        for (int bk = 0; bk < cut; ++bk) rem += hist[bk];
        s_rem = rem;
    }
    __syncthreads();

    auto compact = [&](int lo, int hi) {
        for (int i = tid; i < NMS_N / 4; i += NTHREADS) {
            float4 s4 = sc4[i];
            float ss[4] = {s4.x, s4.y, s4.z, s4.w};
            #pragma unroll
            for (int j = 0; j < 4; ++j) {
                float s = ss[j];
                if (s > score_thr) {
                    int bk = bucketf(s);
                    if (bk >= lo && bk <= hi) {
                        int n = i * 4 + j;
                        int p = atomicAdd(&s_cnt, 1);
                        if (p < SCAP) {
                            key[p] = ((u64)__float_as_uint(s) << 24)
                                   | ((u64)(NMS_N - 1 - n) << 10)
                                   | (u64)p;
                            cbox[p] = boxes_b[n];
                        }
                    }
                }
            }
        }
    };
    compact(s_cutLo, s_cutHi);
    __syncthreads();

    int t = 0;
    while (t < maxo) {
        int m = s_cnt; if (m > SCAP) m = SCAP;
        u64 lmax = 0ull;
        for (int i = tid; i < m; i += NTHREADS) {
            u64 k = key[i];
            if (k > lmax) lmax = k;
        }
        #pragma unroll
        for (int off = 32; off > 0; off >>= 1) {
            u64 o = __shfl_down(lmax, off);
            if (o > lmax) lmax = o;
        }
        if ((tid & 63) == 0) s_wmax[tid >> 6] = lmax;
        __syncthreads();
        if (tid == 0) {
            u64 best = s_wmax[0];
            #pragma unroll
            for (int w = 1; w < NTHREADS / 64; ++w)
                if (s_wmax[w] > best) best = s_wmax[w];
            s_best = best;
            if (best) {
                int slot = (int)(best & 0x3FFull);
                int n    = NMS_N - 1 - (int)((best >> 10) & 0x3FFFull);
                key[slot] = 0ull;
                if (OUT64) {
                    out64[t * 3 + 0] = (long long)b;
                    out64[t * 3 + 1] = (long long)c;
                    out64[t * 3 + 2] = (long long)n;
                } else {
                    out32[t * 3 + 0] = b;
                    out32[t * 3 + 1] = c;
                    out32[t * 3 + 2] = n;
                }
                selbox[t] = cbox[slot];
                s_state = 0;
            } else if (s_rem == 0) {
                s_state = 2;
            } else {
                int hiB = s_cutLo - 1;
                int cum = 0, cut = hiB + 1;
                for (int bk = hiB; bk >= 0; --bk) {
                    int h = hist[bk];
                    if (cum > 0 && cum + h > SCAP) break;
                    cum += h; cut = bk;
                    if (cum >= T_MIN) break;
                }
                s_cutLo = cut; s_cutHi = hiB;
                int rem = 0;
                for (int bk = 0; bk < cut; ++bk) rem += hist[bk];
                s_rem = rem;
                s_cnt = 0;
                s_state = 1;
            }
        }
        __syncthreads();

        if (s_state == 2) break;

        if (s_state == 0) {
            const float4 A = selbox[t];
            const float areaA = __fmul_rn(__fsub_rn(A.z, A.x), __fsub_rn(A.w, A.y));
            int m0 = s_cnt; if (m0 > SCAP) m0 = SCAP;
            for (int i = tid; i < m0; i += NTHREADS) {
                u64 k = key[i];
                if (!k) continue;
                if (iou_exact(A, areaA, cbox[i]) > iou_thr) key[i] = 0ull;
            }
            __syncthreads();
            ++t;
        } else {
            compact(s_cutLo, s_cutHi);
            __syncthreads();
            int m2 = s_cnt; if (m2 > SCAP) m2 = SCAP;
            for (int i = tid; i < m2; i += NTHREADS) {
                u64 k = key[i];
                if (!k) continue;
                float4 Bx = cbox[i];
                for (int j = 0; j < t; ++j) {
                    float4 A = selbox[j];
                    float areaA = __fmul_rn(__fsub_rn(A.z, A.x), __fsub_rn(A.w, A.y));
                    if (iou_exact(A, areaA, Bx) > iou_thr) { key[i] = 0ull; break; }
                }
            }
            __syncthreads();
        }
    }
}

extern "C" void kernel_launch(void* const* d_in, const int* in_sizes, int n_in,
                              void* d_out, int out_size, void* d_ws, size_t ws_size,
                              hipStream_t stream) {
    const float* boxes  = (const float*)d_in[0];
    const float* scores = (const float*)d_in[1];
    const int*   p_maxo = (const int*)d_in[2];
    const float* p_iou  = (const float*)d_in[3];
    const float* p_sthr = (const float*)d_in[4];

    const dim3 block(NTHREADS);
    const bool out64 = (out_size == NLANES * NMS_MAX_OUT * 3 * 2);

    char* ws = (char*)d_ws;
    int*  flags = (int*)(ws + WS_FLAGS);
    int*  cnt   = (int*)(ws + WS_CNT);
    int*  total = (int*)(ws + WS_TOTAL);
    u64*  keys  = (u64*)(ws + WS_KEYS);

    if (ws_size >= WS_NEED) {
        hipMemsetAsync(ws, 0, NLANES * 12, stream);
        hipLaunchKernelGGL(nms_scan, dim3(NLANES * SPLIT), block, 0, stream,
                           scores, p_sthr, cnt, total, keys);
        if (out64) {
            hipLaunchKernelGGL(nms_sortwalk<true>, dim3(NLANES), block, 0, stream,
                               boxes, p_maxo, p_iou, d_out, flags, cnt, total, keys);
            hipLaunchKernelGGL(nms_slow<true>, dim3(NLANES), block, 0, stream,
                               boxes, scores, p_maxo, p_iou, p_sthr, d_out, flags);
        } else {
            hipLaunchKernelGGL(nms_sortwalk<false>, dim3(NLANES), block, 0, stream,
                               boxes, p_maxo, p_iou, d_out, flags, cnt, total, keys);
            hipLaunchKernelGGL(nms_slow<false>, dim3(NLANES), block, 0, stream,
                               boxes, scores, p_maxo, p_iou, p_sthr, d_out, flags);
        }
    } else if (ws_size >= (size_t)NLANES * sizeof(int)) {
        if (out64) {
            hipLaunchKernelGGL(nms_fast_mono<true>, dim3(NLANES), block, 0, stream,
                               boxes, scores, p_maxo, p_iou, p_sthr, d_out, flags);
            hipLaunchKernelGGL(nms_slow<true>, dim3(NLANES), block, 0, stream,
                               boxes, scores, p_maxo, p_iou, p_sthr, d_out, flags);
        } else {
            hipLaunchKernelGGL(nms_fast_mono<false>, dim3(NLANES), block, 0, stream,
                               boxes, scores, p_maxo, p_iou, p_sthr, d_out, flags);
            hipLaunchKernelGGL(nms_slow<false>, dim3(NLANES), block, 0, stream,
                               boxes, scores, p_maxo, p_iou, p_sthr, d_out, flags);
        }
    } else {
        if (out64) {
            hipLaunchKernelGGL(nms_slow<true>, dim3(NLANES), block, 0, stream,
                               boxes, scores, p_maxo, p_iou, p_sthr, d_out, (const int*)nullptr);
        } else {
            hipLaunchKernelGGL(nms_slow<false>, dim3(NLANES), block, 0, stream,
                               boxes, scores, p_maxo, p_iou, p_sthr, d_out, (const int*)nullptr);
        }
    }
}

// Round 9
// 109.497 us; speedup vs baseline: 1.8191x; 1.8191x over previous
//
#include <hip/hip_runtime.h>
#include <stdint.h>

// ONNX NonMaxSuppression: B=8, N=16384, C=80, MAX_OUT=50
// Monolithic fast kernel, one block (256 thr) per (b,c):
//   phase A: streaming score scan (16x float4 preload); candidates above a
//            fixed optimistic cutoff push unique keys (score<<32|invidx<<18)
//            into LDS via LDS atomics.
//   phase B: O(n^2) counting-rank sort: each thread owns 2 keys, streams all
//            512 keys via broadcast ulonglong2 LDS reads, rank = #greater;
//            scatter to ssort[rank]. Barrier-free compare phase (replaces the
//            45-barrier bitonic that owned ~700K bank conflicts).
//   phase C: gather boxes by rank into LDS SoA.
//   phase D: wave-0 sorted walk: alive bitmask replicated per lane, column
//            boxes in registers, per-round register IoU + __ballot; loop
//            restricted to wave-uniform [w, Wlim) word range.
// Exactness: overflow or exhaustion-with-remainder flags the lane in d_ws;
// gated nms_slow (verified adaptive 2-pass kernel) re-solves those lanes.

#define NMS_B 8
#define NMS_N 16384
#define NMS_C 80
#define NMS_MAX_OUT 50
#define NTHREADS 256
#define NLANES (NMS_B * NMS_C)

#define OPT_THR 0.9765625f   // E[cnt]=384, sigma~19.4; FCAP=512 -> +6.6 sigma
#define FCAP 512
#define WMAX (FCAP / 64)

// slow (fallback) kernel
#define NBUCK 256
#define SCAP 1024
#define T_MIN 320

typedef unsigned long long u64;

__device__ __forceinline__ float iou_exact(float4 A, float areaA, float4 Bx) {
    float x1 = fmaxf(A.x, Bx.x);
    float y1 = fmaxf(A.y, Bx.y);
    float x2 = fminf(A.z, Bx.z);
    float y2 = fminf(A.w, Bx.w);
    float dx = fmaxf(__fsub_rn(x2, x1), 0.0f);
    float dy = fmaxf(__fsub_rn(y2, y1), 0.0f);
    if (!(dx > 0.0f && dy > 0.0f)) return 0.0f;   // inter==0 -> iou==0 exactly
    float inter = __fmul_rn(dx, dy);
    float areaB = __fmul_rn(__fsub_rn(Bx.z, Bx.x), __fsub_rn(Bx.w, Bx.y));
    float uni   = __fsub_rn(__fadd_rn(areaA, areaB), inter);
    return __fdiv_rn(inter, fmaxf(uni, 1e-9f));
}

__device__ __forceinline__ float iou_pre(float4 A, float areaA, float4 Bx, float areaB) {
    float x1 = fmaxf(A.x, Bx.x);
    float y1 = fmaxf(A.y, Bx.y);
    float x2 = fminf(A.z, Bx.z);
    float y2 = fminf(A.w, Bx.w);
    float dx = fmaxf(__fsub_rn(x2, x1), 0.0f);
    float dy = fmaxf(__fsub_rn(y2, y1), 0.0f);
    if (!(dx > 0.0f && dy > 0.0f)) return 0.0f;
    float inter = __fmul_rn(dx, dy);
    float uni   = __fsub_rn(__fadd_rn(areaA, areaB), inter);
    return __fdiv_rn(inter, fmaxf(uni, 1e-9f));
}

template <bool OUT64>
__global__ __launch_bounds__(NTHREADS) void nms_fast(
    const float* __restrict__ boxes,
    const float* __restrict__ scores,
    const int* __restrict__ p_maxout,
    const float* __restrict__ p_iou,
    const float* __restrict__ p_sthr,
    void* __restrict__ out_raw,
    int* __restrict__ flags)
{
    __shared__ __align__(16) u64 skey[FCAP];   // unsorted compaction
    __shared__ __align__(16) u64 ssort[FCAP];  // rank-sorted keys
    __shared__ float sx[FCAP], sy[FCAP], sz[FCAP], sw[FCAP];
    __shared__ int   s_cnt, s_total;

    const int tid = threadIdx.x;
    const int bc  = blockIdx.x;
    const int b   = bc / NMS_C;
    const int c   = bc % NMS_C;

    const float score_thr = p_sthr[0];
    const float iou_thr   = p_iou[0];
    int maxo = p_maxout[0];
    if (maxo > NMS_MAX_OUT) maxo = NMS_MAX_OUT;
    if (maxo < 0) maxo = 0;

    int*       out32 = (int*)out_raw       + (size_t)bc * NMS_MAX_OUT * 3;
    long long* out64 = (long long*)out_raw + (size_t)bc * NMS_MAX_OUT * 3;
    for (int i = tid; i < NMS_MAX_OUT * 3; i += NTHREADS) {
        if (OUT64) out64[i] = -1LL; else out32[i] = -1;
    }

    skey[tid] = 0ull;  skey[tid + 256] = 0ull;
    ssort[tid] = 0ull; ssort[tid + 256] = 0ull;
    if (tid == 0) { s_cnt = 0; s_total = 0; }
    __syncthreads();

    const float4* sc4     = (const float4*)(scores + ((size_t)b * NMS_C + c) * NMS_N);
    const float4* boxes_b = (const float4*)(boxes + (size_t)b * NMS_N * 4);

    // ---- phase A: streaming score scan ----
    float4 av[16];
    #pragma unroll
    for (int u = 0; u < 16; ++u) av[u] = sc4[u * NTHREADS + tid];

    int local_total = 0;
    #pragma unroll
    for (int u = 0; u < 16; ++u) {
        const int i = u * NTHREADS + tid;
        float ss[4] = {av[u].x, av[u].y, av[u].z, av[u].w};
        #pragma unroll
        for (int j = 0; j < 4; ++j) {
            float s = ss[j];
            bool cand = (s > score_thr);
            local_total += cand ? 1 : 0;
            if (cand && s >= OPT_THR) {          // rare (~2.3%)
                int n = i * 4 + j;
                int p = atomicAdd(&s_cnt, 1);
                if (p < FCAP) {
                    skey[p] = ((u64)__float_as_uint(s) << 32)
                            | ((u64)(NMS_N - 1 - n) << 18);
                }
            }
        }
    }
    atomicAdd(&s_total, local_total);
    __syncthreads();

    const int  m        = (s_cnt < FCAP) ? s_cnt : FCAP;
    const bool overflow = (s_cnt > FCAP);
    const int  rem      = s_total - s_cnt;   // candidates below optimistic cut

    if (overflow) {                          // uniform block-wide bail
        if (tid == 0) flags[bc] = 1;
        return;
    }

    // ---- phase B: counting-rank sort (descending) ----
    // Keys unique (distinct invidx) => rank = #{greater keys} is a bijection
    // onto 0..m-1. Pads are 0 (never greater, never scattered).
    {
        const u64 k0 = skey[tid], k1 = skey[tid + 256];
        int r0 = 0, r1 = 0;
        const ulonglong2* sk2 = (const ulonglong2*)skey;
        #pragma unroll 4
        for (int i = 0; i < FCAP / 2; ++i) {
            ulonglong2 kv = sk2[i];             // uniform addr -> broadcast
            r0 += (kv.x > k0) ? 1 : 0;
            r0 += (kv.y > k0) ? 1 : 0;
            r1 += (kv.x > k1) ? 1 : 0;
            r1 += (kv.y > k1) ? 1 : 0;
        }
        if (k0) ssort[r0] = k0;                 // writes to ssort, reads skey:
        if (k1) ssort[r1] = k1;                 // no barrier needed before
        __syncthreads();
    }

    // ---- phase C: gather boxes by rank into SoA LDS ----
    #pragma unroll
    for (int q = 0; q < 2; ++q) {
        const int r = tid + q * 256;
        const int n = NMS_N - 1 - (int)((ssort[r] >> 18) & 0x3FFFull);  // pad-safe
        float4 bb = boxes_b[n];
        sx[r] = bb.x; sy[r] = bb.y; sz[r] = bb.z; sw[r] = bb.w;
    }
    __syncthreads();

    if (tid >= 64) return;                   // waves 1..3 retire
    const int lane = tid;

    // ---- phase D: sorted walk ----
    float4 bxc[WMAX];
    float  areaBc[WMAX];
    #pragma unroll
    for (int w2 = 0; w2 < WMAX; ++w2) {
        const int j = w2 * 64 + lane;
        bxc[w2] = make_float4(sx[j], sy[j], sz[j], sw[j]);
        areaBc[w2] = __fmul_rn(__fsub_rn(bxc[w2].z, bxc[w2].x),
                               __fsub_rn(bxc[w2].w, bxc[w2].y));
    }

    u64 aliveW[WMAX];
    #pragma unroll
    for (int w2 = 0; w2 < WMAX; ++w2) {
        const int base = w2 * 64;
        aliveW[w2] = (m > base)
                   ? ((m - base >= 64) ? ~0ull : ((1ull << (m - base)) - 1ull))
                   : 0ull;
    }
    const int Wlim = (m + 63) >> 6;          // wave-uniform
    int wstart = 0, need_slow = 0;

    for (int t = 0; t < maxo; ++t) {
        // find lowest alive rank (lane-local; aliveW replicated => uniform)
        int w = -1; u64 cw = 0ull;
        #pragma unroll
        for (int q = 0; q < WMAX; ++q)
            if (q < Wlim && q >= wstart && w < 0 && aliveW[q] != 0ull) {
                w = q; cw = aliveW[q];
            }
        if (w < 0) {                         // exhausted
            if (rem > 0) need_slow = 1;
            break;
        }
        wstart = w;
        const int bit = __builtin_ctzll(cw);
        const int r   = w * 64 + bit;

        const u64 kr = ssort[r];             // uniform -> broadcast
        const int n  = NMS_N - 1 - (int)((kr >> 18) & 0x3FFFull);
        if (lane == 0) {
            if (OUT64) {
                out64[t * 3 + 0] = (long long)b;
                out64[t * 3 + 1] = (long long)c;
                out64[t * 3 + 2] = (long long)n;
            } else {
                out32[t * 3 + 0] = b;
                out32[t * 3 + 1] = c;
                out32[t * 3 + 2] = n;
            }
        }
        const float4 A = make_float4(sx[r], sy[r], sz[r], sw[r]);  // uniform
        const float areaA  = __fmul_rn(__fsub_rn(A.z, A.x), __fsub_rn(A.w, A.y));
        const u64   himask = (bit == 63) ? 0ull : (~0ull << (bit + 1));

        // suppression: only words [w, Wlim) matter (lower words never revisited);
        // dead lanes' garbage IoU is harmless (their alive bits are already 0).
        #pragma unroll
        for (int w2 = 0; w2 < WMAX; ++w2) {
            if (w2 >= w && w2 < Wlim) {      // wave-uniform guards
                const bool sup = iou_pre(A, areaA, bxc[w2], areaBc[w2]) > iou_thr;
                const u64 kill = __ballot(sup);
                if (w2 == w) aliveW[w2] = (aliveW[w2] & himask) & ~kill;
                else         aliveW[w2] &= ~kill;
            }
        }
    }
    if (lane == 0) flags[bc] = need_slow;
}

// ---- slow exact fallback (verified round-2 structure, flag-gated) ----
__device__ __forceinline__ int bucketf(float s) {
    int v = (int)__float_as_uint(s) - 0x3F000000;
    v >>= 15;
    return v < 0 ? 0 : (v > 255 ? 255 : v);
}

template <bool OUT64>
__global__ __launch_bounds__(NTHREADS) void nms_slow(
    const float* __restrict__ boxes,
    const float* __restrict__ scores,
    const int* __restrict__ p_maxout,
    const float* __restrict__ p_iou,
    const float* __restrict__ p_sthr,
    void* __restrict__ out_raw,
    const int* __restrict__ flags)
{
    __shared__ int    hist[NBUCK];
    __shared__ u64    key[SCAP];
    __shared__ float4 cbox[SCAP];
    __shared__ float4 selbox[NMS_MAX_OUT];
    __shared__ u64    s_wmax[NTHREADS / 64];
    __shared__ u64    s_best;
    __shared__ int    s_cnt, s_cutLo, s_cutHi, s_rem, s_state;

    const int tid = threadIdx.x;
    const int bc  = blockIdx.x;
    if (flags && flags[bc] == 0) return;     // uniform exit before any barrier
    const int b   = bc / NMS_C;
    const int c   = bc % NMS_C;

    const float score_thr = p_sthr[0];
    const float iou_thr   = p_iou[0];
    int maxo = p_maxout[0];
    if (maxo > NMS_MAX_OUT) maxo = NMS_MAX_OUT;
    if (maxo < 0) maxo = 0;

    int*       out32 = (int*)out_raw       + (size_t)bc * NMS_MAX_OUT * 3;
    long long* out64 = (long long*)out_raw + (size_t)bc * NMS_MAX_OUT * 3;
    for (int i = tid; i < NMS_MAX_OUT * 3; i += NTHREADS) {
        if (OUT64) out64[i] = -1LL; else out32[i] = -1;
    }

    const float*  sc      = scores + ((size_t)b * NMS_C + c) * NMS_N;
    const float4* sc4     = (const float4*)sc;
    const float4* boxes_b = (const float4*)(boxes + (size_t)b * NMS_N * 4);

    for (int i = tid; i < NBUCK; i += NTHREADS) hist[i] = 0;
    if (tid == 0) s_cnt = 0;
    __syncthreads();
    for (int i = tid; i < NMS_N / 4; i += NTHREADS) {
        float4 s4 = sc4[i];
        float ss[4] = {s4.x, s4.y, s4.z, s4.w};
        #pragma unroll
        for (int j = 0; j < 4; ++j)
            if (ss[j] > score_thr) atomicAdd(&hist[bucketf(ss[j])], 1);
    }
    __syncthreads();

    if (tid == 0) {
        int cum = 0, cut = NBUCK;
        for (int bk = NBUCK - 1; bk >= 0; --bk) {
            int h = hist[bk];
            if (cum > 0 && cum + h > SCAP) break;
            cum += h; cut = bk;
            if (cum >= T_MIN) break;
        }
        s_cutLo = cut; s_cutHi = NBUCK - 1;
        int rem = 0;
        for (int bk = 0; bk < cut; ++bk) rem += hist[bk];
        s_rem = rem;
    }
    __syncthreads();

    auto compact = [&](int lo, int hi) {
        for (int i = tid; i < NMS_N / 4; i += NTHREADS) {
            float4 s4 = sc4[i];
            float ss[4] = {s4.x, s4.y, s4.z, s4.w};
            #pragma unroll
            for (int j = 0; j < 4; ++j) {
                float s = ss[j];
                if (s > score_thr) {
                    int bk = bucketf(s);
                    if (bk >= lo && bk <= hi) {
                        int n = i * 4 + j;
                        int p = atomicAdd(&s_cnt, 1);
                        if (p < SCAP) {
                            key[p] = ((u64)__float_as_uint(s) << 24)
                                   | ((u64)(NMS_N - 1 - n) << 10)
                                   | (u64)p;
                            cbox[p] = boxes_b[n];
                        }
                    }
                }
            }
        }
    };
    compact(s_cutLo, s_cutHi);
    __syncthreads();

    int t = 0;
    while (t < maxo) {
        int m = s_cnt; if (m > SCAP) m = SCAP;
        u64 lmax = 0ull;
        for (int i = tid; i < m; i += NTHREADS) {
            u64 k = key[i];
            if (k > lmax) lmax = k;
        }
        #pragma unroll
        for (int off = 32; off > 0; off >>= 1) {
            u64 o = __shfl_down(lmax, off);
            if (o > lmax) lmax = o;
        }
        if ((tid & 63) == 0) s_wmax[tid >> 6] = lmax;
        __syncthreads();
        if (tid == 0) {
            u64 best = s_wmax[0];
            #pragma unroll
            for (int w = 1; w < NTHREADS / 64; ++w)
                if (s_wmax[w] > best) best = s_wmax[w];
            s_best = best;
            if (best) {
                int slot = (int)(best & 0x3FFull);
                int n    = NMS_N - 1 - (int)((best >> 10) & 0x3FFFull);
                key[slot] = 0ull;
                if (OUT64) {
                    out64[t * 3 + 0] = (long long)b;
                    out64[t * 3 + 1] = (long long)c;
                    out64[t * 3 + 2] = (long long)n;
                } else {
                    out32[t * 3 + 0] = b;
                    out32[t * 3 + 1] = c;
                    out32[t * 3 + 2] = n;
                }
                selbox[t] = cbox[slot];
                s_state = 0;
            } else if (s_rem == 0) {
                s_state = 2;
            } else {
                int hiB = s_cutLo - 1;
                int cum = 0, cut = hiB + 1;
                for (int bk = hiB; bk >= 0; --bk) {
                    int h = hist[bk];
                    if (cum > 0 && cum + h > SCAP) break;
                    cum += h; cut = bk;
                    if (cum >= T_MIN) break;
                }
                s_cutLo = cut; s_cutHi = hiB;
                int rem = 0;
                for (int bk = 0; bk < cut; ++bk) rem += hist[bk];
                s_rem = rem;
                s_cnt = 0;
                s_state = 1;
            }
        }
        __syncthreads();

        if (s_state == 2) break;

        if (s_state == 0) {
            const float4 A = selbox[t];
            const float areaA = __fmul_rn(__fsub_rn(A.z, A.x), __fsub_rn(A.w, A.y));
            int m0 = s_cnt; if (m0 > SCAP) m0 = SCAP;
            for (int i = tid; i < m0; i += NTHREADS) {
                u64 k = key[i];
                if (!k) continue;
                if (iou_exact(A, areaA, cbox[i]) > iou_thr) key[i] = 0ull;
            }
            __syncthreads();
            ++t;
        } else {
            compact(s_cutLo, s_cutHi);
            __syncthreads();
            int m2 = s_cnt; if (m2 > SCAP) m2 = SCAP;
            for (int i = tid; i < m2; i += NTHREADS) {
                u64 k = key[i];
                if (!k) continue;
                float4 Bx = cbox[i];
                for (int j = 0; j < t; ++j) {
                    float4 A = selbox[j];
                    float areaA = __fmul_rn(__fsub_rn(A.z, A.x), __fsub_rn(A.w, A.y));
                    if (iou_exact(A, areaA, Bx) > iou_thr) { key[i] = 0ull; break; }
                }
            }
            __syncthreads();
        }
    }
}

extern "C" void kernel_launch(void* const* d_in, const int* in_sizes, int n_in,
                              void* d_out, int out_size, void* d_ws, size_t ws_size,
                              hipStream_t stream) {
    const float* boxes  = (const float*)d_in[0];
    const float* scores = (const float*)d_in[1];
    const int*   p_maxo = (const int*)d_in[2];
    const float* p_iou  = (const float*)d_in[3];
    const float* p_sthr = (const float*)d_in[4];

    const dim3 grid(NLANES);
    const dim3 block(NTHREADS);
    const bool out64 = (out_size == NLANES * NMS_MAX_OUT * 3 * 2);

    int* flags = (ws_size >= (size_t)NLANES * sizeof(int)) ? (int*)d_ws : nullptr;

    if (flags) {
        if (out64) {
            hipLaunchKernelGGL(nms_fast<true>, grid, block, 0, stream,
                               boxes, scores, p_maxo, p_iou, p_sthr, d_out, flags);
            hipLaunchKernelGGL(nms_slow<true>, grid, block, 0, stream,
                               boxes, scores, p_maxo, p_iou, p_sthr, d_out, flags);
        } else {
            hipLaunchKernelGGL(nms_fast<false>, grid, block, 0, stream,
                               boxes, scores, p_maxo, p_iou, p_sthr, d_out, flags);
            hipLaunchKernelGGL(nms_slow<false>, grid, block, 0, stream,
                               boxes, scores, p_maxo, p_iou, p_sthr, d_out, flags);
        }
    } else {
        if (out64) {
            hipLaunchKernelGGL(nms_slow<true>, grid, block, 0, stream,
                               boxes, scores, p_maxo, p_iou, p_sthr, d_out, (const int*)nullptr);
        } else {
            hipLaunchKernelGGL(nms_slow<false>, grid, block, 0, stream,
                               boxes, scores, p_maxo, p_iou, p_sthr, d_out, (const int*)nullptr);
        }
    }
}

// Round 10
// 59.717 us; speedup vs baseline: 3.3354x; 1.8336x over previous
//
#include <hip/hip_runtime.h>
#include <stdint.h>

// ONNX NonMaxSuppression: B=8, N=16384, C=80, MAX_OUT=50
// Monolithic fast kernel (r6-proven structure), one block per (b,c):
//   phase A: streaming score scan (16x float4); candidates above fixed
//            optimistic cutoff push unique keys (score<<32|invidx<<18) to LDS
//   phase B: bitonic sort desc over FCAP=256 keys (36 stages)
//   phase C: gather boxes by rank into LDS SoA
//   phase D: wave-0 sorted walk: alive bitmask replicated per lane (4 u64),
//            column boxes in registers, per-round register IoU + __ballot
// FCAP=256 / OPT_THR=0.98828125 (E[cnt]=192): halves every post-scan phase
// vs r6. Overflow (+4.6 sigma) or exhaustion-with-remainder flags the lane;
// gated nms_slow (verified adaptive 2-pass kernel) re-solves those exactly.

#define NMS_B 8
#define NMS_N 16384
#define NMS_C 80
#define NMS_MAX_OUT 50
#define NTHREADS 256
#define NLANES (NMS_B * NMS_C)

#define OPT_THR 0.98828125f  // = 1 - 192/16384 exactly; E[cnt]=192, sigma~13.8
#define FCAP 256
#define WMAX (FCAP / 64)     // 4 alive words

// slow (fallback) kernel
#define NBUCK 256
#define SCAP 1024
#define T_MIN 320

typedef unsigned long long u64;

__device__ __forceinline__ float iou_exact(float4 A, float areaA, float4 Bx) {
    float x1 = fmaxf(A.x, Bx.x);
    float y1 = fmaxf(A.y, Bx.y);
    float x2 = fminf(A.z, Bx.z);
    float y2 = fminf(A.w, Bx.w);
    float dx = fmaxf(__fsub_rn(x2, x1), 0.0f);
    float dy = fmaxf(__fsub_rn(y2, y1), 0.0f);
    if (!(dx > 0.0f && dy > 0.0f)) return 0.0f;   // inter==0 -> iou==0 exactly
    float inter = __fmul_rn(dx, dy);
    float areaB = __fmul_rn(__fsub_rn(Bx.z, Bx.x), __fsub_rn(Bx.w, Bx.y));
    float uni   = __fsub_rn(__fadd_rn(areaA, areaB), inter);
    return __fdiv_rn(inter, fmaxf(uni, 1e-9f));
}

__device__ __forceinline__ float iou_pre(float4 A, float areaA, float4 Bx, float areaB) {
    float x1 = fmaxf(A.x, Bx.x);
    float y1 = fmaxf(A.y, Bx.y);
    float x2 = fminf(A.z, Bx.z);
    float y2 = fminf(A.w, Bx.w);
    float dx = fmaxf(__fsub_rn(x2, x1), 0.0f);
    float dy = fmaxf(__fsub_rn(y2, y1), 0.0f);
    if (!(dx > 0.0f && dy > 0.0f)) return 0.0f;
    float inter = __fmul_rn(dx, dy);
    float uni   = __fsub_rn(__fadd_rn(areaA, areaB), inter);
    return __fdiv_rn(inter, fmaxf(uni, 1e-9f));
}

template <bool OUT64>
__global__ __launch_bounds__(NTHREADS) void nms_fast(
    const float* __restrict__ boxes,
    const float* __restrict__ scores,
    const int* __restrict__ p_maxout,
    const float* __restrict__ p_iou,
    const float* __restrict__ p_sthr,
    void* __restrict__ out_raw,
    int* __restrict__ flags)
{
    __shared__ u64   skey[FCAP];
    __shared__ float sx[FCAP], sy[FCAP], sz[FCAP], sw[FCAP];
    __shared__ int   s_cnt, s_total;

    const int tid = threadIdx.x;
    const int bc  = blockIdx.x;
    const int b   = bc / NMS_C;
    const int c   = bc % NMS_C;

    const float score_thr = p_sthr[0];
    const float iou_thr   = p_iou[0];
    int maxo = p_maxout[0];
    if (maxo > NMS_MAX_OUT) maxo = NMS_MAX_OUT;
    if (maxo < 0) maxo = 0;

    int*       out32 = (int*)out_raw       + (size_t)bc * NMS_MAX_OUT * 3;
    long long* out64 = (long long*)out_raw + (size_t)bc * NMS_MAX_OUT * 3;
    for (int i = tid; i < NMS_MAX_OUT * 3; i += NTHREADS) {
        if (OUT64) out64[i] = -1LL; else out32[i] = -1;
    }

    skey[tid] = 0ull;                        // FCAP == NTHREADS
    if (tid == 0) { s_cnt = 0; s_total = 0; }
    __syncthreads();

    const float4* sc4     = (const float4*)(scores + ((size_t)b * NMS_C + c) * NMS_N);
    const float4* boxes_b = (const float4*)(boxes + (size_t)b * NMS_N * 4);

    // ---- phase A: streaming score scan ----
    float4 av[16];
    #pragma unroll
    for (int u = 0; u < 16; ++u) av[u] = sc4[u * NTHREADS + tid];

    int local_total = 0;
    #pragma unroll
    for (int u = 0; u < 16; ++u) {
        const int i = u * NTHREADS + tid;
        float ss[4] = {av[u].x, av[u].y, av[u].z, av[u].w};
        #pragma unroll
        for (int j = 0; j < 4; ++j) {
            float s = ss[j];
            bool cand = (s > score_thr);
            local_total += cand ? 1 : 0;
            if (cand && s >= OPT_THR) {      // rare (~1.2%)
                int n = i * 4 + j;
                int p = atomicAdd(&s_cnt, 1);
                if (p < FCAP) {
                    skey[p] = ((u64)__float_as_uint(s) << 32)
                            | ((u64)(NMS_N - 1 - n) << 18);
                }
            }
        }
    }
    atomicAdd(&s_total, local_total);
    __syncthreads();

    const int  m        = (s_cnt < FCAP) ? s_cnt : FCAP;
    const bool overflow = (s_cnt > FCAP);
    const int  rem      = s_total - s_cnt;   // candidates below optimistic cut

    if (overflow) {                          // uniform block-wide bail
        if (tid == 0) flags[bc] = 1;
        return;
    }

    // ---- phase B: bitonic sort descending over FCAP=256 keys (36 stages) ----
    for (int kk = 2; kk <= FCAP; kk <<= 1) {
        for (int jj = kk >> 1; jj > 0; jj >>= 1) {
            if (tid < FCAP / 2) {
                int i  = 2 * jj * (tid / jj) + (tid % jj);
                int p2 = i + jj;
                bool dirDesc = ((i & kk) == 0);
                u64 a = skey[i], bkey = skey[p2];
                bool swapq = dirDesc ? (a < bkey) : (a > bkey);
                if (swapq) { skey[i] = bkey; skey[p2] = a; }
            }
            __syncthreads();
        }
    }

    // ---- phase C: gather boxes by rank into SoA LDS ----
    {
        const int n = NMS_N - 1 - (int)((skey[tid] >> 18) & 0x3FFFull);  // pad-safe
        float4 bb = boxes_b[n];
        sx[tid] = bb.x; sy[tid] = bb.y; sz[tid] = bb.z; sw[tid] = bb.w;
    }
    __syncthreads();

    if (tid >= 64) return;                   // waves 1..3 retire
    const int lane = tid;

    // ---- phase D: sorted walk, alive mask replicated in every lane ----
    float4 bxc[WMAX];
    float  areaBc[WMAX];
    #pragma unroll
    for (int w2 = 0; w2 < WMAX; ++w2) {
        const int j = w2 * 64 + lane;
        bxc[w2] = make_float4(sx[j], sy[j], sz[j], sw[j]);
        areaBc[w2] = __fmul_rn(__fsub_rn(bxc[w2].z, bxc[w2].x),
                               __fsub_rn(bxc[w2].w, bxc[w2].y));
    }

    u64 aliveW[WMAX];
    #pragma unroll
    for (int w2 = 0; w2 < WMAX; ++w2) {
        const int base = w2 * 64;
        aliveW[w2] = (m > base)
                   ? ((m - base >= 64) ? ~0ull : ((1ull << (m - base)) - 1ull))
                   : 0ull;
    }

    int need_slow = 0;
    for (int t = 0; t < maxo; ++t) {
        // lane-local find of lowest-rank alive candidate (replicated => uniform)
        int w = WMAX; u64 cw = 0ull;
        #pragma unroll
        for (int q = WMAX - 1; q >= 0; --q)
            if (aliveW[q] != 0ull) { w = q; cw = aliveW[q]; }
        if (w == WMAX) {                     // exhausted
            if (rem > 0) need_slow = 1;
            break;
        }
        const int bit = __builtin_ctzll(cw);
        const int r   = w * 64 + bit;

        const u64 kr = skey[r];              // uniform -> broadcast
        const int n  = NMS_N - 1 - (int)((kr >> 18) & 0x3FFFull);
        if (lane == 0) {
            if (OUT64) {
                out64[t * 3 + 0] = (long long)b;
                out64[t * 3 + 1] = (long long)c;
                out64[t * 3 + 2] = (long long)n;
            } else {
                out32[t * 3 + 0] = b;
                out32[t * 3 + 1] = c;
                out32[t * 3 + 2] = n;
            }
        }
        const float4 A = make_float4(sx[r], sy[r], sz[r], sw[r]);  // uniform
        const float areaA = __fmul_rn(__fsub_rn(A.z, A.x), __fsub_rn(A.w, A.y));

        #pragma unroll
        for (int w2 = 0; w2 < WMAX; ++w2) {
            const bool valid = (w2 * 64 + lane) < m;
            const bool sup = valid &&
                (iou_pre(A, areaA, bxc[w2], areaBc[w2]) > iou_thr);
            u64 kill = __ballot(sup);
            if (w2 == w) kill |= (1ull << bit);   // self (zero-area safe)
            aliveW[w2] &= ~kill;
        }
    }
    if (lane == 0) flags[bc] = need_slow;
}

// ---- slow exact fallback (verified round-2 structure, flag-gated) ----
__device__ __forceinline__ int bucketf(float s) {
    int v = (int)__float_as_uint(s) - 0x3F000000;
    v >>= 15;
    return v < 0 ? 0 : (v > 255 ? 255 : v);
}

template <bool OUT64>
__global__ __launch_bounds__(NTHREADS) void nms_slow(
    const float* __restrict__ boxes,
    const float* __restrict__ scores,
    const int* __restrict__ p_maxout,
    const float* __restrict__ p_iou,
    const float* __restrict__ p_sthr,
    void* __restrict__ out_raw,
    const int* __restrict__ flags)
{
    __shared__ int    hist[NBUCK];
    __shared__ u64    key[SCAP];
    __shared__ float4 cbox[SCAP];
    __shared__ float4 selbox[NMS_MAX_OUT];
    __shared__ u64    s_wmax[NTHREADS / 64];
    __shared__ u64    s_best;
    __shared__ int    s_cnt, s_cutLo, s_cutHi, s_rem, s_state;

    const int tid = threadIdx.x;
    const int bc  = blockIdx.x;
    if (flags && flags[bc] == 0) return;     // uniform exit before any barrier
    const int b   = bc / NMS_C;
    const int c   = bc % NMS_C;

    const float score_thr = p_sthr[0];
    const float iou_thr   = p_iou[0];
    int maxo = p_maxout[0];
    if (maxo > NMS_MAX_OUT) maxo = NMS_MAX_OUT;
    if (maxo < 0) maxo = 0;

    int*       out32 = (int*)out_raw       + (size_t)bc * NMS_MAX_OUT * 3;
    long long* out64 = (long long*)out_raw + (size_t)bc * NMS_MAX_OUT * 3;
    for (int i = tid; i < NMS_MAX_OUT * 3; i += NTHREADS) {
        if (OUT64) out64[i] = -1LL; else out32[i] = -1;
    }

    const float*  sc      = scores + ((size_t)b * NMS_C + c) * NMS_N;
    const float4* sc4     = (const float4*)sc;
    const float4* boxes_b = (const float4*)(boxes + (size_t)b * NMS_N * 4);

    for (int i = tid; i < NBUCK; i += NTHREADS) hist[i] = 0;
    if (tid == 0) s_cnt = 0;
    __syncthreads();
    for (int i = tid; i < NMS_N / 4; i += NTHREADS) {
        float4 s4 = sc4[i];
        float ss[4] = {s4.x, s4.y, s4.z, s4.w};
        #pragma unroll
        for (int j = 0; j < 4; ++j)
            if (ss[j] > score_thr) atomicAdd(&hist[bucketf(ss[j])], 1);
    }
    __syncthreads();

    if (tid == 0) {
        int cum = 0, cut = NBUCK;
        for (int bk = NBUCK - 1; bk >= 0; --bk) {
            int h = hist[bk];
            if (cum > 0 && cum + h > SCAP) break;
            cum += h; cut = bk;
            if (cum >= T_MIN) break;
        }
        s_cutLo = cut; s_cutHi = NBUCK - 1;
        int rem = 0;
        for (int bk = 0; bk < cut; ++bk) rem += hist[bk];
        s_rem = rem;
    }
    __syncthreads();

    auto compact = [&](int lo, int hi) {
        for (int i = tid; i < NMS_N / 4; i += NTHREADS) {
            float4 s4 = sc4[i];
            float ss[4] = {s4.x, s4.y, s4.z, s4.w};
            #pragma unroll
            for (int j = 0; j < 4; ++j) {
                float s = ss[j];
                if (s > score_thr) {
                    int bk = bucketf(s);
                    if (bk >= lo && bk <= hi) {
                        int n = i * 4 + j;
                        int p = atomicAdd(&s_cnt, 1);
                        if (p < SCAP) {
                            key[p] = ((u64)__float_as_uint(s) << 24)
                                   | ((u64)(NMS_N - 1 - n) << 10)
                                   | (u64)p;
                            cbox[p] = boxes_b[n];
                        }
                    }
                }
            }
        }
    };
    compact(s_cutLo, s_cutHi);
    __syncthreads();

    int t = 0;
    while (t < maxo) {
        int m = s_cnt; if (m > SCAP) m = SCAP;
        u64 lmax = 0ull;
        for (int i = tid; i < m; i += NTHREADS) {
            u64 k = key[i];
            if (k > lmax) lmax = k;
        }
        #pragma unroll
        for (int off = 32; off > 0; off >>= 1) {
            u64 o = __shfl_down(lmax, off);
            if (o > lmax) lmax = o;
        }
        if ((tid & 63) == 0) s_wmax[tid >> 6] = lmax;
        __syncthreads();
        if (tid == 0) {
            u64 best = s_wmax[0];
            #pragma unroll
            for (int w = 1; w < NTHREADS / 64; ++w)
                if (s_wmax[w] > best) best = s_wmax[w];
            s_best = best;
            if (best) {
                int slot = (int)(best & 0x3FFull);
                int n    = NMS_N - 1 - (int)((best >> 10) & 0x3FFFull);
                key[slot] = 0ull;
                if (OUT64) {
                    out64[t * 3 + 0] = (long long)b;
                    out64[t * 3 + 1] = (long long)c;
                    out64[t * 3 + 2] = (long long)n;
                } else {
                    out32[t * 3 + 0] = b;
                    out32[t * 3 + 1] = c;
                    out32[t * 3 + 2] = n;
                }
                selbox[t] = cbox[slot];
                s_state = 0;
            } else if (s_rem == 0) {
                s_state = 2;
            } else {
                int hiB = s_cutLo - 1;
                int cum = 0, cut = hiB + 1;
                for (int bk = hiB; bk >= 0; --bk) {
                    int h = hist[bk];
                    if (cum > 0 && cum + h > SCAP) break;
                    cum += h; cut = bk;
                    if (cum >= T_MIN) break;
                }
                s_cutLo = cut; s_cutHi = hiB;
                int rem = 0;
                for (int bk = 0; bk < cut; ++bk) rem += hist[bk];
                s_rem = rem;
                s_cnt = 0;
                s_state = 1;
            }
        }
        __syncthreads();

        if (s_state == 2) break;

        if (s_state == 0) {
            const float4 A = selbox[t];
            const float areaA = __fmul_rn(__fsub_rn(A.z, A.x), __fsub_rn(A.w, A.y));
            int m0 = s_cnt; if (m0 > SCAP) m0 = SCAP;
            for (int i = tid; i < m0; i += NTHREADS) {
                u64 k = key[i];
                if (!k) continue;
                if (iou_exact(A, areaA, cbox[i]) > iou_thr) key[i] = 0ull;
            }
            __syncthreads();
            ++t;
        } else {
            compact(s_cutLo, s_cutHi);
            __syncthreads();
            int m2 = s_cnt; if (m2 > SCAP) m2 = SCAP;
            for (int i = tid; i < m2; i += NTHREADS) {
                u64 k = key[i];
                if (!k) continue;
                float4 Bx = cbox[i];
                for (int j = 0; j < t; ++j) {
                    float4 A = selbox[j];
                    float areaA = __fmul_rn(__fsub_rn(A.z, A.x), __fsub_rn(A.w, A.y));
                    if (iou_exact(A, areaA, Bx) > iou_thr) { key[i] = 0ull; break; }
                }
            }
            __syncthreads();
        }
    }
}

extern "C" void kernel_launch(void* const* d_in, const int* in_sizes, int n_in,
                              void* d_out, int out_size, void* d_ws, size_t ws_size,
                              hipStream_t stream) {
    const float* boxes  = (const float*)d_in[0];
    const float* scores = (const float*)d_in[1];
    const int*   p_maxo = (const int*)d_in[2];
    const float* p_iou  = (const float*)d_in[3];
    const float* p_sthr = (const float*)d_in[4];

    const dim3 grid(NLANES);
    const dim3 block(NTHREADS);
    const bool out64 = (out_size == NLANES * NMS_MAX_OUT * 3 * 2);

    int* flags = (ws_size >= (size_t)NLANES * sizeof(int)) ? (int*)d_ws : nullptr;

    if (flags) {
        if (out64) {
            hipLaunchKernelGGL(nms_fast<true>, grid, block, 0, stream,
                               boxes, scores, p_maxo, p_iou, p_sthr, d_out, flags);
            hipLaunchKernelGGL(nms_slow<true>, grid, block, 0, stream,
                               boxes, scores, p_maxo, p_iou, p_sthr, d_out, flags);
        } else {
            hipLaunchKernelGGL(nms_fast<false>, grid, block, 0, stream,
                               boxes, scores, p_maxo, p_iou, p_sthr, d_out, flags);
            hipLaunchKernelGGL(nms_slow<false>, grid, block, 0, stream,
                               boxes, scores, p_maxo, p_iou, p_sthr, d_out, flags);
        }
    } else {
        if (out64) {
            hipLaunchKernelGGL(nms_slow<true>, grid, block, 0, stream,
                               boxes, scores, p_maxo, p_iou, p_sthr, d_out, (const int*)nullptr);
        } else {
            hipLaunchKernelGGL(nms_slow<false>, grid, block, 0, stream,
                               boxes, scores, p_maxo, p_iou, p_sthr, d_out, (const int*)nullptr);
        }
    }
}

// Round 11
// 57.381 us; speedup vs baseline: 3.4712x; 1.0407x over previous
//
#include <hip/hip_runtime.h>
#include <stdint.h>

// ONNX NonMaxSuppression: B=8, N=16384, C=80, MAX_OUT=50
// Monolithic fast kernel (r10-proven structure), one block per (b,c):
//   phase A: streaming score scan; 16x float4 preload FORCED into flight
//            (launch_bounds(256,4) lifts VGPR cap; sched_barrier(0) pins
//            loads before consumes -> one latency exposure, not ~4)
//   phase B: bitonic sort desc over FCAP=256 keys (36 stages)
//   phase C: gather boxes by rank into LDS SoA
//   phase D: wave-0 sorted walk: alive bitmask replicated per lane (4 u64),
//            column boxes in registers, per-round register IoU + __ballot,
//            word loop restricted to wave-uniform [w, Wlim)
// Exactness: overflow or exhaustion-with-remainder flags the lane in d_ws;
// gated nms_slow (verified adaptive 2-pass kernel) re-solves those lanes.

#define NMS_B 8
#define NMS_N 16384
#define NMS_C 80
#define NMS_MAX_OUT 50
#define NTHREADS 256
#define NLANES (NMS_B * NMS_C)

#define OPT_THR 0.98828125f  // = 1 - 192/16384 exactly; E[cnt]=192, sigma~13.8
#define FCAP 256
#define WMAX (FCAP / 64)     // 4 alive words

// slow (fallback) kernel
#define NBUCK 256
#define SCAP 1024
#define T_MIN 320

typedef unsigned long long u64;

__device__ __forceinline__ float iou_exact(float4 A, float areaA, float4 Bx) {
    float x1 = fmaxf(A.x, Bx.x);
    float y1 = fmaxf(A.y, Bx.y);
    float x2 = fminf(A.z, Bx.z);
    float y2 = fminf(A.w, Bx.w);
    float dx = fmaxf(__fsub_rn(x2, x1), 0.0f);
    float dy = fmaxf(__fsub_rn(y2, y1), 0.0f);
    if (!(dx > 0.0f && dy > 0.0f)) return 0.0f;   // inter==0 -> iou==0 exactly
    float inter = __fmul_rn(dx, dy);
    float areaB = __fmul_rn(__fsub_rn(Bx.z, Bx.x), __fsub_rn(Bx.w, Bx.y));
    float uni   = __fsub_rn(__fadd_rn(areaA, areaB), inter);
    return __fdiv_rn(inter, fmaxf(uni, 1e-9f));
}

__device__ __forceinline__ float iou_pre(float4 A, float areaA, float4 Bx, float areaB) {
    float x1 = fmaxf(A.x, Bx.x);
    float y1 = fmaxf(A.y, Bx.y);
    float x2 = fminf(A.z, Bx.z);
    float y2 = fminf(A.w, Bx.w);
    float dx = fmaxf(__fsub_rn(x2, x1), 0.0f);
    float dy = fmaxf(__fsub_rn(y2, y1), 0.0f);
    if (!(dx > 0.0f && dy > 0.0f)) return 0.0f;
    float inter = __fmul_rn(dx, dy);
    float uni   = __fsub_rn(__fadd_rn(areaA, areaB), inter);
    return __fdiv_rn(inter, fmaxf(uni, 1e-9f));
}

template <bool OUT64>
__global__ __launch_bounds__(NTHREADS, 4) void nms_fast(
    const float* __restrict__ boxes,
    const float* __restrict__ scores,
    const int* __restrict__ p_maxout,
    const float* __restrict__ p_iou,
    const float* __restrict__ p_sthr,
    void* __restrict__ out_raw,
    int* __restrict__ flags)
{
    __shared__ u64   skey[FCAP];
    __shared__ float sx[FCAP], sy[FCAP], sz[FCAP], sw[FCAP];
    __shared__ int   s_cnt, s_total;

    const int tid = threadIdx.x;
    const int bc  = blockIdx.x;
    const int b   = bc / NMS_C;
    const int c   = bc % NMS_C;

    const float4* sc4     = (const float4*)(scores + ((size_t)b * NMS_C + c) * NMS_N);
    const float4* boxes_b = (const float4*)(boxes + (size_t)b * NMS_N * 4);

    // issue ALL 16 score loads first; nothing below depends on them yet
    float4 av[16];
    #pragma unroll
    for (int u = 0; u < 16; ++u) av[u] = sc4[u * NTHREADS + tid];
    __builtin_amdgcn_sched_barrier(0);       // keep loads ahead of consumes

    const float score_thr = p_sthr[0];
    const float iou_thr   = p_iou[0];
    int maxo = p_maxout[0];
    if (maxo > NMS_MAX_OUT) maxo = NMS_MAX_OUT;
    if (maxo < 0) maxo = 0;

    int*       out32 = (int*)out_raw       + (size_t)bc * NMS_MAX_OUT * 3;
    long long* out64 = (long long*)out_raw + (size_t)bc * NMS_MAX_OUT * 3;
    for (int i = tid; i < NMS_MAX_OUT * 3; i += NTHREADS) {
        if (OUT64) out64[i] = -1LL; else out32[i] = -1;
    }

    skey[tid] = 0ull;                        // FCAP == NTHREADS
    if (tid == 0) { s_cnt = 0; s_total = 0; }
    __syncthreads();

    // ---- phase A: consume the in-flight scores ----
    int local_total = 0;
    #pragma unroll
    for (int u = 0; u < 16; ++u) {
        const int i = u * NTHREADS + tid;
        float ss[4] = {av[u].x, av[u].y, av[u].z, av[u].w};
        #pragma unroll
        for (int j = 0; j < 4; ++j) {
            float s = ss[j];
            bool cand = (s > score_thr);
            local_total += cand ? 1 : 0;
            if (cand && s >= OPT_THR) {      // rare (~1.2%)
                int n = i * 4 + j;
                int p = atomicAdd(&s_cnt, 1);
                if (p < FCAP) {
                    skey[p] = ((u64)__float_as_uint(s) << 32)
                            | ((u64)(NMS_N - 1 - n) << 18);
                }
            }
        }
    }
    atomicAdd(&s_total, local_total);
    __syncthreads();

    const int  m        = (s_cnt < FCAP) ? s_cnt : FCAP;
    const bool overflow = (s_cnt > FCAP);
    const int  rem      = s_total - s_cnt;   // candidates below optimistic cut

    if (overflow) {                          // uniform block-wide bail
        if (tid == 0) flags[bc] = 1;
        return;
    }

    // ---- phase B: bitonic sort descending over FCAP=256 keys (36 stages) ----
    for (int kk = 2; kk <= FCAP; kk <<= 1) {
        for (int jj = kk >> 1; jj > 0; jj >>= 1) {
            if (tid < FCAP / 2) {
                int i  = 2 * jj * (tid / jj) + (tid % jj);
                int p2 = i + jj;
                bool dirDesc = ((i & kk) == 0);
                u64 a = skey[i], bkey = skey[p2];
                bool swapq = dirDesc ? (a < bkey) : (a > bkey);
                if (swapq) { skey[i] = bkey; skey[p2] = a; }
            }
            __syncthreads();
        }
    }

    // ---- phase C: gather boxes by rank into SoA LDS ----
    {
        const int n = NMS_N - 1 - (int)((skey[tid] >> 18) & 0x3FFFull);  // pad-safe
        float4 bb = boxes_b[n];
        sx[tid] = bb.x; sy[tid] = bb.y; sz[tid] = bb.z; sw[tid] = bb.w;
    }
    __syncthreads();

    if (tid >= 64) return;                   // waves 1..3 retire
    const int lane = tid;

    // ---- phase D: sorted walk, alive mask replicated in every lane ----
    float4 bxc[WMAX];
    float  areaBc[WMAX];
    #pragma unroll
    for (int w2 = 0; w2 < WMAX; ++w2) {
        const int j = w2 * 64 + lane;
        bxc[w2] = make_float4(sx[j], sy[j], sz[j], sw[j]);
        areaBc[w2] = __fmul_rn(__fsub_rn(bxc[w2].z, bxc[w2].x),
                               __fsub_rn(bxc[w2].w, bxc[w2].y));
    }

    u64 aliveW[WMAX];
    #pragma unroll
    for (int w2 = 0; w2 < WMAX; ++w2) {
        const int base = w2 * 64;
        aliveW[w2] = (m > base)
                   ? ((m - base >= 64) ? ~0ull : ((1ull << (m - base)) - 1ull))
                   : 0ull;
    }
    const int Wlim = (m + 63) >> 6;          // wave-uniform

    int need_slow = 0;
    for (int t = 0; t < maxo; ++t) {
        // lane-local find of lowest-rank alive candidate (replicated => uniform)
        int w = WMAX; u64 cw = 0ull;
        #pragma unroll
        for (int q = WMAX - 1; q >= 0; --q)
            if (aliveW[q] != 0ull) { w = q; cw = aliveW[q]; }
        if (w == WMAX) {                     // exhausted
            if (rem > 0) need_slow = 1;
            break;
        }
        const int bit = __builtin_ctzll(cw);
        const int r   = w * 64 + bit;

        const u64 kr = skey[r];              // uniform -> broadcast
        const int n  = NMS_N - 1 - (int)((kr >> 18) & 0x3FFFull);
        if (lane == 0) {
            if (OUT64) {
                out64[t * 3 + 0] = (long long)b;
                out64[t * 3 + 1] = (long long)c;
                out64[t * 3 + 2] = (long long)n;
            } else {
                out32[t * 3 + 0] = b;
                out32[t * 3 + 1] = c;
                out32[t * 3 + 2] = n;
            }
        }
        const float4 A = make_float4(sx[r], sy[r], sz[r], sw[r]);  // uniform
        const float areaA = __fmul_rn(__fsub_rn(A.z, A.x), __fsub_rn(A.w, A.y));

        // suppression: only words [w, Wlim) can hold alive bits
        #pragma unroll
        for (int w2 = 0; w2 < WMAX; ++w2) {
            if (w2 >= w && w2 < Wlim) {      // wave-uniform guards
                const bool sup = iou_pre(A, areaA, bxc[w2], areaBc[w2]) > iou_thr;
                u64 kill = __ballot(sup);
                if (w2 == w) kill |= (1ull << bit);   // self (zero-area safe)
                aliveW[w2] &= ~kill;
            }
        }
    }
    if (lane == 0) flags[bc] = need_slow;
}

// ---- slow exact fallback (verified round-2 structure, flag-gated) ----
__device__ __forceinline__ int bucketf(float s) {
    int v = (int)__float_as_uint(s) - 0x3F000000;
    v >>= 15;
    return v < 0 ? 0 : (v > 255 ? 255 : v);
}

template <bool OUT64>
__global__ __launch_bounds__(NTHREADS) void nms_slow(
    const float* __restrict__ boxes,
    const float* __restrict__ scores,
    const int* __restrict__ p_maxout,
    const float* __restrict__ p_iou,
    const float* __restrict__ p_sthr,
    void* __restrict__ out_raw,
    const int* __restrict__ flags)
{
    __shared__ int    hist[NBUCK];
    __shared__ u64    key[SCAP];
    __shared__ float4 cbox[SCAP];
    __shared__ float4 selbox[NMS_MAX_OUT];
    __shared__ u64    s_wmax[NTHREADS / 64];
    __shared__ u64    s_best;
    __shared__ int    s_cnt, s_cutLo, s_cutHi, s_rem, s_state;

    const int tid = threadIdx.x;
    const int bc  = blockIdx.x;
    if (flags && flags[bc] == 0) return;     // uniform exit before any barrier
    const int b   = bc / NMS_C;
    const int c   = bc % NMS_C;

    const float score_thr = p_sthr[0];
    const float iou_thr   = p_iou[0];
    int maxo = p_maxout[0];
    if (maxo > NMS_MAX_OUT) maxo = NMS_MAX_OUT;
    if (maxo < 0) maxo = 0;

    int*       out32 = (int*)out_raw       + (size_t)bc * NMS_MAX_OUT * 3;
    long long* out64 = (long long*)out_raw + (size_t)bc * NMS_MAX_OUT * 3;
    for (int i = tid; i < NMS_MAX_OUT * 3; i += NTHREADS) {
        if (OUT64) out64[i] = -1LL; else out32[i] = -1;
    }

    const float*  sc      = scores + ((size_t)b * NMS_C + c) * NMS_N;
    const float4* sc4     = (const float4*)sc;
    const float4* boxes_b = (const float4*)(boxes + (size_t)b * NMS_N * 4);

    for (int i = tid; i < NBUCK; i += NTHREADS) hist[i] = 0;
    if (tid == 0) s_cnt = 0;
    __syncthreads();
    for (int i = tid; i < NMS_N / 4; i += NTHREADS) {
        float4 s4 = sc4[i];
        float ss[4] = {s4.x, s4.y, s4.z, s4.w};
        #pragma unroll
        for (int j = 0; j < 4; ++j)
            if (ss[j] > score_thr) atomicAdd(&hist[bucketf(ss[j])], 1);
    }
    __syncthreads();

    if (tid == 0) {
        int cum = 0, cut = NBUCK;
        for (int bk = NBUCK - 1; bk >= 0; --bk) {
            int h = hist[bk];
            if (cum > 0 && cum + h > SCAP) break;
            cum += h; cut = bk;
            if (cum >= T_MIN) break;
        }
        s_cutLo = cut; s_cutHi = NBUCK - 1;
        int rem = 0;
        for (int bk = 0; bk < cut; ++bk) rem += hist[bk];
        s_rem = rem;
    }
    __syncthreads();

    auto compact = [&](int lo, int hi) {
        for (int i = tid; i < NMS_N / 4; i += NTHREADS) {
            float4 s4 = sc4[i];
            float ss[4] = {s4.x, s4.y, s4.z, s4.w};
            #pragma unroll
            for (int j = 0; j < 4; ++j) {
                float s = ss[j];
                if (s > score_thr) {
                    int bk = bucketf(s);
                    if (bk >= lo && bk <= hi) {
                        int n = i * 4 + j;
                        int p = atomicAdd(&s_cnt, 1);
                        if (p < SCAP) {
                            key[p] = ((u64)__float_as_uint(s) << 24)
                                   | ((u64)(NMS_N - 1 - n) << 10)
                                   | (u64)p;
                            cbox[p] = boxes_b[n];
                        }
                    }
                }
            }
        }
    };
    compact(s_cutLo, s_cutHi);
    __syncthreads();

    int t = 0;
    while (t < maxo) {
        int m = s_cnt; if (m > SCAP) m = SCAP;
        u64 lmax = 0ull;
        for (int i = tid; i < m; i += NTHREADS) {
            u64 k = key[i];
            if (k > lmax) lmax = k;
        }
        #pragma unroll
        for (int off = 32; off > 0; off >>= 1) {
            u64 o = __shfl_down(lmax, off);
            if (o > lmax) lmax = o;
        }
        if ((tid & 63) == 0) s_wmax[tid >> 6] = lmax;
        __syncthreads();
        if (tid == 0) {
            u64 best = s_wmax[0];
            #pragma unroll
            for (int w = 1; w < NTHREADS / 64; ++w)
                if (s_wmax[w] > best) best = s_wmax[w];
            s_best = best;
            if (best) {
                int slot = (int)(best & 0x3FFull);
                int n    = NMS_N - 1 - (int)((best >> 10) & 0x3FFFull);
                key[slot] = 0ull;
                if (OUT64) {
                    out64[t * 3 + 0] = (long long)b;
                    out64[t * 3 + 1] = (long long)c;
                    out64[t * 3 + 2] = (long long)n;
                } else {
                    out32[t * 3 + 0] = b;
                    out32[t * 3 + 1] = c;
                    out32[t * 3 + 2] = n;
                }
                selbox[t] = cbox[slot];
                s_state = 0;
            } else if (s_rem == 0) {
                s_state = 2;
            } else {
                int hiB = s_cutLo - 1;
                int cum = 0, cut = hiB + 1;
                for (int bk = hiB; bk >= 0; --bk) {
                    int h = hist[bk];
                    if (cum > 0 && cum + h > SCAP) break;
                    cum += h; cut = bk;
                    if (cum >= T_MIN) break;
                }
                s_cutLo = cut; s_cutHi = hiB;
                int rem = 0;
                for (int bk = 0; bk < cut; ++bk) rem += hist[bk];
                s_rem = rem;
                s_cnt = 0;
                s_state = 1;
            }
        }
        __syncthreads();

        if (s_state == 2) break;

        if (s_state == 0) {
            const float4 A = selbox[t];
            const float areaA = __fmul_rn(__fsub_rn(A.z, A.x), __fsub_rn(A.w, A.y));
            int m0 = s_cnt; if (m0 > SCAP) m0 = SCAP;
            for (int i = tid; i < m0; i += NTHREADS) {
                u64 k = key[i];
                if (!k) continue;
                if (iou_exact(A, areaA, cbox[i]) > iou_thr) key[i] = 0ull;
            }
            __syncthreads();
            ++t;
        } else {
            compact(s_cutLo, s_cutHi);
            __syncthreads();
            int m2 = s_cnt; if (m2 > SCAP) m2 = SCAP;
            for (int i = tid; i < m2; i += NTHREADS) {
                u64 k = key[i];
                if (!k) continue;
                float4 Bx = cbox[i];
                for (int j = 0; j < t; ++j) {
                    float4 A = selbox[j];
                    float areaA = __fmul_rn(__fsub_rn(A.z, A.x), __fsub_rn(A.w, A.y));
                    if (iou_exact(A, areaA, Bx) > iou_thr) { key[i] = 0ull; break; }
                }
            }
            __syncthreads();
        }
    }
}

extern "C" void kernel_launch(void* const* d_in, const int* in_sizes, int n_in,
                              void* d_out, int out_size, void* d_ws, size_t ws_size,
                              hipStream_t stream) {
    const float* boxes  = (const float*)d_in[0];
    const float* scores = (const float*)d_in[1];
    const int*   p_maxo = (const int*)d_in[2];
    const float* p_iou  = (const float*)d_in[3];
    const float* p_sthr = (const float*)d_in[4];

    const dim3 grid(NLANES);
    const dim3 block(NTHREADS);
    const bool out64 = (out_size == NLANES * NMS_MAX_OUT * 3 * 2);

    int* flags = (ws_size >= (size_t)NLANES * sizeof(int)) ? (int*)d_ws : nullptr;

    if (flags) {
        if (out64) {
            hipLaunchKernelGGL(nms_fast<true>, grid, block, 0, stream,
                               boxes, scores, p_maxo, p_iou, p_sthr, d_out, flags);
            hipLaunchKernelGGL(nms_slow<true>, grid, block, 0, stream,
                               boxes, scores, p_maxo, p_iou, p_sthr, d_out, flags);
        } else {
            hipLaunchKernelGGL(nms_fast<false>, grid, block, 0, stream,
                               boxes, scores, p_maxo, p_iou, p_sthr, d_out, flags);
            hipLaunchKernelGGL(nms_slow<false>, grid, block, 0, stream,
                               boxes, scores, p_maxo, p_iou, p_sthr, d_out, flags);
        }
    } else {
        if (out64) {
            hipLaunchKernelGGL(nms_slow<true>, grid, block, 0, stream,
                               boxes, scores, p_maxo, p_iou, p_sthr, d_out, (const int*)nullptr);
        } else {
            hipLaunchKernelGGL(nms_slow<false>, grid, block, 0, stream,
                               boxes, scores, p_maxo, p_iou, p_sthr, d_out, (const int*)nullptr);
        }
    }
}

// Round 12
// 56.959 us; speedup vs baseline: 3.4969x; 1.0074x over previous
//
#include <hip/hip_runtime.h>
#include <stdint.h>

// ONNX NonMaxSuppression: B=8, N=16384, C=80, MAX_OUT=50
// Monolithic fast kernel, one block per (b,c):
//   phase A: streaming score scan (16x float4 preload); candidates above
//            fixed optimistic cutoff push unique keys to LDS (unsorted)
//   phase B: REGISTER bitonic sort in wave 0: 4 keys/lane (i = q*64+lane),
//            33 shfl_xor stages + 3 register-pair stages, ZERO barriers,
//            zero LDS traffic (replaces 36-barrier LDS bitonic)
//   phase C: wave 0 gathers boxes straight into the walk's column registers
//            (sorted layout == walk layout); writes n + box per rank to LDS
//            once for the uniform per-round broadcast reads
//   phase D: sorted walk: alive bitmask replicated per lane (4 u64),
//            per-round register IoU + __ballot, words [w, Wlim) only
// Exactness: overflow or exhaustion-with-remainder flags the lane in d_ws;
// gated nms_slow (verified adaptive 2-pass kernel) re-solves those lanes.

#define NMS_B 8
#define NMS_N 16384
#define NMS_C 80
#define NMS_MAX_OUT 50
#define NTHREADS 256
#define NLANES (NMS_B * NMS_C)

#define OPT_THR 0.98828125f  // = 1 - 192/16384 exactly; E[cnt]=192, sigma~13.8
#define FCAP 256
#define WMAX (FCAP / 64)     // 4 alive words / 4 regs per lane

// slow (fallback) kernel
#define NBUCK 256
#define SCAP 1024
#define T_MIN 320

typedef unsigned long long u64;

__device__ __forceinline__ float iou_exact(float4 A, float areaA, float4 Bx) {
    float x1 = fmaxf(A.x, Bx.x);
    float y1 = fmaxf(A.y, Bx.y);
    float x2 = fminf(A.z, Bx.z);
    float y2 = fminf(A.w, Bx.w);
    float dx = fmaxf(__fsub_rn(x2, x1), 0.0f);
    float dy = fmaxf(__fsub_rn(y2, y1), 0.0f);
    if (!(dx > 0.0f && dy > 0.0f)) return 0.0f;   // inter==0 -> iou==0 exactly
    float inter = __fmul_rn(dx, dy);
    float areaB = __fmul_rn(__fsub_rn(Bx.z, Bx.x), __fsub_rn(Bx.w, Bx.y));
    float uni   = __fsub_rn(__fadd_rn(areaA, areaB), inter);
    return __fdiv_rn(inter, fmaxf(uni, 1e-9f));
}

__device__ __forceinline__ float iou_pre(float4 A, float areaA, float4 Bx, float areaB) {
    float x1 = fmaxf(A.x, Bx.x);
    float y1 = fmaxf(A.y, Bx.y);
    float x2 = fminf(A.z, Bx.z);
    float y2 = fminf(A.w, Bx.w);
    float dx = fmaxf(__fsub_rn(x2, x1), 0.0f);
    float dy = fmaxf(__fsub_rn(y2, y1), 0.0f);
    if (!(dx > 0.0f && dy > 0.0f)) return 0.0f;
    float inter = __fmul_rn(dx, dy);
    float uni   = __fsub_rn(__fadd_rn(areaA, areaB), inter);
    return __fdiv_rn(inter, fmaxf(uni, 1e-9f));
}

__device__ __forceinline__ u64 umax64(u64 a, u64 b) { return a > b ? a : b; }
__device__ __forceinline__ u64 umin64(u64 a, u64 b) { return a < b ? a : b; }

template <bool OUT64>
__global__ __launch_bounds__(NTHREADS, 4) void nms_fast(
    const float* __restrict__ boxes,
    const float* __restrict__ scores,
    const int* __restrict__ p_maxout,
    const float* __restrict__ p_iou,
    const float* __restrict__ p_sthr,
    void* __restrict__ out_raw,
    int* __restrict__ flags)
{
    __shared__ u64    skey[FCAP];           // unsorted compaction
    __shared__ int    sn[FCAP];             // sorted: box index per rank
    __shared__ float4 sbox[FCAP];           // sorted: box per rank
    __shared__ int    s_cnt, s_total;

    const int tid = threadIdx.x;
    const int bc  = blockIdx.x;
    const int b   = bc / NMS_C;
    const int c   = bc % NMS_C;

    const float4* sc4     = (const float4*)(scores + ((size_t)b * NMS_C + c) * NMS_N);
    const float4* boxes_b = (const float4*)(boxes + (size_t)b * NMS_N * 4);

    // issue ALL 16 score loads first
    float4 av[16];
    #pragma unroll
    for (int u = 0; u < 16; ++u) av[u] = sc4[u * NTHREADS + tid];
    __builtin_amdgcn_sched_barrier(0);

    const float score_thr = p_sthr[0];
    const float iou_thr   = p_iou[0];
    int maxo = p_maxout[0];
    if (maxo > NMS_MAX_OUT) maxo = NMS_MAX_OUT;
    if (maxo < 0) maxo = 0;

    int*       out32 = (int*)out_raw       + (size_t)bc * NMS_MAX_OUT * 3;
    long long* out64 = (long long*)out_raw + (size_t)bc * NMS_MAX_OUT * 3;
    for (int i = tid; i < NMS_MAX_OUT * 3; i += NTHREADS) {
        if (OUT64) out64[i] = -1LL; else out32[i] = -1;
    }

    if (tid == 0) { s_cnt = 0; s_total = 0; }
    __syncthreads();

    // ---- phase A: consume in-flight scores, compact candidates ----
    int local_total = 0;
    #pragma unroll
    for (int u = 0; u < 16; ++u) {
        const int i = u * NTHREADS + tid;
        float ss[4] = {av[u].x, av[u].y, av[u].z, av[u].w};
        #pragma unroll
        for (int j = 0; j < 4; ++j) {
            float s = ss[j];
            bool cand = (s > score_thr);
            local_total += cand ? 1 : 0;
            if (cand && s >= OPT_THR) {      // rare (~1.2%)
                int n = i * 4 + j;
                int p = atomicAdd(&s_cnt, 1);
                if (p < FCAP) {
                    skey[p] = ((u64)__float_as_uint(s) << 32)
                            | ((u64)(NMS_N - 1 - n) << 18);
                }
            }
        }
    }
    atomicAdd(&s_total, local_total);
    __syncthreads();                         // last block-wide barrier

    const int  cn  = s_cnt;
    const int  m   = (cn < FCAP) ? cn : FCAP;
    if (cn > FCAP) {                         // uniform block-wide bail
        if (tid == 0) flags[bc] = 1;
        return;
    }
    if (tid >= 64) return;                   // waves 1..3 retire here
    const int lane = tid;
    const int rem  = s_total - cn;           // candidates below optimistic cut

    // ---- phase B: register bitonic sort (desc), 256 elems, i = q*64+lane ----
    u64 v[WMAX];
    #pragma unroll
    for (int q = 0; q < WMAX; ++q) {
        const int idx = q * 64 + lane;
        v[q] = (idx < m) ? skey[idx] : 0ull;
    }

    // shfl compare-exchange at stride J with per-reg direction flags
    #define STAGE_SHFL(J, D0, D1, D2, D3) {                                       \
        const bool low_ = ((lane & (J)) == 0);                                    \
        { u64 o = __shfl_xor(v[0], (J), 64); bool d_ = (D0);                      \
          v[0] = (low_ == d_) ? umax64(v[0], o) : umin64(v[0], o); }              \
        { u64 o = __shfl_xor(v[1], (J), 64); bool d_ = (D1);                      \
          v[1] = (low_ == d_) ? umax64(v[1], o) : umin64(v[1], o); }              \
        { u64 o = __shfl_xor(v[2], (J), 64); bool d_ = (D2);                      \
          v[2] = (low_ == d_) ? umax64(v[2], o) : umin64(v[2], o); }              \
        { u64 o = __shfl_xor(v[3], (J), 64); bool d_ = (D3);                      \
          v[3] = (low_ == d_) ? umax64(v[3], o) : umin64(v[3], o); }              \
    }

    // k = 2..32: dir = (lane & k) == 0 for every reg
    #pragma unroll
    for (int k = 2; k <= 32; k <<= 1) {
        #pragma unroll
        for (int j = k >> 1; j > 0; j >>= 1) {
            const bool dd = ((lane & k) == 0);
            STAGE_SHFL(j, dd, dd, dd, dd);
        }
    }
    // k = 64: dir = ((q & 1) == 0)
    #pragma unroll
    for (int j = 32; j > 0; j >>= 1) STAGE_SHFL(j, true, false, true, false);
    // k = 128: j = 64 -> register pairs (0,1) dir=true, (2,3) dir=false
    { u64 a = v[0], bb = v[1]; v[0] = umax64(a, bb); v[1] = umin64(a, bb); }
    { u64 a = v[2], bb = v[3]; v[2] = umin64(a, bb); v[3] = umax64(a, bb); }
    //         j = 32..1: dir = ((q & 2) == 0)
    #pragma unroll
    for (int j = 32; j > 0; j >>= 1) STAGE_SHFL(j, true, true, false, false);
    // k = 256: j = 128 -> pairs (0,2),(1,3), dir=true
    { u64 a = v[0], bb = v[2]; v[0] = umax64(a, bb); v[2] = umin64(a, bb); }
    { u64 a = v[1], bb = v[3]; v[1] = umax64(a, bb); v[3] = umin64(a, bb); }
    //          j = 64 -> pairs (0,1),(2,3), dir=true
    { u64 a = v[0], bb = v[1]; v[0] = umax64(a, bb); v[1] = umin64(a, bb); }
    { u64 a = v[2], bb = v[3]; v[2] = umax64(a, bb); v[3] = umin64(a, bb); }
    //          j = 32..1: dir=true
    #pragma unroll
    for (int j = 32; j > 0; j >>= 1) STAGE_SHFL(j, true, true, true, true);
    #undef STAGE_SHFL

    // ---- phase C: gather boxes into column regs; publish n+box per rank ----
    // sorted layout v[q] (rank q*64+lane) == walk column layout bxc[q]
    float4 bxc[WMAX];
    float  areaBc[WMAX];
    #pragma unroll
    for (int q = 0; q < WMAX; ++q) {
        const int r = q * 64 + lane;
        const int n = NMS_N - 1 - (int)((v[q] >> 18) & 0x3FFFull);  // pad-safe
        sn[r] = n;
        float4 bb = boxes_b[n];
        bxc[q] = bb;
        sbox[r] = bb;
        areaBc[q] = __fmul_rn(__fsub_rn(bb.z, bb.x), __fsub_rn(bb.w, bb.y));
    }
    // single wave: in-order LDS, compiler inserts lgkmcnt before reads

    // ---- phase D: sorted walk, alive mask replicated in every lane ----
    u64 aliveW[WMAX];
    #pragma unroll
    for (int w2 = 0; w2 < WMAX; ++w2) {
        const int base = w2 * 64;
        aliveW[w2] = (m > base)
                   ? ((m - base >= 64) ? ~0ull : ((1ull << (m - base)) - 1ull))
                   : 0ull;
    }
    const int Wlim = (m + 63) >> 6;          // wave-uniform

    int need_slow = 0;
    for (int t = 0; t < maxo; ++t) {
        int w = WMAX; u64 cw = 0ull;
        #pragma unroll
        for (int q = WMAX - 1; q >= 0; --q)
            if (aliveW[q] != 0ull) { w = q; cw = aliveW[q]; }
        if (w == WMAX) {                     // exhausted
            if (rem > 0) need_slow = 1;
            break;
        }
        const int bit = __builtin_ctzll(cw);
        const int r   = w * 64 + bit;

        const int n = sn[r];                 // uniform -> broadcast
        if (lane == 0) {
            if (OUT64) {
                out64[t * 3 + 0] = (long long)b;
                out64[t * 3 + 1] = (long long)c;
                out64[t * 3 + 2] = (long long)n;
            } else {
                out32[t * 3 + 0] = b;
                out32[t * 3 + 1] = c;
                out32[t * 3 + 2] = n;
            }
        }
        const float4 A = sbox[r];            // uniform ds_read_b128
        const float areaA = __fmul_rn(__fsub_rn(A.z, A.x), __fsub_rn(A.w, A.y));

        #pragma unroll
        for (int w2 = 0; w2 < WMAX; ++w2) {
            if (w2 >= w && w2 < Wlim) {      // wave-uniform guards
                const bool sup = iou_pre(A, areaA, bxc[w2], areaBc[w2]) > iou_thr;
                u64 kill = __ballot(sup);
                if (w2 == w) kill |= (1ull << bit);   // self (zero-area safe)
                aliveW[w2] &= ~kill;
            }
        }
    }
    if (lane == 0) flags[bc] = need_slow;
}

// ---- slow exact fallback (verified round-2 structure, flag-gated) ----
__device__ __forceinline__ int bucketf(float s) {
    int v = (int)__float_as_uint(s) - 0x3F000000;
    v >>= 15;
    return v < 0 ? 0 : (v > 255 ? 255 : v);
}

template <bool OUT64>
__global__ __launch_bounds__(NTHREADS) void nms_slow(
    const float* __restrict__ boxes,
    const float* __restrict__ scores,
    const int* __restrict__ p_maxout,
    const float* __restrict__ p_iou,
    const float* __restrict__ p_sthr,
    void* __restrict__ out_raw,
    const int* __restrict__ flags)
{
    __shared__ int    hist[NBUCK];
    __shared__ u64    key[SCAP];
    __shared__ float4 cbox[SCAP];
    __shared__ float4 selbox[NMS_MAX_OUT];
    __shared__ u64    s_wmax[NTHREADS / 64];
    __shared__ u64    s_best;
    __shared__ int    s_cnt, s_cutLo, s_cutHi, s_rem, s_state;

    const int tid = threadIdx.x;
    const int bc  = blockIdx.x;
    if (flags && flags[bc] == 0) return;     // uniform exit before any barrier
    const int b   = bc / NMS_C;
    const int c   = bc % NMS_C;

    const float score_thr = p_sthr[0];
    const float iou_thr   = p_iou[0];
    int maxo = p_maxout[0];
    if (maxo > NMS_MAX_OUT) maxo = NMS_MAX_OUT;
    if (maxo < 0) maxo = 0;

    int*       out32 = (int*)out_raw       + (size_t)bc * NMS_MAX_OUT * 3;
    long long* out64 = (long long*)out_raw + (size_t)bc * NMS_MAX_OUT * 3;
    for (int i = tid; i < NMS_MAX_OUT * 3; i += NTHREADS) {
        if (OUT64) out64[i] = -1LL; else out32[i] = -1;
    }

    const float*  sc      = scores + ((size_t)b * NMS_C + c) * NMS_N;
    const float4* sc4     = (const float4*)sc;
    const float4* boxes_b = (const float4*)(boxes + (size_t)b * NMS_N * 4);

    for (int i = tid; i < NBUCK; i += NTHREADS) hist[i] = 0;
    if (tid == 0) s_cnt = 0;
    __syncthreads();
    for (int i = tid; i < NMS_N / 4; i += NTHREADS) {
        float4 s4 = sc4[i];
        float ss[4] = {s4.x, s4.y, s4.z, s4.w};
        #pragma unroll
        for (int j = 0; j < 4; ++j)
            if (ss[j] > score_thr) atomicAdd(&hist[bucketf(ss[j])], 1);
    }
    __syncthreads();

    if (tid == 0) {
        int cum = 0, cut = NBUCK;
        for (int bk = NBUCK - 1; bk >= 0; --bk) {
            int h = hist[bk];
            if (cum > 0 && cum + h > SCAP) break;
            cum += h; cut = bk;
            if (cum >= T_MIN) break;
        }
        s_cutLo = cut; s_cutHi = NBUCK - 1;
        int rem = 0;
        for (int bk = 0; bk < cut; ++bk) rem += hist[bk];
        s_rem = rem;
    }
    __syncthreads();

    auto compact = [&](int lo, int hi) {
        for (int i = tid; i < NMS_N / 4; i += NTHREADS) {
            float4 s4 = sc4[i];
            float ss[4] = {s4.x, s4.y, s4.z, s4.w};
            #pragma unroll
            for (int j = 0; j < 4; ++j) {
                float s = ss[j];
                if (s > score_thr) {
                    int bk = bucketf(s);
                    if (bk >= lo && bk <= hi) {
                        int n = i * 4 + j;
                        int p = atomicAdd(&s_cnt, 1);
                        if (p < SCAP) {
                            key[p] = ((u64)__float_as_uint(s) << 24)
                                   | ((u64)(NMS_N - 1 - n) << 10)
                                   | (u64)p;
                            cbox[p] = boxes_b[n];
                        }
                    }
                }
            }
        }
    };
    compact(s_cutLo, s_cutHi);
    __syncthreads();

    int t = 0;
    while (t < maxo) {
        int m = s_cnt; if (m > SCAP) m = SCAP;
        u64 lmax = 0ull;
        for (int i = tid; i < m; i += NTHREADS) {
            u64 k = key[i];
            if (k > lmax) lmax = k;
        }
        #pragma unroll
        for (int off = 32; off > 0; off >>= 1) {
            u64 o = __shfl_down(lmax, off);
            if (o > lmax) lmax = o;
        }
        if ((tid & 63) == 0) s_wmax[tid >> 6] = lmax;
        __syncthreads();
        if (tid == 0) {
            u64 best = s_wmax[0];
            #pragma unroll
            for (int w = 1; w < NTHREADS / 64; ++w)
                if (s_wmax[w] > best) best = s_wmax[w];
            s_best = best;
            if (best) {
                int slot = (int)(best & 0x3FFull);
                int n    = NMS_N - 1 - (int)((best >> 10) & 0x3FFFull);
                key[slot] = 0ull;
                if (OUT64) {
                    out64[t * 3 + 0] = (long long)b;
                    out64[t * 3 + 1] = (long long)c;
                    out64[t * 3 + 2] = (long long)n;
                } else {
                    out32[t * 3 + 0] = b;
                    out32[t * 3 + 1] = c;
                    out32[t * 3 + 2] = n;
                }
                selbox[t] = cbox[slot];
                s_state = 0;
            } else if (s_rem == 0) {
                s_state = 2;
            } else {
                int hiB = s_cutLo - 1;
                int cum = 0, cut = hiB + 1;
                for (int bk = hiB; bk >= 0; --bk) {
                    int h = hist[bk];
                    if (cum > 0 && cum + h > SCAP) break;
                    cum += h; cut = bk;
                    if (cum >= T_MIN) break;
                }
                s_cutLo = cut; s_cutHi = hiB;
                int rem = 0;
                for (int bk = 0; bk < cut; ++bk) rem += hist[bk];
                s_rem = rem;
                s_cnt = 0;
                s_state = 1;
            }
        }
        __syncthreads();

        if (s_state == 2) break;

        if (s_state == 0) {
            const float4 A = selbox[t];
            const float areaA = __fmul_rn(__fsub_rn(A.z, A.x), __fsub_rn(A.w, A.y));
            int m0 = s_cnt; if (m0 > SCAP) m0 = SCAP;
            for (int i = tid; i < m0; i += NTHREADS) {
                u64 k = key[i];
                if (!k) continue;
                if (iou_exact(A, areaA, cbox[i]) > iou_thr) key[i] = 0ull;
            }
            __syncthreads();
            ++t;
        } else {
            compact(s_cutLo, s_cutHi);
            __syncthreads();
            int m2 = s_cnt; if (m2 > SCAP) m2 = SCAP;
            for (int i = tid; i < m2; i += NTHREADS) {
                u64 k = key[i];
                if (!k) continue;
                float4 Bx = cbox[i];
                for (int j = 0; j < t; ++j) {
                    float4 A = selbox[j];
                    float areaA = __fmul_rn(__fsub_rn(A.z, A.x), __fsub_rn(A.w, A.y));
                    if (iou_exact(A, areaA, Bx) > iou_thr) { key[i] = 0ull; break; }
                }
            }
            __syncthreads();
        }
    }
}

extern "C" void kernel_launch(void* const* d_in, const int* in_sizes, int n_in,
                              void* d_out, int out_size, void* d_ws, size_t ws_size,
                              hipStream_t stream) {
    const float* boxes  = (const float*)d_in[0];
    const float* scores = (const float*)d_in[1];
    const int*   p_maxo = (const int*)d_in[2];
    const float* p_iou  = (const float*)d_in[3];
    const float* p_sthr = (const float*)d_in[4];

    const dim3 grid(NLANES);
    const dim3 block(NTHREADS);
    const bool out64 = (out_size == NLANES * NMS_MAX_OUT * 3 * 2);

    int* flags = (ws_size >= (size_t)NLANES * sizeof(int)) ? (int*)d_ws : nullptr;

    if (flags) {
        if (out64) {
            hipLaunchKernelGGL(nms_fast<true>, grid, block, 0, stream,
                               boxes, scores, p_maxo, p_iou, p_sthr, d_out, flags);
            hipLaunchKernelGGL(nms_slow<true>, grid, block, 0, stream,
                               boxes, scores, p_maxo, p_iou, p_sthr, d_out, flags);
        } else {
            hipLaunchKernelGGL(nms_fast<false>, grid, block, 0, stream,
                               boxes, scores, p_maxo, p_iou, p_sthr, d_out, flags);
            hipLaunchKernelGGL(nms_slow<false>, grid, block, 0, stream,
                               boxes, scores, p_maxo, p_iou, p_sthr, d_out, flags);
        }
    } else {
        if (out64) {
            hipLaunchKernelGGL(nms_slow<true>, grid, block, 0, stream,
                               boxes, scores, p_maxo, p_iou, p_sthr, d_out, (const int*)nullptr);
        } else {
            hipLaunchKernelGGL(nms_slow<false>, grid, block, 0, stream,
                               boxes, scores, p_maxo, p_iou, p_sthr, d_out, (const int*)nullptr);
        }
    }
}

// Round 13
// 54.865 us; speedup vs baseline: 3.6304x; 1.0382x over previous
//
#include <hip/hip_runtime.h>
#include <stdint.h>

// ONNX NonMaxSuppression: B=8, N=16384, C=80, MAX_OUT=50
// Split pipeline, zero cross-block atomics:
//   nms_scan: 4 blocks per (b,c), each streams 4096 scores (4 float4/thread,
//             one latency exposure), compacts candidates >= OPT_THR into LDS,
//             then writes a PRIVATE key segment + non-atomic count/total.
//   nms_sortwalk: 1 block per (b,c): prefix-sum 4 counts, 4 waves copy their
//             segment to LDS, wave 0 runs register bitonic sort (r12-proven,
//             0 bank conflicts) + box gather + ballot walk.
//   nms_slow: gated exact fallback (segment/FCAP overflow or
//             exhaustion-with-remainder). flags always written -> no memset.
// Fallbacks: monolithic r12 kernel (ws >= 2560B), else slow-for-all.

#define NMS_B 8
#define NMS_N 16384
#define NMS_C 80
#define NMS_MAX_OUT 50
#define NTHREADS 256
#define NLANES (NMS_B * NMS_C)

#define OPT_THR 0.98828125f  // = 1 - 192/16384 exactly; E[cnt]=192, sigma~13.8
#define FCAP 256
#define WMAX (FCAP / 64)     // 4 alive words / 4 regs per lane
#define SPLIT 4
#define SEG 120              // per-part capacity: E=48, sigma~6.9 -> +10 sigma
#define SCAN_N (NMS_N / SPLIT)

// slow (fallback) kernel
#define NBUCK 256
#define SCAP 1024
#define T_MIN 320

typedef unsigned long long u64;

// ws layout
#define WS_FLAGS  0
#define WS_CNTS   (NLANES * 4)
#define WS_TOTALS (WS_CNTS + NLANES * SPLIT * 4)
#define WS_KEYS   (WS_TOTALS + NLANES * SPLIT * 4)
#define WS_NEED   ((size_t)WS_KEYS + (size_t)NLANES * SPLIT * SEG * 8)

__device__ __forceinline__ float iou_exact(float4 A, float areaA, float4 Bx) {
    float x1 = fmaxf(A.x, Bx.x);
    float y1 = fmaxf(A.y, Bx.y);
    float x2 = fminf(A.z, Bx.z);
    float y2 = fminf(A.w, Bx.w);
    float dx = fmaxf(__fsub_rn(x2, x1), 0.0f);
    float dy = fmaxf(__fsub_rn(y2, y1), 0.0f);
    if (!(dx > 0.0f && dy > 0.0f)) return 0.0f;   // inter==0 -> iou==0 exactly
    float inter = __fmul_rn(dx, dy);
    float areaB = __fmul_rn(__fsub_rn(Bx.z, Bx.x), __fsub_rn(Bx.w, Bx.y));
    float uni   = __fsub_rn(__fadd_rn(areaA, areaB), inter);
    return __fdiv_rn(inter, fmaxf(uni, 1e-9f));
}

__device__ __forceinline__ float iou_pre(float4 A, float areaA, float4 Bx, float areaB) {
    float x1 = fmaxf(A.x, Bx.x);
    float y1 = fmaxf(A.y, Bx.y);
    float x2 = fminf(A.z, Bx.z);
    float y2 = fminf(A.w, Bx.w);
    float dx = fmaxf(__fsub_rn(x2, x1), 0.0f);
    float dy = fmaxf(__fsub_rn(y2, y1), 0.0f);
    if (!(dx > 0.0f && dy > 0.0f)) return 0.0f;
    float inter = __fmul_rn(dx, dy);
    float uni   = __fsub_rn(__fadd_rn(areaA, areaB), inter);
    return __fdiv_rn(inter, fmaxf(uni, 1e-9f));
}

__device__ __forceinline__ u64 umax64(u64 a, u64 b) { return a > b ? a : b; }
__device__ __forceinline__ u64 umin64(u64 a, u64 b) { return a < b ? a : b; }

// ---------------- phase 1: contention-free parallel scan ----------------
__global__ __launch_bounds__(NTHREADS) void nms_scan(
    const float* __restrict__ scores,
    const float* __restrict__ p_sthr,
    int* __restrict__ cnts,
    int* __restrict__ totals,
    u64* __restrict__ keys)
{
    __shared__ u64 lkey[SEG];
    __shared__ int lcnt, ltot;

    const int bid  = blockIdx.x;
    const int bc   = bid / SPLIT;
    const int part = bid % SPLIT;
    const int tid  = threadIdx.x;

    const float4* sc4 = (const float4*)(scores + (size_t)bc * NMS_N + part * SCAN_N);
    float4 av[4];
    #pragma unroll
    for (int u = 0; u < 4; ++u) av[u] = sc4[u * NTHREADS + tid];
    __builtin_amdgcn_sched_barrier(0);       // all 4 loads in flight

    if (tid == 0) { lcnt = 0; ltot = 0; }
    __syncthreads();

    const float sthr = p_sthr[0];
    int lt = 0;
    #pragma unroll
    for (int u = 0; u < 4; ++u) {
        const int i = u * NTHREADS + tid;
        float ss[4] = {av[u].x, av[u].y, av[u].z, av[u].w};
        #pragma unroll
        for (int j = 0; j < 4; ++j) {
            float s = ss[j];
            bool cand = (s > sthr);
            lt += cand ? 1 : 0;
            if (cand && s >= OPT_THR) {      // rare
                int n = part * SCAN_N + i * 4 + j;
                int p = atomicAdd(&lcnt, 1);
                if (p < SEG)
                    lkey[p] = ((u64)__float_as_uint(s) << 32)
                            | ((u64)(NMS_N - 1 - n) << 18);
            }
        }
    }
    // wave-reduce totals, 4 LDS atomics instead of 256
    #pragma unroll
    for (int off = 32; off > 0; off >>= 1) lt += __shfl_down(lt, off, 64);
    if ((tid & 63) == 0) atomicAdd(&ltot, lt);
    __syncthreads();

    const int cnt = lcnt;
    if (tid == 0) {
        cnts[bc * SPLIT + part]   = cnt;     // may exceed SEG -> flagged later
        totals[bc * SPLIT + part] = ltot;
    }
    u64* kseg = keys + ((size_t)bc * SPLIT + part) * SEG;
    const int mm = (cnt < SEG) ? cnt : SEG;
    if (tid < mm) kseg[tid] = lkey[tid];     // mm <= 120 < 256: one step
}

// ---------------- phase 2: sort + walk (r12 core) ----------------
template <bool OUT64>
__global__ __launch_bounds__(NTHREADS) void nms_sortwalk(
    const float* __restrict__ boxes,
    const int* __restrict__ p_maxout,
    const float* __restrict__ p_iou,
    void* __restrict__ out_raw,
    int* __restrict__ flags,
    const int* __restrict__ cnts,
    const int* __restrict__ totals,
    const u64* __restrict__ keys)
{
    __shared__ u64    skey[FCAP];
    __shared__ int    sn_[FCAP];
    __shared__ float4 sbox[FCAP];
    __shared__ int    s_off[SPLIT + 1], s_tot, s_bad;

    const int tid = threadIdx.x;
    const int bc  = blockIdx.x;
    const int b   = bc / NMS_C;
    const int c   = bc % NMS_C;

    const float iou_thr = p_iou[0];
    int maxo = p_maxout[0];
    if (maxo > NMS_MAX_OUT) maxo = NMS_MAX_OUT;
    if (maxo < 0) maxo = 0;

    int*       out32 = (int*)out_raw       + (size_t)bc * NMS_MAX_OUT * 3;
    long long* out64 = (long long*)out_raw + (size_t)bc * NMS_MAX_OUT * 3;
    for (int i = tid; i < NMS_MAX_OUT * 3; i += NTHREADS) {
        if (OUT64) out64[i] = -1LL; else out32[i] = -1;
    }

    if (tid == 0) {
        int off = 0, bad = 0, tot = 0;
        #pragma unroll
        for (int p = 0; p < SPLIT; ++p) {
            s_off[p] = off;
            int cp = cnts[bc * SPLIT + p];
            bad |= (cp > SEG);
            off += cp;
            tot += totals[bc * SPLIT + p];
        }
        s_off[SPLIT] = off;
        bad |= (off > FCAP);
        s_bad = bad; s_tot = tot;
    }
    __syncthreads();
    if (s_bad) {                             // uniform bail to slow path
        if (tid == 0) flags[bc] = 1;
        return;
    }
    const int m = s_off[SPLIT];

    // wave p copies its segment into LDS
    {
        const int p = tid >> 6, l = tid & 63;
        const int o = s_off[p], cp = s_off[p + 1] - o;
        const u64* kseg = keys + ((size_t)bc * SPLIT + p) * SEG;
        for (int i = l; i < cp; i += 64) skey[o + i] = kseg[i];
    }
    __syncthreads();

    if (tid >= 64) return;                   // waves 1..3 retire
    const int lane = tid;
    const int rem  = s_tot - m;

    // ---- register bitonic sort (desc), 256 elems, i = q*64+lane ----
    u64 v[WMAX];
    #pragma unroll
    for (int q = 0; q < WMAX; ++q) {
        const int idx = q * 64 + lane;
        v[q] = (idx < m) ? skey[idx] : 0ull;
    }

    #define STAGE_SHFL(J, D0, D1, D2, D3) {                                       \
        const bool low_ = ((lane & (J)) == 0);                                    \
        { u64 o = __shfl_xor(v[0], (J), 64); bool d_ = (D0);                      \
          v[0] = (low_ == d_) ? umax64(v[0], o) : umin64(v[0], o); }              \
        { u64 o = __shfl_xor(v[1], (J), 64); bool d_ = (D1);                      \
          v[1] = (low_ == d_) ? umax64(v[1], o) : umin64(v[1], o); }              \
        { u64 o = __shfl_xor(v[2], (J), 64); bool d_ = (D2);                      \
          v[2] = (low_ == d_) ? umax64(v[2], o) : umin64(v[2], o); }              \
        { u64 o = __shfl_xor(v[3], (J), 64); bool d_ = (D3);                      \
          v[3] = (low_ == d_) ? umax64(v[3], o) : umin64(v[3], o); }              \
    }

    #pragma unroll
    for (int k = 2; k <= 32; k <<= 1) {
        #pragma unroll
        for (int j = k >> 1; j > 0; j >>= 1) {
            const bool dd = ((lane & k) == 0);
            STAGE_SHFL(j, dd, dd, dd, dd);
        }
    }
    #pragma unroll
    for (int j = 32; j > 0; j >>= 1) STAGE_SHFL(j, true, false, true, false);
    { u64 a = v[0], bb = v[1]; v[0] = umax64(a, bb); v[1] = umin64(a, bb); }
    { u64 a = v[2], bb = v[3]; v[2] = umin64(a, bb); v[3] = umax64(a, bb); }
    #pragma unroll
    for (int j = 32; j > 0; j >>= 1) STAGE_SHFL(j, true, true, false, false);
    { u64 a = v[0], bb = v[2]; v[0] = umax64(a, bb); v[2] = umin64(a, bb); }
    { u64 a = v[1], bb = v[3]; v[1] = umax64(a, bb); v[3] = umin64(a, bb); }
    { u64 a = v[0], bb = v[1]; v[0] = umax64(a, bb); v[1] = umin64(a, bb); }
    { u64 a = v[2], bb = v[3]; v[2] = umax64(a, bb); v[3] = umin64(a, bb); }
    #pragma unroll
    for (int j = 32; j > 0; j >>= 1) STAGE_SHFL(j, true, true, true, true);
    #undef STAGE_SHFL

    // ---- gather boxes into column regs; publish n+box per rank ----
    const float4* boxes_b = (const float4*)(boxes + (size_t)b * NMS_N * 4);
    float4 bxc[WMAX];
    float  areaBc[WMAX];
    #pragma unroll
    for (int q = 0; q < WMAX; ++q) {
        const int r = q * 64 + lane;
        const int n = NMS_N - 1 - (int)((v[q] >> 18) & 0x3FFFull);  // pad-safe
        sn_[r] = n;
        float4 bb = boxes_b[n];
        bxc[q] = bb;
        sbox[r] = bb;
        areaBc[q] = __fmul_rn(__fsub_rn(bb.z, bb.x), __fsub_rn(bb.w, bb.y));
    }
    // single wave: in-order LDS

    // ---- sorted walk ----
    u64 aliveW[WMAX];
    #pragma unroll
    for (int w2 = 0; w2 < WMAX; ++w2) {
        const int base = w2 * 64;
        aliveW[w2] = (m > base)
                   ? ((m - base >= 64) ? ~0ull : ((1ull << (m - base)) - 1ull))
                   : 0ull;
    }
    const int Wlim = (m + 63) >> 6;          // wave-uniform

    int need_slow = 0;
    for (int t = 0; t < maxo; ++t) {
        int w = WMAX; u64 cw = 0ull;
        #pragma unroll
        for (int q = WMAX - 1; q >= 0; --q)
            if (aliveW[q] != 0ull) { w = q; cw = aliveW[q]; }
        if (w == WMAX) {
            if (rem > 0) need_slow = 1;
            break;
        }
        const int bit = __builtin_ctzll(cw);
        const int r   = w * 64 + bit;

        const int n = sn_[r];                // uniform -> broadcast
        if (lane == 0) {
            if (OUT64) {
                out64[t * 3 + 0] = (long long)b;
                out64[t * 3 + 1] = (long long)c;
                out64[t * 3 + 2] = (long long)n;
            } else {
                out32[t * 3 + 0] = b;
                out32[t * 3 + 1] = c;
                out32[t * 3 + 2] = n;
            }
        }
        const float4 A = sbox[r];            // uniform ds_read_b128
        const float areaA = __fmul_rn(__fsub_rn(A.z, A.x), __fsub_rn(A.w, A.y));

        #pragma unroll
        for (int w2 = 0; w2 < WMAX; ++w2) {
            if (w2 >= w && w2 < Wlim) {
                const bool sup = iou_pre(A, areaA, bxc[w2], areaBc[w2]) > iou_thr;
                u64 kill = __ballot(sup);
                if (w2 == w) kill |= (1ull << bit);
                aliveW[w2] &= ~kill;
            }
        }
    }
    if (lane == 0) flags[bc] = need_slow;
}

// ---------------- monolithic r12 fallback (mid-ws) ----------------
template <bool OUT64>
__global__ __launch_bounds__(NTHREADS, 4) void nms_fast_mono(
    const float* __restrict__ boxes,
    const float* __restrict__ scores,
    const int* __restrict__ p_maxout,
    const float* __restrict__ p_iou,
    const float* __restrict__ p_sthr,
    void* __restrict__ out_raw,
    int* __restrict__ flags)
{
    __shared__ u64    skey[FCAP];
    __shared__ int    sn_[FCAP];
    __shared__ float4 sbox[FCAP];
    __shared__ int    s_cnt, s_total;

    const int tid = threadIdx.x;
    const int bc  = blockIdx.x;
    const int b   = bc / NMS_C;
    const int c   = bc % NMS_C;

    const float4* sc4     = (const float4*)(scores + ((size_t)b * NMS_C + c) * NMS_N);
    const float4* boxes_b = (const float4*)(boxes + (size_t)b * NMS_N * 4);

    float4 av[16];
    #pragma unroll
    for (int u = 0; u < 16; ++u) av[u] = sc4[u * NTHREADS + tid];
    __builtin_amdgcn_sched_barrier(0);

    const float score_thr = p_sthr[0];
    const float iou_thr   = p_iou[0];
    int maxo = p_maxout[0];
    if (maxo > NMS_MAX_OUT) maxo = NMS_MAX_OUT;
    if (maxo < 0) maxo = 0;

    int*       out32 = (int*)out_raw       + (size_t)bc * NMS_MAX_OUT * 3;
    long long* out64 = (long long*)out_raw + (size_t)bc * NMS_MAX_OUT * 3;
    for (int i = tid; i < NMS_MAX_OUT * 3; i += NTHREADS) {
        if (OUT64) out64[i] = -1LL; else out32[i] = -1;
    }

    if (tid == 0) { s_cnt = 0; s_total = 0; }
    __syncthreads();

    int local_total = 0;
    #pragma unroll
    for (int u = 0; u < 16; ++u) {
        const int i = u * NTHREADS + tid;
        float ss[4] = {av[u].x, av[u].y, av[u].z, av[u].w};
        #pragma unroll
        for (int j = 0; j < 4; ++j) {
            float s = ss[j];
            bool cand = (s > score_thr);
            local_total += cand ? 1 : 0;
            if (cand && s >= OPT_THR) {
                int n = i * 4 + j;
                int p = atomicAdd(&s_cnt, 1);
                if (p < FCAP) {
                    skey[p] = ((u64)__float_as_uint(s) << 32)
                            | ((u64)(NMS_N - 1 - n) << 18);
                }
            }
        }
    }
    atomicAdd(&s_total, local_total);
    __syncthreads();

    const int cn = s_cnt;
    const int m  = (cn < FCAP) ? cn : FCAP;
    if (cn > FCAP) {
        if (tid == 0) flags[bc] = 1;
        return;
    }
    if (tid >= 64) return;
    const int lane = tid;
    const int rem  = s_total - cn;

    u64 v[WMAX];
    #pragma unroll
    for (int q = 0; q < WMAX; ++q) {
        const int idx = q * 64 + lane;
        v[q] = (idx < m) ? skey[idx] : 0ull;
    }

    #define STAGE_SHFL(J, D0, D1, D2, D3) {                                       \
        const bool low_ = ((lane & (J)) == 0);                                    \
        { u64 o = __shfl_xor(v[0], (J), 64); bool d_ = (D0);                      \
          v[0] = (low_ == d_) ? umax64(v[0], o) : umin64(v[0], o); }              \
        { u64 o = __shfl_xor(v[1], (J), 64); bool d_ = (D1);                      \
          v[1] = (low_ == d_) ? umax64(v[1], o) : umin64(v[1], o); }              \
        { u64 o = __shfl_xor(v[2], (J), 64); bool d_ = (D2);                      \
          v[2] = (low_ == d_) ? umax64(v[2], o) : umin64(v[2], o); }              \
        { u64 o = __shfl_xor(v[3], (J), 64); bool d_ = (D3);                      \
          v[3] = (low_ == d_) ? umax64(v[3], o) : umin64(v[3], o); }              \
    }

    #pragma unroll
    for (int k = 2; k <= 32; k <<= 1) {
        #pragma unroll
        for (int j = k >> 1; j > 0; j >>= 1) {
            const bool dd = ((lane & k) == 0);
            STAGE_SHFL(j, dd, dd, dd, dd);
        }
    }
    #pragma unroll
    for (int j = 32; j > 0; j >>= 1) STAGE_SHFL(j, true, false, true, false);
    { u64 a = v[0], bb = v[1]; v[0] = umax64(a, bb); v[1] = umin64(a, bb); }
    { u64 a = v[2], bb = v[3]; v[2] = umin64(a, bb); v[3] = umax64(a, bb); }
    #pragma unroll
    for (int j = 32; j > 0; j >>= 1) STAGE_SHFL(j, true, true, false, false);
    { u64 a = v[0], bb = v[2]; v[0] = umax64(a, bb); v[2] = umin64(a, bb); }
    { u64 a = v[1], bb = v[3]; v[1] = umax64(a, bb); v[3] = umax64(a, bb) == v[1] ? umin64(a, bb) : umin64(a, bb); }
    { u64 a = v[0], bb = v[1]; v[0] = umax64(a, bb); v[1] = umin64(a, bb); }
    { u64 a = v[2], bb = v[3]; v[2] = umax64(a, bb); v[3] = umin64(a, bb); }
    #pragma unroll
    for (int j = 32; j > 0; j >>= 1) STAGE_SHFL(j, true, true, true, true);
    #undef STAGE_SHFL

    float4 bxc[WMAX];
    float  areaBc[WMAX];
    #pragma unroll
    for (int q = 0; q < WMAX; ++q) {
        const int r = q * 64 + lane;
        const int n = NMS_N - 1 - (int)((v[q] >> 18) & 0x3FFFull);
        sn_[r] = n;
        float4 bb = boxes_b[n];
        bxc[q] = bb;
        sbox[r] = bb;
        areaBc[q] = __fmul_rn(__fsub_rn(bb.z, bb.x), __fsub_rn(bb.w, bb.y));
    }

    u64 aliveW[WMAX];
    #pragma unroll
    for (int w2 = 0; w2 < WMAX; ++w2) {
        const int base = w2 * 64;
        aliveW[w2] = (m > base)
                   ? ((m - base >= 64) ? ~0ull : ((1ull << (m - base)) - 1ull))
                   : 0ull;
    }
    const int Wlim = (m + 63) >> 6;

    int need_slow = 0;
    for (int t = 0; t < maxo; ++t) {
        int w = WMAX; u64 cw = 0ull;
        #pragma unroll
        for (int q = WMAX - 1; q >= 0; --q)
            if (aliveW[q] != 0ull) { w = q; cw = aliveW[q]; }
        if (w == WMAX) {
            if (rem > 0) need_slow = 1;
            break;
        }
        const int bit = __builtin_ctzll(cw);
        const int r   = w * 64 + bit;
        const int n = sn_[r];
        if (lane == 0) {
            if (OUT64) {
                out64[t * 3 + 0] = (long long)b;
                out64[t * 3 + 1] = (long long)c;
                out64[t * 3 + 2] = (long long)n;
            } else {
                out32[t * 3 + 0] = b;
                out32[t * 3 + 1] = c;
                out32[t * 3 + 2] = n;
            }
        }
        const float4 A = sbox[r];
        const float areaA = __fmul_rn(__fsub_rn(A.z, A.x), __fsub_rn(A.w, A.y));
        #pragma unroll
        for (int w2 = 0; w2 < WMAX; ++w2) {
            if (w2 >= w && w2 < Wlim) {
                const bool sup = iou_pre(A, areaA, bxc[w2], areaBc[w2]) > iou_thr;
                u64 kill = __ballot(sup);
                if (w2 == w) kill |= (1ull << bit);
                aliveW[w2] &= ~kill;
            }
        }
    }
    if (lane == 0) flags[bc] = need_slow;
}

// ---- slow exact fallback (verified round-2 structure, flag-gated) ----
__device__ __forceinline__ int bucketf(float s) {
    int v = (int)__float_as_uint(s) - 0x3F000000;
    v >>= 15;
    return v < 0 ? 0 : (v > 255 ? 255 : v);
}

template <bool OUT64>
__global__ __launch_bounds__(NTHREADS) void nms_slow(
    const float* __restrict__ boxes,
    const float* __restrict__ scores,
    const int* __restrict__ p_maxout,
    const float* __restrict__ p_iou,
    const float* __restrict__ p_sthr,
    void* __restrict__ out_raw,
    const int* __restrict__ flags)
{
    __shared__ int    hist[NBUCK];
    __shared__ u64    key[SCAP];
    __shared__ float4 cbox[SCAP];
    __shared__ float4 selbox[NMS_MAX_OUT];
    __shared__ u64    s_wmax[NTHREADS / 64];
    __shared__ u64    s_best;
    __shared__ int    s_cnt, s_cutLo, s_cutHi, s_rem, s_state;

    const int tid = threadIdx.x;
    const int bc  = blockIdx.x;
    if (flags && flags[bc] == 0) return;
    const int b   = bc / NMS_C;
    const int c   = bc % NMS_C;

    const float score_thr = p_sthr[0];
    const float iou_thr   = p_iou[0];
    int maxo = p_maxout[0];
    if (maxo > NMS_MAX_OUT) maxo = NMS_MAX_OUT;
    if (maxo < 0) maxo = 0;

    int*       out32 = (int*)out_raw       + (size_t)bc * NMS_MAX_OUT * 3;
    long long* out64 = (long long*)out_raw + (size_t)bc * NMS_MAX_OUT * 3;
    for (int i = tid; i < NMS_MAX_OUT * 3; i += NTHREADS) {
        if (OUT64) out64[i] = -1LL; else out32[i] = -1;
    }

    const float*  sc      = scores + ((size_t)b * NMS_C + c) * NMS_N;
    const float4* sc4     = (const float4*)sc;
    const float4* boxes_b = (const float4*)(boxes + (size_t)b * NMS_N * 4);

    for (int i = tid; i < NBUCK; i += NTHREADS) hist[i] = 0;
    if (tid == 0) s_cnt = 0;
    __syncthreads();
    for (int i = tid; i < NMS_N / 4; i += NTHREADS) {
        float4 s4 = sc4[i];
        float ss[4] = {s4.x, s4.y, s4.z, s4.w};
        #pragma unroll
        for (int j = 0; j < 4; ++j)
            if (ss[j] > score_thr) atomicAdd(&hist[bucketf(ss[j])], 1);
    }
    __syncthreads();

    if (tid == 0) {
        int cum = 0, cut = NBUCK;
        for (int bk = NBUCK - 1; bk >= 0; --bk) {
            int h = hist[bk];
            if (cum > 0 && cum + h > SCAP) break;
            cum += h; cut = bk;
            if (cum >= T_MIN) break;
        }
        s_cutLo = cut; s_cutHi = NBUCK - 1;
        int rem = 0;
        for (int bk = 0; bk < cut; ++bk) rem += hist[bk];
        s_rem = rem;
    }
    __syncthreads();

    auto compact = [&](int lo, int hi) {
        for (int i = tid; i < NMS_N / 4; i += NTHREADS) {
            float4 s4 = sc4[i];
            float ss[4] = {s4.x, s4.y, s4.z, s4.w};
            #pragma unroll
            for (int j = 0; j < 4; ++j) {
                float s = ss[j];
                if (s > score_thr) {
                    int bk = bucketf(s);
                    if (bk >= lo && bk <= hi) {
                        int n = i * 4 + j;
                        int p = atomicAdd(&s_cnt, 1);
                        if (p < SCAP) {
                            key[p] = ((u64)__float_as_uint(s) << 24)
                                   | ((u64)(NMS_N - 1 - n) << 10)
                                   | (u64)p;
                            cbox[p] = boxes_b[n];
                        }
                    }
                }
            }
        }
    };
    compact(s_cutLo, s_cutHi);
    __syncthreads();

    int t = 0;
    while (t < maxo) {
        int m = s_cnt; if (m > SCAP) m = SCAP;
        u64 lmax = 0ull;
        for (int i = tid; i < m; i += NTHREADS) {
            u64 k = key[i];
            if (k > lmax) lmax = k;
        }
        #pragma unroll
        for (int off = 32; off > 0; off >>= 1) {
            u64 o = __shfl_down(lmax, off);
            if (o > lmax) lmax = o;
        }
        if ((tid & 63) == 0) s_wmax[tid >> 6] = lmax;
        __syncthreads();
        if (tid == 0) {
            u64 best = s_wmax[0];
            #pragma unroll
            for (int w = 1; w < NTHREADS / 64; ++w)
                if (s_wmax[w] > best) best = s_wmax[w];
            s_best = best;
            if (best) {
                int slot = (int)(best & 0x3FFull);
                int n    = NMS_N - 1 - (int)((best >> 10) & 0x3FFFull);
                key[slot] = 0ull;
                if (OUT64) {
                    out64[t * 3 + 0] = (long long)b;
                    out64[t * 3 + 1] = (long long)c;
                    out64[t * 3 + 2] = (long long)n;
                } else {
                    out32[t * 3 + 0] = b;
                    out32[t * 3 + 1] = c;
                    out32[t * 3 + 2] = n;
                }
                selbox[t] = cbox[slot];
                s_state = 0;
            } else if (s_rem == 0) {
                s_state = 2;
            } else {
                int hiB = s_cutLo - 1;
                int cum = 0, cut = hiB + 1;
                for (int bk = hiB; bk >= 0; --bk) {
                    int h = hist[bk];
                    if (cum > 0 && cum + h > SCAP) break;
                    cum += h; cut = bk;
                    if (cum >= T_MIN) break;
                }
                s_cutLo = cut; s_cutHi = hiB;
                int rem = 0;
                for (int bk = 0; bk < cut; ++bk) rem += hist[bk];
                s_rem = rem;
                s_cnt = 0;
                s_state = 1;
            }
        }
        __syncthreads();

        if (s_state == 2) break;

        if (s_state == 0) {
            const float4 A = selbox[t];
            const float areaA = __fmul_rn(__fsub_rn(A.z, A.x), __fsub_rn(A.w, A.y));
            int m0 = s_cnt; if (m0 > SCAP) m0 = SCAP;
            for (int i = tid; i < m0; i += NTHREADS) {
                u64 k = key[i];
                if (!k) continue;
                if (iou_exact(A, areaA, cbox[i]) > iou_thr) key[i] = 0ull;
            }
            __syncthreads();
            ++t;
        } else {
            compact(s_cutLo, s_cutHi);
            __syncthreads();
            int m2 = s_cnt; if (m2 > SCAP) m2 = SCAP;
            for (int i = tid; i < m2; i += NTHREADS) {
                u64 k = key[i];
                if (!k) continue;
                float4 Bx = cbox[i];
                for (int j = 0; j < t; ++j) {
                    float4 A = selbox[j];
                    float areaA = __fmul_rn(__fsub_rn(A.z, A.x), __fsub_rn(A.w, A.y));
                    if (iou_exact(A, areaA, Bx) > iou_thr) { key[i] = 0ull; break; }
                }
            }
            __syncthreads();
        }
    }
}

extern "C" void kernel_launch(void* const* d_in, const int* in_sizes, int n_in,
                              void* d_out, int out_size, void* d_ws, size_t ws_size,
                              hipStream_t stream) {
    const float* boxes  = (const float*)d_in[0];
    const float* scores = (const float*)d_in[1];
    const int*   p_maxo = (const int*)d_in[2];
    const float* p_iou  = (const float*)d_in[3];
    const float* p_sthr = (const float*)d_in[4];

    const dim3 block(NTHREADS);
    const bool out64 = (out_size == NLANES * NMS_MAX_OUT * 3 * 2);

    char* ws = (char*)d_ws;
    int*  flags  = (int*)(ws + WS_FLAGS);
    int*  cnts   = (int*)(ws + WS_CNTS);
    int*  totals = (int*)(ws + WS_TOTALS);
    u64*  keys   = (u64*)(ws + WS_KEYS);

    if (ws_size >= WS_NEED) {
        hipLaunchKernelGGL(nms_scan, dim3(NLANES * SPLIT), block, 0, stream,
                           scores, p_sthr, cnts, totals, keys);
        if (out64) {
            hipLaunchKernelGGL(nms_sortwalk<true>, dim3(NLANES), block, 0, stream,
                               boxes, p_maxo, p_iou, d_out, flags, cnts, totals, keys);
            hipLaunchKernelGGL(nms_slow<true>, dim3(NLANES), block, 0, stream,
                               boxes, scores, p_maxo, p_iou, p_sthr, d_out, flags);
        } else {
            hipLaunchKernelGGL(nms_sortwalk<false>, dim3(NLANES), block, 0, stream,
                               boxes, p_maxo, p_iou, d_out, flags, cnts, totals, keys);
            hipLaunchKernelGGL(nms_slow<false>, dim3(NLANES), block, 0, stream,
                               boxes, scores, p_maxo, p_iou, p_sthr, d_out, flags);
        }
    } else if (ws_size >= (size_t)NLANES * sizeof(int)) {
        if (out64) {
            hipLaunchKernelGGL(nms_fast_mono<true>, dim3(NLANES), block, 0, stream,
                               boxes, scores, p_maxo, p_iou, p_sthr, d_out, flags);
            hipLaunchKernelGGL(nms_slow<true>, dim3(NLANES), block, 0, stream,
                               boxes, scores, p_maxo, p_iou, p_sthr, d_out, flags);
        } else {
            hipLaunchKernelGGL(nms_fast_mono<false>, dim3(NLANES), block, 0, stream,
                               boxes, scores, p_maxo, p_iou, p_sthr, d_out, flags);
            hipLaunchKernelGGL(nms_slow<false>, dim3(NLANES), block, 0, stream,
                               boxes, scores, p_maxo, p_iou, p_sthr, d_out, flags);
        }
    } else {
        if (out64) {
            hipLaunchKernelGGL(nms_slow<true>, dim3(NLANES), block, 0, stream,
                               boxes, scores, p_maxo, p_iou, p_sthr, d_out, (const int*)nullptr);
        } else {
            hipLaunchKernelGGL(nms_slow<false>, dim3(NLANES), block, 0, stream,
                               boxes, scores, p_maxo, p_iou, p_sthr, d_out, (const int*)nullptr);
        }
    }
}

// Round 14
// 39.898 us; speedup vs baseline: 4.9922x; 1.3751x over previous
//
#include <hip/hip_runtime.h>
#include <stdint.h>

// ONNX NonMaxSuppression: B=8, N=16384, C=80, MAX_OUT=50
// Split pipeline, zero cross-block atomics:
//   nms_scan: 4 blocks per (b,c) stream scores, compact candidates >= OPT_THR
//             into private ws segments + non-atomic count/total.
//   nms_sortwalk: 1 block per (b,c): prefix-sum counts, copy segments, wave 0
//             register-bitonic-sorts 256 keys (0 barriers, 0 bank conflicts),
//             gathers boxes by rank, then runs the LAZY sorted walk:
//             lane l holds pick-l's box; cursor walks ranks in order; one
//             IoU/lane + one ballot per examined candidate; ballot==0 -> pick.
//             Lazy == eager greedy NMS on a sorted list (standard identity).
//             sbox[r+1] prefetched under the current IoU (LDS off the chain).
//   nms_slow: gated exact fallback (segment/FCAP overflow or
//             exhaustion-with-remainder). flags always written -> no memset.
// Fallbacks: monolithic kernel (ws >= 2560B), else slow-for-all.

#define NMS_B 8
#define NMS_N 16384
#define NMS_C 80
#define NMS_MAX_OUT 50
#define NTHREADS 256
#define NLANES (NMS_B * NMS_C)

#define OPT_THR 0.98828125f  // = 1 - 192/16384 exactly; E[cnt]=192, sigma~13.8
#define FCAP 256
#define WMAX (FCAP / 64)     // 4 regs per lane in the register sort
#define SPLIT 4
#define SEG 120              // per-part capacity: E=48, sigma~6.9 -> +10 sigma
#define SCAN_N (NMS_N / SPLIT)

// slow (fallback) kernel
#define NBUCK 256
#define SCAP 1024
#define T_MIN 320

typedef unsigned long long u64;

// ws layout
#define WS_FLAGS  0
#define WS_CNTS   (NLANES * 4)
#define WS_TOTALS (WS_CNTS + NLANES * SPLIT * 4)
#define WS_KEYS   (WS_TOTALS + NLANES * SPLIT * 4)
#define WS_NEED   ((size_t)WS_KEYS + (size_t)NLANES * SPLIT * SEG * 8)

__device__ __forceinline__ float iou_exact(float4 A, float areaA, float4 Bx) {
    float x1 = fmaxf(A.x, Bx.x);
    float y1 = fmaxf(A.y, Bx.y);
    float x2 = fminf(A.z, Bx.z);
    float y2 = fminf(A.w, Bx.w);
    float dx = fmaxf(__fsub_rn(x2, x1), 0.0f);
    float dy = fmaxf(__fsub_rn(y2, y1), 0.0f);
    if (!(dx > 0.0f && dy > 0.0f)) return 0.0f;   // inter==0 -> iou==0 exactly
    float inter = __fmul_rn(dx, dy);
    float areaB = __fmul_rn(__fsub_rn(Bx.z, Bx.x), __fsub_rn(Bx.w, Bx.y));
    float uni   = __fsub_rn(__fadd_rn(areaA, areaB), inter);
    return __fdiv_rn(inter, fmaxf(uni, 1e-9f));
}

__device__ __forceinline__ float iou_pre(float4 A, float areaA, float4 Bx, float areaB) {
    float x1 = fmaxf(A.x, Bx.x);
    float y1 = fmaxf(A.y, Bx.y);
    float x2 = fminf(A.z, Bx.z);
    float y2 = fminf(A.w, Bx.w);
    float dx = fmaxf(__fsub_rn(x2, x1), 0.0f);
    float dy = fmaxf(__fsub_rn(y2, y1), 0.0f);
    if (!(dx > 0.0f && dy > 0.0f)) return 0.0f;
    float inter = __fmul_rn(dx, dy);
    float uni   = __fsub_rn(__fadd_rn(areaA, areaB), inter);
    return __fdiv_rn(inter, fmaxf(uni, 1e-9f));
}

__device__ __forceinline__ u64 umax64(u64 a, u64 b) { return a > b ? a : b; }
__device__ __forceinline__ u64 umin64(u64 a, u64 b) { return a < b ? a : b; }

// ---------------- phase 1: contention-free parallel scan ----------------
__global__ __launch_bounds__(NTHREADS) void nms_scan(
    const float* __restrict__ scores,
    const float* __restrict__ p_sthr,
    int* __restrict__ cnts,
    int* __restrict__ totals,
    u64* __restrict__ keys)
{
    __shared__ u64 lkey[SEG];
    __shared__ int lcnt, ltot;

    const int bid  = blockIdx.x;
    const int bc   = bid / SPLIT;
    const int part = bid % SPLIT;
    const int tid  = threadIdx.x;

    const float4* sc4 = (const float4*)(scores + (size_t)bc * NMS_N + part * SCAN_N);
    float4 av[4];
    #pragma unroll
    for (int u = 0; u < 4; ++u) av[u] = sc4[u * NTHREADS + tid];
    __builtin_amdgcn_sched_barrier(0);       // all 4 loads in flight

    if (tid == 0) { lcnt = 0; ltot = 0; }
    __syncthreads();

    const float sthr = p_sthr[0];
    int lt = 0;
    #pragma unroll
    for (int u = 0; u < 4; ++u) {
        const int i = u * NTHREADS + tid;
        float ss[4] = {av[u].x, av[u].y, av[u].z, av[u].w};
        #pragma unroll
        for (int j = 0; j < 4; ++j) {
            float s = ss[j];
            bool cand = (s > sthr);
            lt += cand ? 1 : 0;
            if (cand && s >= OPT_THR) {      // rare
                int n = part * SCAN_N + i * 4 + j;
                int p = atomicAdd(&lcnt, 1);
                if (p < SEG)
                    lkey[p] = ((u64)__float_as_uint(s) << 32)
                            | ((u64)(NMS_N - 1 - n) << 18);
            }
        }
    }
    // wave-reduce totals, 4 LDS atomics instead of 256
    #pragma unroll
    for (int off = 32; off > 0; off >>= 1) lt += __shfl_down(lt, off, 64);
    if ((tid & 63) == 0) atomicAdd(&ltot, lt);
    __syncthreads();

    const int cnt = lcnt;
    if (tid == 0) {
        cnts[bc * SPLIT + part]   = cnt;     // may exceed SEG -> flagged later
        totals[bc * SPLIT + part] = ltot;
    }
    u64* kseg = keys + ((size_t)bc * SPLIT + part) * SEG;
    const int mm = (cnt < SEG) ? cnt : SEG;
    if (tid < mm) kseg[tid] = lkey[tid];
}

// ---------------- phase 2: sort + LAZY walk ----------------
template <bool OUT64>
__global__ __launch_bounds__(NTHREADS) void nms_sortwalk(
    const float* __restrict__ boxes,
    const int* __restrict__ p_maxout,
    const float* __restrict__ p_iou,
    void* __restrict__ out_raw,
    int* __restrict__ flags,
    const int* __restrict__ cnts,
    const int* __restrict__ totals,
    const u64* __restrict__ keys)
{
    __shared__ u64    skey[FCAP];
    __shared__ int    sn_[FCAP];
    __shared__ float4 sbox[FCAP];
    __shared__ int    s_off[SPLIT + 1], s_tot, s_bad;

    const int tid = threadIdx.x;
    const int bc  = blockIdx.x;
    const int b   = bc / NMS_C;
    const int c   = bc % NMS_C;

    const float iou_thr = p_iou[0];
    int maxo = p_maxout[0];
    if (maxo > NMS_MAX_OUT) maxo = NMS_MAX_OUT;
    if (maxo < 0) maxo = 0;

    int*       out32 = (int*)out_raw       + (size_t)bc * NMS_MAX_OUT * 3;
    long long* out64 = (long long*)out_raw + (size_t)bc * NMS_MAX_OUT * 3;
    for (int i = tid; i < NMS_MAX_OUT * 3; i += NTHREADS) {
        if (OUT64) out64[i] = -1LL; else out32[i] = -1;
    }

    if (tid == 0) {
        int off = 0, bad = 0, tot = 0;
        #pragma unroll
        for (int p = 0; p < SPLIT; ++p) {
            s_off[p] = off;
            int cp = cnts[bc * SPLIT + p];
            bad |= (cp > SEG);
            off += cp;
            tot += totals[bc * SPLIT + p];
        }
        s_off[SPLIT] = off;
        bad |= (off > FCAP);
        s_bad = bad; s_tot = tot;
    }
    __syncthreads();
    if (s_bad) {                             // uniform bail to slow path
        if (tid == 0) flags[bc] = 1;
        return;
    }
    const int m = s_off[SPLIT];

    // wave p copies its segment into LDS
    {
        const int p = tid >> 6, l = tid & 63;
        const int o = s_off[p], cp = s_off[p + 1] - o;
        const u64* kseg = keys + ((size_t)bc * SPLIT + p) * SEG;
        for (int i = l; i < cp; i += 64) skey[o + i] = kseg[i];
    }
    __syncthreads();

    if (tid >= 64) return;                   // waves 1..3 retire
    const int lane = tid;
    const int rem  = s_tot - m;

    // ---- register bitonic sort (desc), 256 elems, i = q*64+lane ----
    u64 v[WMAX];
    #pragma unroll
    for (int q = 0; q < WMAX; ++q) {
        const int idx = q * 64 + lane;
        v[q] = (idx < m) ? skey[idx] : 0ull;
    }

    #define STAGE_SHFL(J, D0, D1, D2, D3) {                                       \
        const bool low_ = ((lane & (J)) == 0);                                    \
        { u64 o = __shfl_xor(v[0], (J), 64); bool d_ = (D0);                      \
          v[0] = (low_ == d_) ? umax64(v[0], o) : umin64(v[0], o); }              \
        { u64 o = __shfl_xor(v[1], (J), 64); bool d_ = (D1);                      \
          v[1] = (low_ == d_) ? umax64(v[1], o) : umin64(v[1], o); }              \
        { u64 o = __shfl_xor(v[2], (J), 64); bool d_ = (D2);                      \
          v[2] = (low_ == d_) ? umax64(v[2], o) : umin64(v[2], o); }              \
        { u64 o = __shfl_xor(v[3], (J), 64); bool d_ = (D3);                      \
          v[3] = (low_ == d_) ? umax64(v[3], o) : umin64(v[3], o); }              \
    }

    #pragma unroll
    for (int k = 2; k <= 32; k <<= 1) {
        #pragma unroll
        for (int j = k >> 1; j > 0; j >>= 1) {
            const bool dd = ((lane & k) == 0);
            STAGE_SHFL(j, dd, dd, dd, dd);
        }
    }
    #pragma unroll
    for (int j = 32; j > 0; j >>= 1) STAGE_SHFL(j, true, false, true, false);
    { u64 a = v[0], bb = v[1]; v[0] = umax64(a, bb); v[1] = umin64(a, bb); }
    { u64 a = v[2], bb = v[3]; v[2] = umin64(a, bb); v[3] = umax64(a, bb); }
    #pragma unroll
    for (int j = 32; j > 0; j >>= 1) STAGE_SHFL(j, true, true, false, false);
    { u64 a = v[0], bb = v[2]; v[0] = umax64(a, bb); v[2] = umin64(a, bb); }
    { u64 a = v[1], bb = v[3]; v[1] = umax64(a, bb); v[3] = umin64(a, bb); }
    { u64 a = v[0], bb = v[1]; v[0] = umax64(a, bb); v[1] = umin64(a, bb); }
    { u64 a = v[2], bb = v[3]; v[2] = umax64(a, bb); v[3] = umin64(a, bb); }
    #pragma unroll
    for (int j = 32; j > 0; j >>= 1) STAGE_SHFL(j, true, true, true, true);
    #undef STAGE_SHFL

    // ---- gather boxes by rank; publish n + box per rank to LDS ----
    const float4* boxes_b = (const float4*)(boxes + (size_t)b * NMS_N * 4);
    #pragma unroll
    for (int q = 0; q < WMAX; ++q) {
        const int r = q * 64 + lane;
        const int n = NMS_N - 1 - (int)((v[q] >> 18) & 0x3FFFull);  // pad-safe
        sn_[r] = n;
        sbox[r] = boxes_b[n];
    }
    // single wave: per-wave LDS is in-order; no barrier needed

    // ---- LAZY sorted walk: lane l holds pick-l's box ----
    // sentinel (degenerate) sel for lanes >= t: IoU path yields dx=0 -> sup=false
    float selx = 1e30f, sely = 1e30f, selz = -1e30f, selw = -1e30f, sela = 0.0f;
    int t = 0, r = 0, need_slow = 0;
    float4 cand = (m > 0) ? sbox[0] : make_float4(0.f, 0.f, 0.f, 0.f);

    while (t < maxo && r < m) {
        const int rn = (r + 1 < FCAP) ? (r + 1) : r;
        const float4 nxt = sbox[rn];         // prefetch next rank under the IoU

        // candidate area (reference chain; identical in all lanes)
        const float areaC = __fmul_rn(__fsub_rn(cand.z, cand.x),
                                      __fsub_rn(cand.w, cand.y));
        // IoU(sel_lane, cand) — bit-exact reference order (sel first)
        float x1 = fmaxf(selx, cand.x);
        float y1 = fmaxf(sely, cand.y);
        float x2 = fminf(selz, cand.z);
        float y2 = fminf(selw, cand.w);
        float dx = fmaxf(__fsub_rn(x2, x1), 0.0f);
        float dy = fmaxf(__fsub_rn(y2, y1), 0.0f);
        bool sup = false;
        if (dx > 0.0f && dy > 0.0f) {        // inter==0 -> iou==0 exact skip
            float inter = __fmul_rn(dx, dy);
            float uni   = __fsub_rn(__fadd_rn(sela, areaC), inter);
            sup = __fdiv_rn(inter, fmaxf(uni, 1e-9f)) > iou_thr;
        }
        if (__ballot(sup) == 0ull) {         // no prior pick suppresses -> pick
            if (lane == 0) {
                const int n = sn_[r];
                if (OUT64) {
                    out64[t * 3 + 0] = (long long)b;
                    out64[t * 3 + 1] = (long long)c;
                    out64[t * 3 + 2] = (long long)n;
                } else {
                    out32[t * 3 + 0] = b;
                    out32[t * 3 + 1] = c;
                    out32[t * 3 + 2] = n;
                }
            }
            if (lane == t) {                 // latch pick-t into this lane
                selx = cand.x; sely = cand.y; selz = cand.z; selw = cand.w;
                sela = areaC;
            }
            ++t;
        }
        ++r;
        cand = nxt;
    }
    // exhausted the optimistic subset with picks left and lower cands remain?
    if (t < maxo && rem > 0) need_slow = 1;
    if (lane == 0) flags[bc] = need_slow;
}

// ---------------- monolithic fallback (mid-ws; r13-verified path) ----------------
template <bool OUT64>
__global__ __launch_bounds__(NTHREADS, 4) void nms_fast_mono(
    const float* __restrict__ boxes,
    const float* __restrict__ scores,
    const int* __restrict__ p_maxout,
    const float* __restrict__ p_iou,
    const float* __restrict__ p_sthr,
    void* __restrict__ out_raw,
    int* __restrict__ flags)
{
    __shared__ u64    skey[FCAP];
    __shared__ int    sn_[FCAP];
    __shared__ float4 sbox[FCAP];
    __shared__ int    s_cnt, s_total;

    const int tid = threadIdx.x;
    const int bc  = blockIdx.x;
    const int b   = bc / NMS_C;
    const int c   = bc % NMS_C;

    const float4* sc4     = (const float4*)(scores + ((size_t)b * NMS_C + c) * NMS_N);
    const float4* boxes_b = (const float4*)(boxes + (size_t)b * NMS_N * 4);

    float4 av[16];
    #pragma unroll
    for (int u = 0; u < 16; ++u) av[u] = sc4[u * NTHREADS + tid];
    __builtin_amdgcn_sched_barrier(0);

    const float score_thr = p_sthr[0];
    const float iou_thr   = p_iou[0];
    int maxo = p_maxout[0];
    if (maxo > NMS_MAX_OUT) maxo = NMS_MAX_OUT;
    if (maxo < 0) maxo = 0;

    int*       out32 = (int*)out_raw       + (size_t)bc * NMS_MAX_OUT * 3;
    long long* out64 = (long long*)out_raw + (size_t)bc * NMS_MAX_OUT * 3;
    for (int i = tid; i < NMS_MAX_OUT * 3; i += NTHREADS) {
        if (OUT64) out64[i] = -1LL; else out32[i] = -1;
    }

    if (tid == 0) { s_cnt = 0; s_total = 0; }
    __syncthreads();

    int local_total = 0;
    #pragma unroll
    for (int u = 0; u < 16; ++u) {
        const int i = u * NTHREADS + tid;
        float ss[4] = {av[u].x, av[u].y, av[u].z, av[u].w};
        #pragma unroll
        for (int j = 0; j < 4; ++j) {
            float s = ss[j];
            bool cand = (s > score_thr);
            local_total += cand ? 1 : 0;
            if (cand && s >= OPT_THR) {
                int n = i * 4 + j;
                int p = atomicAdd(&s_cnt, 1);
                if (p < FCAP) {
                    skey[p] = ((u64)__float_as_uint(s) << 32)
                            | ((u64)(NMS_N - 1 - n) << 18);
                }
            }
        }
    }
    atomicAdd(&s_total, local_total);
    __syncthreads();

    const int cn = s_cnt;
    const int m  = (cn < FCAP) ? cn : FCAP;
    if (cn > FCAP) {
        if (tid == 0) flags[bc] = 1;
        return;
    }
    if (tid >= 64) return;
    const int lane = tid;
    const int rem  = s_total - cn;

    u64 v[WMAX];
    #pragma unroll
    for (int q = 0; q < WMAX; ++q) {
        const int idx = q * 64 + lane;
        v[q] = (idx < m) ? skey[idx] : 0ull;
    }

    #define STAGE_SHFL(J, D0, D1, D2, D3) {                                       \
        const bool low_ = ((lane & (J)) == 0);                                    \
        { u64 o = __shfl_xor(v[0], (J), 64); bool d_ = (D0);                      \
          v[0] = (low_ == d_) ? umax64(v[0], o) : umin64(v[0], o); }              \
        { u64 o = __shfl_xor(v[1], (J), 64); bool d_ = (D1);                      \
          v[1] = (low_ == d_) ? umax64(v[1], o) : umin64(v[1], o); }              \
        { u64 o = __shfl_xor(v[2], (J), 64); bool d_ = (D2);                      \
          v[2] = (low_ == d_) ? umax64(v[2], o) : umin64(v[2], o); }              \
        { u64 o = __shfl_xor(v[3], (J), 64); bool d_ = (D3);                      \
          v[3] = (low_ == d_) ? umax64(v[3], o) : umin64(v[3], o); }              \
    }

    #pragma unroll
    for (int k = 2; k <= 32; k <<= 1) {
        #pragma unroll
        for (int j = k >> 1; j > 0; j >>= 1) {
            const bool dd = ((lane & k) == 0);
            STAGE_SHFL(j, dd, dd, dd, dd);
        }
    }
    #pragma unroll
    for (int j = 32; j > 0; j >>= 1) STAGE_SHFL(j, true, false, true, false);
    { u64 a = v[0], bb = v[1]; v[0] = umax64(a, bb); v[1] = umin64(a, bb); }
    { u64 a = v[2], bb = v[3]; v[2] = umin64(a, bb); v[3] = umax64(a, bb); }
    #pragma unroll
    for (int j = 32; j > 0; j >>= 1) STAGE_SHFL(j, true, true, false, false);
    { u64 a = v[0], bb = v[2]; v[0] = umax64(a, bb); v[2] = umin64(a, bb); }
    { u64 a = v[1], bb = v[3]; v[1] = umax64(a, bb); v[3] = umin64(a, bb); }
    { u64 a = v[0], bb = v[1]; v[0] = umax64(a, bb); v[1] = umin64(a, bb); }
    { u64 a = v[2], bb = v[3]; v[2] = umax64(a, bb); v[3] = umin64(a, bb); }
    #pragma unroll
    for (int j = 32; j > 0; j >>= 1) STAGE_SHFL(j, true, true, true, true);
    #undef STAGE_SHFL

    #pragma unroll
    for (int q = 0; q < WMAX; ++q) {
        const int r = q * 64 + lane;
        const int n = NMS_N - 1 - (int)((v[q] >> 18) & 0x3FFFull);
        sn_[r] = n;
        sbox[r] = boxes_b[n];
    }

    // lazy walk (same as nms_sortwalk)
    float selx = 1e30f, sely = 1e30f, selz = -1e30f, selw = -1e30f, sela = 0.0f;
    int t = 0, r = 0, need_slow = 0;
    float4 cand = (m > 0) ? sbox[0] : make_float4(0.f, 0.f, 0.f, 0.f);

    while (t < maxo && r < m) {
        const int rn = (r + 1 < FCAP) ? (r + 1) : r;
        const float4 nxt = sbox[rn];
        const float areaC = __fmul_rn(__fsub_rn(cand.z, cand.x),
                                      __fsub_rn(cand.w, cand.y));
        float x1 = fmaxf(selx, cand.x);
        float y1 = fmaxf(sely, cand.y);
        float x2 = fminf(selz, cand.z);
        float y2 = fminf(selw, cand.w);
        float dx = fmaxf(__fsub_rn(x2, x1), 0.0f);
        float dy = fmaxf(__fsub_rn(y2, y1), 0.0f);
        bool sup = false;
        if (dx > 0.0f && dy > 0.0f) {
            float inter = __fmul_rn(dx, dy);
            float uni   = __fsub_rn(__fadd_rn(sela, areaC), inter);
            sup = __fdiv_rn(inter, fmaxf(uni, 1e-9f)) > iou_thr;
        }
        if (__ballot(sup) == 0ull) {
            if (lane == 0) {
                const int n = sn_[r];
                if (OUT64) {
                    out64[t * 3 + 0] = (long long)b;
                    out64[t * 3 + 1] = (long long)c;
                    out64[t * 3 + 2] = (long long)n;
                } else {
                    out32[t * 3 + 0] = b;
                    out32[t * 3 + 1] = c;
                    out32[t * 3 + 2] = n;
                }
            }
            if (lane == t) {
                selx = cand.x; sely = cand.y; selz = cand.z; selw = cand.w;
                sela = areaC;
            }
            ++t;
        }
        ++r;
        cand = nxt;
    }
    if (t < maxo && rem > 0) need_slow = 1;
    if (lane == 0) flags[bc] = need_slow;
}

// ---- slow exact fallback (verified round-2 structure, flag-gated) ----
__device__ __forceinline__ int bucketf(float s) {
    int v = (int)__float_as_uint(s) - 0x3F000000;
    v >>= 15;
    return v < 0 ? 0 : (v > 255 ? 255 : v);
}

template <bool OUT64>
__global__ __launch_bounds__(NTHREADS) void nms_slow(
    const float* __restrict__ boxes,
    const float* __restrict__ scores,
    const int* __restrict__ p_maxout,
    const float* __restrict__ p_iou,
    const float* __restrict__ p_sthr,
    void* __restrict__ out_raw,
    const int* __restrict__ flags)
{
    __shared__ int    hist[NBUCK];
    __shared__ u64    key[SCAP];
    __shared__ float4 cbox[SCAP];
    __shared__ float4 selbox[NMS_MAX_OUT];
    __shared__ u64    s_wmax[NTHREADS / 64];
    __shared__ u64    s_best;
    __shared__ int    s_cnt, s_cutLo, s_cutHi, s_rem, s_state;

    const int tid = threadIdx.x;
    const int bc  = blockIdx.x;
    if (flags && flags[bc] == 0) return;
    const int b   = bc / NMS_C;
    const int c   = bc % NMS_C;

    const float score_thr = p_sthr[0];
    const float iou_thr   = p_iou[0];
    int maxo = p_maxout[0];
    if (maxo > NMS_MAX_OUT) maxo = NMS_MAX_OUT;
    if (maxo < 0) maxo = 0;

    int*       out32 = (int*)out_raw       + (size_t)bc * NMS_MAX_OUT * 3;
    long long* out64 = (long long*)out_raw + (size_t)bc * NMS_MAX_OUT * 3;
    for (int i = tid; i < NMS_MAX_OUT * 3; i += NTHREADS) {
        if (OUT64) out64[i] = -1LL; else out32[i] = -1;
    }

    const float*  sc      = scores + ((size_t)b * NMS_C + c) * NMS_N;
    const float4* sc4     = (const float4*)sc;
    const float4* boxes_b = (const float4*)(boxes + (size_t)b * NMS_N * 4);

    for (int i = tid; i < NBUCK; i += NTHREADS) hist[i] = 0;
    if (tid == 0) s_cnt = 0;
    __syncthreads();
    for (int i = tid; i < NMS_N / 4; i += NTHREADS) {
        float4 s4 = sc4[i];
        float ss[4] = {s4.x, s4.y, s4.z, s4.w};
        #pragma unroll
        for (int j = 0; j < 4; ++j)
            if (ss[j] > score_thr) atomicAdd(&hist[bucketf(ss[j])], 1);
    }
    __syncthreads();

    if (tid == 0) {
        int cum = 0, cut = NBUCK;
        for (int bk = NBUCK - 1; bk >= 0; --bk) {
            int h = hist[bk];
            if (cum > 0 && cum + h > SCAP) break;
            cum += h; cut = bk;
            if (cum >= T_MIN) break;
        }
        s_cutLo = cut; s_cutHi = NBUCK - 1;
        int rem = 0;
        for (int bk = 0; bk < cut; ++bk) rem += hist[bk];
        s_rem = rem;
    }
    __syncthreads();

    auto compact = [&](int lo, int hi) {
        for (int i = tid; i < NMS_N / 4; i += NTHREADS) {
            float4 s4 = sc4[i];
            float ss[4] = {s4.x, s4.y, s4.z, s4.w};
            #pragma unroll
            for (int j = 0; j < 4; ++j) {
                float s = ss[j];
                if (s > score_thr) {
                    int bk = bucketf(s);
                    if (bk >= lo && bk <= hi) {
                        int n = i * 4 + j;
                        int p = atomicAdd(&s_cnt, 1);
                        if (p < SCAP) {
                            key[p] = ((u64)__float_as_uint(s) << 24)
                                   | ((u64)(NMS_N - 1 - n) << 10)
                                   | (u64)p;
                            cbox[p] = boxes_b[n];
                        }
                    }
                }
            }
        }
    };
    compact(s_cutLo, s_cutHi);
    __syncthreads();

    int t = 0;
    while (t < maxo) {
        int m = s_cnt; if (m > SCAP) m = SCAP;
        u64 lmax = 0ull;
        for (int i = tid; i < m; i += NTHREADS) {
            u64 k = key[i];
            if (k > lmax) lmax = k;
        }
        #pragma unroll
        for (int off = 32; off > 0; off >>= 1) {
            u64 o = __shfl_down(lmax, off);
            if (o > lmax) lmax = o;
        }
        if ((tid & 63) == 0) s_wmax[tid >> 6] = lmax;
        __syncthreads();
        if (tid == 0) {
            u64 best = s_wmax[0];
            #pragma unroll
            for (int w = 1; w < NTHREADS / 64; ++w)
                if (s_wmax[w] > best) best = s_wmax[w];
            s_best = best;
            if (best) {
                int slot = (int)(best & 0x3FFull);
                int n    = NMS_N - 1 - (int)((best >> 10) & 0x3FFFull);
                key[slot] = 0ull;
                if (OUT64) {
                    out64[t * 3 + 0] = (long long)b;
                    out64[t * 3 + 1] = (long long)c;
                    out64[t * 3 + 2] = (long long)n;
                } else {
                    out32[t * 3 + 0] = b;
                    out32[t * 3 + 1] = c;
                    out32[t * 3 + 2] = n;
                }
                selbox[t] = cbox[slot];
                s_state = 0;
            } else if (s_rem == 0) {
                s_state = 2;
            } else {
                int hiB = s_cutLo - 1;
                int cum = 0, cut = hiB + 1;
                for (int bk = hiB; bk >= 0; --bk) {
                    int h = hist[bk];
                    if (cum > 0 && cum + h > SCAP) break;
                    cum += h; cut = bk;
                    if (cum >= T_MIN) break;
                }
                s_cutLo = cut; s_cutHi = hiB;
                int rem = 0;
                for (int bk = 0; bk < cut; ++bk) rem += hist[bk];
                s_rem = rem;
                s_cnt = 0;
                s_state = 1;
            }
        }
        __syncthreads();

        if (s_state == 2) break;

        if (s_state == 0) {
            const float4 A = selbox[t];
            const float areaA = __fmul_rn(__fsub_rn(A.z, A.x), __fsub_rn(A.w, A.y));
            int m0 = s_cnt; if (m0 > SCAP) m0 = SCAP;
            for (int i = tid; i < m0; i += NTHREADS) {
                u64 k = key[i];
                if (!k) continue;
                if (iou_exact(A, areaA, cbox[i]) > iou_thr) key[i] = 0ull;
            }
            __syncthreads();
            ++t;
        } else {
            compact(s_cutLo, s_cutHi);
            __syncthreads();
            int m2 = s_cnt; if (m2 > SCAP) m2 = SCAP;
            for (int i = tid; i < m2; i += NTHREADS) {
                u64 k = key[i];
                if (!k) continue;
                float4 Bx = cbox[i];
                for (int j = 0; j < t; ++j) {
                    float4 A = selbox[j];
                    float areaA = __fmul_rn(__fsub_rn(A.z, A.x), __fsub_rn(A.w, A.y));
                    if (iou_exact(A, areaA, Bx) > iou_thr) { key[i] = 0ull; break; }
                }
            }
            __syncthreads();
        }
    }
}

extern "C" void kernel_launch(void* const* d_in, const int* in_sizes, int n_in,
                              void* d_out, int out_size, void* d_ws, size_t ws_size,
                              hipStream_t stream) {
    const float* boxes  = (const float*)d_in[0];
    const float* scores = (const float*)d_in[1];
    const int*   p_maxo = (const int*)d_in[2];
    const float* p_iou  = (const float*)d_in[3];
    const float* p_sthr = (const float*)d_in[4];

    const dim3 block(NTHREADS);
    const bool out64 = (out_size == NLANES * NMS_MAX_OUT * 3 * 2);

    char* ws = (char*)d_ws;
    int*  flags  = (int*)(ws + WS_FLAGS);
    int*  cnts   = (int*)(ws + WS_CNTS);
    int*  totals = (int*)(ws + WS_TOTALS);
    u64*  keys   = (u64*)(ws + WS_KEYS);

    if (ws_size >= WS_NEED) {
        hipLaunchKernelGGL(nms_scan, dim3(NLANES * SPLIT), block, 0, stream,
                           scores, p_sthr, cnts, totals, keys);
        if (out64) {
            hipLaunchKernelGGL(nms_sortwalk<true>, dim3(NLANES), block, 0, stream,
                               boxes, p_maxo, p_iou, d_out, flags, cnts, totals, keys);
            hipLaunchKernelGGL(nms_slow<true>, dim3(NLANES), block, 0, stream,
                               boxes, scores, p_maxo, p_iou, p_sthr, d_out, flags);
        } else {
            hipLaunchKernelGGL(nms_sortwalk<false>, dim3(NLANES), block, 0, stream,
                               boxes, p_maxo, p_iou, d_out, flags, cnts, totals, keys);
            hipLaunchKernelGGL(nms_slow<false>, dim3(NLANES), block, 0, stream,
                               boxes, scores, p_maxo, p_iou, p_sthr, d_out, flags);
        }
    } else if (ws_size >= (size_t)NLANES * sizeof(int)) {
        if (out64) {
            hipLaunchKernelGGL(nms_fast_mono<true>, dim3(NLANES), block, 0, stream,
                               boxes, scores, p_maxo, p_iou, p_sthr, d_out, flags);
            hipLaunchKernelGGL(nms_slow<true>, dim3(NLANES), block, 0, stream,
                               boxes, scores, p_maxo, p_iou, p_sthr, d_out, flags);
        } else {
            hipLaunchKernelGGL(nms_fast_mono<false>, dim3(NLANES), block, 0, stream,
                               boxes, scores, p_maxo, p_iou, p_sthr, d_out, flags);
            hipLaunchKernelGGL(nms_slow<false>, dim3(NLANES), block, 0, stream,
                               boxes, scores, p_maxo, p_iou, p_sthr, d_out, flags);
        }
    } else {
        if (out64) {
            hipLaunchKernelGGL(nms_slow<true>, dim3(NLANES), block, 0, stream,
                               boxes, scores, p_maxo, p_iou, p_sthr, d_out, (const int*)nullptr);
        } else {
            hipLaunchKernelGGL(nms_slow<false>, dim3(NLANES), block, 0, stream,
                               boxes, scores, p_maxo, p_iou, p_sthr, d_out, (const int*)nullptr);
        }
    }
}

// Round 15
// 39.756 us; speedup vs baseline: 5.0100x; 1.0036x over previous
//
#include <hip/hip_runtime.h>
#include <stdint.h>

// ONNX NonMaxSuppression: B=8, N=16384, C=80, MAX_OUT=50
// Split pipeline, zero cross-block atomics:
//   nms_scan: 4 blocks per (b,c) stream scores, compact candidates >= OPT_THR
//             into private ws segments + non-atomic count/total.
//   nms_sortwalk (64-thread single-wave, ZERO barriers): all lanes read the
//             4 counts/totals (uniform broadcast); keys load straight
//             global->register via prefix-sum part-select; register bitonic
//             sort; box gather; LAZY sorted walk (lane l holds pick-l's box,
//             one IoU + one ballot per examined rank; ballot==0 -> pick).
//             Lazy == eager greedy NMS on a sorted list (standard identity).
//   nms_slow: gated exact fallback (segment/FCAP overflow or
//             exhaustion-with-remainder). flags always written -> no memset.
// Fallbacks: monolithic kernel (ws >= 2560B), else slow-for-all.

#define NMS_B 8
#define NMS_N 16384
#define NMS_C 80
#define NMS_MAX_OUT 50
#define NTHREADS 256
#define NLANES (NMS_B * NMS_C)

#define OPT_THR 0.98828125f  // = 1 - 192/16384 exactly; E[cnt]=192, sigma~13.8
#define FCAP 256
#define WMAX (FCAP / 64)     // 4 regs per lane in the register sort
#define SPLIT 4
#define SEG 120              // per-part capacity: E=48, sigma~6.9 -> +10 sigma
#define SCAN_N (NMS_N / SPLIT)

// slow (fallback) kernel
#define NBUCK 256
#define SCAP 1024
#define T_MIN 320

typedef unsigned long long u64;

// ws layout
#define WS_FLAGS  0
#define WS_CNTS   (NLANES * 4)
#define WS_TOTALS (WS_CNTS + NLANES * SPLIT * 4)
#define WS_KEYS   (WS_TOTALS + NLANES * SPLIT * 4)
#define WS_NEED   ((size_t)WS_KEYS + (size_t)NLANES * SPLIT * SEG * 8)

__device__ __forceinline__ float iou_exact(float4 A, float areaA, float4 Bx) {
    float x1 = fmaxf(A.x, Bx.x);
    float y1 = fmaxf(A.y, Bx.y);
    float x2 = fminf(A.z, Bx.z);
    float y2 = fminf(A.w, Bx.w);
    float dx = fmaxf(__fsub_rn(x2, x1), 0.0f);
    float dy = fmaxf(__fsub_rn(y2, y1), 0.0f);
    if (!(dx > 0.0f && dy > 0.0f)) return 0.0f;   // inter==0 -> iou==0 exactly
    float inter = __fmul_rn(dx, dy);
    float areaB = __fmul_rn(__fsub_rn(Bx.z, Bx.x), __fsub_rn(Bx.w, Bx.y));
    float uni   = __fsub_rn(__fadd_rn(areaA, areaB), inter);
    return __fdiv_rn(inter, fmaxf(uni, 1e-9f));
}

__device__ __forceinline__ u64 umax64(u64 a, u64 b) { return a > b ? a : b; }
__device__ __forceinline__ u64 umin64(u64 a, u64 b) { return a < b ? a : b; }

// ---------------- phase 1: contention-free parallel scan ----------------
__global__ __launch_bounds__(NTHREADS) void nms_scan(
    const float* __restrict__ scores,
    const float* __restrict__ p_sthr,
    int* __restrict__ cnts,
    int* __restrict__ totals,
    u64* __restrict__ keys)
{
    __shared__ u64 lkey[SEG];
    __shared__ int lcnt, ltot;

    const int bid  = blockIdx.x;
    const int bc   = bid / SPLIT;
    const int part = bid % SPLIT;
    const int tid  = threadIdx.x;

    const float4* sc4 = (const float4*)(scores + (size_t)bc * NMS_N + part * SCAN_N);
    float4 av[4];
    #pragma unroll
    for (int u = 0; u < 4; ++u) av[u] = sc4[u * NTHREADS + tid];
    __builtin_amdgcn_sched_barrier(0);       // all 4 loads in flight

    if (tid == 0) { lcnt = 0; ltot = 0; }
    __syncthreads();

    const float sthr = p_sthr[0];
    int lt = 0;
    #pragma unroll
    for (int u = 0; u < 4; ++u) {
        const int i = u * NTHREADS + tid;
        float ss[4] = {av[u].x, av[u].y, av[u].z, av[u].w};
        #pragma unroll
        for (int j = 0; j < 4; ++j) {
            float s = ss[j];
            bool cand = (s > sthr);
            lt += cand ? 1 : 0;
            if (cand && s >= OPT_THR) {      // rare
                int n = part * SCAN_N + i * 4 + j;
                int p = atomicAdd(&lcnt, 1);
                if (p < SEG)
                    lkey[p] = ((u64)__float_as_uint(s) << 32)
                            | ((u64)(NMS_N - 1 - n) << 18);
            }
        }
    }
    // wave-reduce totals, 4 LDS atomics instead of 256
    #pragma unroll
    for (int off = 32; off > 0; off >>= 1) lt += __shfl_down(lt, off, 64);
    if ((tid & 63) == 0) atomicAdd(&ltot, lt);
    __syncthreads();

    const int cnt = lcnt;
    if (tid == 0) {
        cnts[bc * SPLIT + part]   = cnt;     // may exceed SEG -> flagged later
        totals[bc * SPLIT + part] = ltot;
    }
    u64* kseg = keys + ((size_t)bc * SPLIT + part) * SEG;
    const int mm = (cnt < SEG) ? cnt : SEG;
    if (tid < mm) kseg[tid] = lkey[tid];
}

// ---------------- phase 2: single-wave sort + LAZY walk ----------------
template <bool OUT64>
__global__ __launch_bounds__(64) void nms_sortwalk(
    const float* __restrict__ boxes,
    const int* __restrict__ p_maxout,
    const float* __restrict__ p_iou,
    void* __restrict__ out_raw,
    int* __restrict__ flags,
    const int* __restrict__ cnts,
    const int* __restrict__ totals,
    const u64* __restrict__ keys)
{
    __shared__ int    sn_[FCAP];
    __shared__ float4 sbox[FCAP];

    const int lane = threadIdx.x;
    const int bc   = blockIdx.x;
    const int b    = bc / NMS_C;
    const int c    = bc % NMS_C;

    const float iou_thr = p_iou[0];
    int maxo = p_maxout[0];
    if (maxo > NMS_MAX_OUT) maxo = NMS_MAX_OUT;
    if (maxo < 0) maxo = 0;

    int*       out32 = (int*)out_raw       + (size_t)bc * NMS_MAX_OUT * 3;
    long long* out64 = (long long*)out_raw + (size_t)bc * NMS_MAX_OUT * 3;
    #pragma unroll
    for (int i = lane; i < NMS_MAX_OUT * 3; i += 64) {
        if (OUT64) out64[i] = -1LL; else out32[i] = -1;
    }

    // uniform loads (same address across lanes -> broadcast)
    const int c0 = cnts[bc * SPLIT + 0], c1 = cnts[bc * SPLIT + 1];
    const int c2 = cnts[bc * SPLIT + 2], c3 = cnts[bc * SPLIT + 3];
    const int tt = totals[bc * SPLIT + 0] + totals[bc * SPLIT + 1]
                 + totals[bc * SPLIT + 2] + totals[bc * SPLIT + 3];
    const int o1 = c0, o2 = c0 + c1, o3 = c0 + c1 + c2;
    const int m  = o3 + c3;
    const bool bad = (c0 > SEG) | (c1 > SEG) | (c2 > SEG) | (c3 > SEG) | (m > FCAP);
    if (bad) {                               // uniform bail to slow path
        if (lane == 0) flags[bc] = 1;
        return;
    }
    const int rem = tt - m;

    // ---- keys straight global -> register (part-select per reg) ----
    const u64* kb = keys + (size_t)bc * SPLIT * SEG;
    u64 v[WMAX];
    #pragma unroll
    for (int q = 0; q < WMAX; ++q) {
        const int idx = q * 64 + lane;
        int p, base;
        if (idx < o1)      { p = 0; base = 0;  }
        else if (idx < o2) { p = 1; base = o1; }
        else if (idx < o3) { p = 2; base = o2; }
        else               { p = 3; base = o3; }
        v[q] = (idx < m) ? kb[(size_t)p * SEG + (idx - base)] : 0ull;
    }

    // ---- register bitonic sort (desc), 256 elems, i = q*64+lane ----
    #define STAGE_SHFL(J, D0, D1, D2, D3) {                                       \
        const bool low_ = ((lane & (J)) == 0);                                    \
        { u64 o = __shfl_xor(v[0], (J), 64); bool d_ = (D0);                      \
          v[0] = (low_ == d_) ? umax64(v[0], o) : umin64(v[0], o); }              \
        { u64 o = __shfl_xor(v[1], (J), 64); bool d_ = (D1);                      \
          v[1] = (low_ == d_) ? umax64(v[1], o) : umin64(v[1], o); }              \
        { u64 o = __shfl_xor(v[2], (J), 64); bool d_ = (D2);                      \
          v[2] = (low_ == d_) ? umax64(v[2], o) : umin64(v[2], o); }              \
        { u64 o = __shfl_xor(v[3], (J), 64); bool d_ = (D3);                      \
          v[3] = (low_ == d_) ? umax64(v[3], o) : umin64(v[3], o); }              \
    }

    #pragma unroll
    for (int k = 2; k <= 32; k <<= 1) {
        #pragma unroll
        for (int j = k >> 1; j > 0; j >>= 1) {
            const bool dd = ((lane & k) == 0);
            STAGE_SHFL(j, dd, dd, dd, dd);
        }
    }
    #pragma unroll
    for (int j = 32; j > 0; j >>= 1) STAGE_SHFL(j, true, false, true, false);
    { u64 a = v[0], bb = v[1]; v[0] = umax64(a, bb); v[1] = umin64(a, bb); }
    { u64 a = v[2], bb = v[3]; v[2] = umin64(a, bb); v[3] = umax64(a, bb); }
    #pragma unroll
    for (int j = 32; j > 0; j >>= 1) STAGE_SHFL(j, true, true, false, false);
    { u64 a = v[0], bb = v[2]; v[0] = umax64(a, bb); v[2] = umin64(a, bb); }
    { u64 a = v[1], bb = v[3]; v[1] = umax64(a, bb); v[3] = umin64(a, bb); }
    { u64 a = v[0], bb = v[1]; v[0] = umax64(a, bb); v[1] = umin64(a, bb); }
    { u64 a = v[2], bb = v[3]; v[2] = umax64(a, bb); v[3] = umin64(a, bb); }
    #pragma unroll
    for (int j = 32; j > 0; j >>= 1) STAGE_SHFL(j, true, true, true, true);
    #undef STAGE_SHFL

    // ---- gather boxes by rank; publish n + box per rank to LDS ----
    const float4* boxes_b = (const float4*)(boxes + (size_t)b * NMS_N * 4);
    #pragma unroll
    for (int q = 0; q < WMAX; ++q) {
        const int r = q * 64 + lane;
        const int n = NMS_N - 1 - (int)((v[q] >> 18) & 0x3FFFull);  // pad-safe
        sn_[r] = n;
        sbox[r] = boxes_b[n];
    }
    // single wave: per-wave LDS is in-order; no barrier needed

    // ---- LAZY sorted walk: lane l holds pick-l's box ----
    float selx = 1e30f, sely = 1e30f, selz = -1e30f, selw = -1e30f, sela = 0.0f;
    int t = 0, r = 0, need_slow = 0;
    float4 cand = (m > 0) ? sbox[0] : make_float4(0.f, 0.f, 0.f, 0.f);

    while (t < maxo && r < m) {
        const int rn = (r + 1 < FCAP) ? (r + 1) : r;
        const float4 nxt = sbox[rn];         // prefetch next rank under the IoU

        const float areaC = __fmul_rn(__fsub_rn(cand.z, cand.x),
                                      __fsub_rn(cand.w, cand.y));
        // IoU(sel_lane, cand) — bit-exact reference order (sel first)
        float x1 = fmaxf(selx, cand.x);
        float y1 = fmaxf(sely, cand.y);
        float x2 = fminf(selz, cand.z);
        float y2 = fminf(selw, cand.w);
        float dx = fmaxf(__fsub_rn(x2, x1), 0.0f);
        float dy = fmaxf(__fsub_rn(y2, y1), 0.0f);
        bool sup = false;
        if (dx > 0.0f && dy > 0.0f) {        // inter==0 -> iou==0 exact skip
            float inter = __fmul_rn(dx, dy);
            float uni   = __fsub_rn(__fadd_rn(sela, areaC), inter);
            sup = __fdiv_rn(inter, fmaxf(uni, 1e-9f)) > iou_thr;
        }
        if (__ballot(sup) == 0ull) {         // no prior pick suppresses -> pick
            if (lane == 0) {
                const int n = sn_[r];
                if (OUT64) {
                    out64[t * 3 + 0] = (long long)b;
                    out64[t * 3 + 1] = (long long)c;
                    out64[t * 3 + 2] = (long long)n;
                } else {
                    out32[t * 3 + 0] = b;
                    out32[t * 3 + 1] = c;
                    out32[t * 3 + 2] = n;
                }
            }
            if (lane == t) {                 // latch pick-t into this lane
                selx = cand.x; sely = cand.y; selz = cand.z; selw = cand.w;
                sela = areaC;
            }
            ++t;
        }
        ++r;
        cand = nxt;
    }
    if (t < maxo && rem > 0) need_slow = 1;
    if (lane == 0) flags[bc] = need_slow;
}

// ---------------- monolithic fallback (mid-ws; r14-verified path) ----------------
template <bool OUT64>
__global__ __launch_bounds__(NTHREADS, 4) void nms_fast_mono(
    const float* __restrict__ boxes,
    const float* __restrict__ scores,
    const int* __restrict__ p_maxout,
    const float* __restrict__ p_iou,
    const float* __restrict__ p_sthr,
    void* __restrict__ out_raw,
    int* __restrict__ flags)
{
    __shared__ u64    skey[FCAP];
    __shared__ int    sn_[FCAP];
    __shared__ float4 sbox[FCAP];
    __shared__ int    s_cnt, s_total;

    const int tid = threadIdx.x;
    const int bc  = blockIdx.x;
    const int b   = bc / NMS_C;
    const int c   = bc % NMS_C;

    const float4* sc4     = (const float4*)(scores + ((size_t)b * NMS_C + c) * NMS_N);
    const float4* boxes_b = (const float4*)(boxes + (size_t)b * NMS_N * 4);

    float4 av[16];
    #pragma unroll
    for (int u = 0; u < 16; ++u) av[u] = sc4[u * NTHREADS + tid];
    __builtin_amdgcn_sched_barrier(0);

    const float score_thr = p_sthr[0];
    const float iou_thr   = p_iou[0];
    int maxo = p_maxout[0];
    if (maxo > NMS_MAX_OUT) maxo = NMS_MAX_OUT;
    if (maxo < 0) maxo = 0;

    int*       out32 = (int*)out_raw       + (size_t)bc * NMS_MAX_OUT * 3;
    long long* out64 = (long long*)out_raw + (size_t)bc * NMS_MAX_OUT * 3;
    for (int i = tid; i < NMS_MAX_OUT * 3; i += NTHREADS) {
        if (OUT64) out64[i] = -1LL; else out32[i] = -1;
    }

    if (tid == 0) { s_cnt = 0; s_total = 0; }
    __syncthreads();

    int local_total = 0;
    #pragma unroll
    for (int u = 0; u < 16; ++u) {
        const int i = u * NTHREADS + tid;
        float ss[4] = {av[u].x, av[u].y, av[u].z, av[u].w};
        #pragma unroll
        for (int j = 0; j < 4; ++j) {
            float s = ss[j];
            bool cand = (s > score_thr);
            local_total += cand ? 1 : 0;
            if (cand && s >= OPT_THR) {
                int n = i * 4 + j;
                int p = atomicAdd(&s_cnt, 1);
                if (p < FCAP) {
                    skey[p] = ((u64)__float_as_uint(s) << 32)
                            | ((u64)(NMS_N - 1 - n) << 18);
                }
            }
        }
    }
    atomicAdd(&s_total, local_total);
    __syncthreads();

    const int cn = s_cnt;
    const int m  = (cn < FCAP) ? cn : FCAP;
    if (cn > FCAP) {
        if (tid == 0) flags[bc] = 1;
        return;
    }
    if (tid >= 64) return;
    const int lane = tid;
    const int rem  = s_total - cn;

    u64 v[WMAX];
    #pragma unroll
    for (int q = 0; q < WMAX; ++q) {
        const int idx = q * 64 + lane;
        v[q] = (idx < m) ? skey[idx] : 0ull;
    }

    #define STAGE_SHFL(J, D0, D1, D2, D3) {                                       \
        const bool low_ = ((lane & (J)) == 0);                                    \
        { u64 o = __shfl_xor(v[0], (J), 64); bool d_ = (D0);                      \
          v[0] = (low_ == d_) ? umax64(v[0], o) : umin64(v[0], o); }              \
        { u64 o = __shfl_xor(v[1], (J), 64); bool d_ = (D1);                      \
          v[1] = (low_ == d_) ? umax64(v[1], o) : umin64(v[1], o); }              \
        { u64 o = __shfl_xor(v[2], (J), 64); bool d_ = (D2);                      \
          v[2] = (low_ == d_) ? umax64(v[2], o) : umin64(v[2], o); }              \
        { u64 o = __shfl_xor(v[3], (J), 64); bool d_ = (D3);                      \
          v[3] = (low_ == d_) ? umax64(v[3], o) : umin64(v[3], o); }              \
    }

    #pragma unroll
    for (int k = 2; k <= 32; k <<= 1) {
        #pragma unroll
        for (int j = k >> 1; j > 0; j >>= 1) {
            const bool dd = ((lane & k) == 0);
            STAGE_SHFL(j, dd, dd, dd, dd);
        }
    }
    #pragma unroll
    for (int j = 32; j > 0; j >>= 1) STAGE_SHFL(j, true, false, true, false);
    { u64 a = v[0], bb = v[1]; v[0] = umax64(a, bb); v[1] = umin64(a, bb); }
    { u64 a = v[2], bb = v[3]; v[2] = umin64(a, bb); v[3] = umax64(a, bb); }
    #pragma unroll
    for (int j = 32; j > 0; j >>= 1) STAGE_SHFL(j, true, true, false, false);
    { u64 a = v[0], bb = v[2]; v[0] = umax64(a, bb); v[2] = umin64(a, bb); }
    { u64 a = v[1], bb = v[3]; v[1] = umax64(a, bb); v[3] = umin64(a, bb); }
    { u64 a = v[0], bb = v[1]; v[0] = umax64(a, bb); v[1] = umin64(a, bb); }
    { u64 a = v[2], bb = v[3]; v[2] = umax64(a, bb); v[3] = umin64(a, bb); }
    #pragma unroll
    for (int j = 32; j > 0; j >>= 1) STAGE_SHFL(j, true, true, true, true);
    #undef STAGE_SHFL

    #pragma unroll
    for (int q = 0; q < WMAX; ++q) {
        const int r = q * 64 + lane;
        const int n = NMS_N - 1 - (int)((v[q] >> 18) & 0x3FFFull);
        sn_[r] = n;
        sbox[r] = boxes_b[n];
    }

    float selx = 1e30f, sely = 1e30f, selz = -1e30f, selw = -1e30f, sela = 0.0f;
    int t = 0, r = 0, need_slow = 0;
    float4 cand = (m > 0) ? sbox[0] : make_float4(0.f, 0.f, 0.f, 0.f);

    while (t < maxo && r < m) {
        const int rn = (r + 1 < FCAP) ? (r + 1) : r;
        const float4 nxt = sbox[rn];
        const float areaC = __fmul_rn(__fsub_rn(cand.z, cand.x),
                                      __fsub_rn(cand.w, cand.y));
        float x1 = fmaxf(selx, cand.x);
        float y1 = fmaxf(sely, cand.y);
        float x2 = fminf(selz, cand.z);
        float y2 = fminf(selw, cand.w);
        float dx = fmaxf(__fsub_rn(x2, x1), 0.0f);
        float dy = fmaxf(__fsub_rn(y2, y1), 0.0f);
        bool sup = false;
        if (dx > 0.0f && dy > 0.0f) {
            float inter = __fmul_rn(dx, dy);
            float uni   = __fsub_rn(__fadd_rn(sela, areaC), inter);
            sup = __fdiv_rn(inter, fmaxf(uni, 1e-9f)) > iou_thr;
        }
        if (__ballot(sup) == 0ull) {
            if (lane == 0) {
                const int n = sn_[r];
                if (OUT64) {
                    out64[t * 3 + 0] = (long long)b;
                    out64[t * 3 + 1] = (long long)c;
                    out64[t * 3 + 2] = (long long)n;
                } else {
                    out32[t * 3 + 0] = b;
                    out32[t * 3 + 1] = c;
                    out32[t * 3 + 2] = n;
                }
            }
            if (lane == t) {
                selx = cand.x; sely = cand.y; selz = cand.z; selw = cand.w;
                sela = areaC;
            }
            ++t;
        }
        ++r;
        cand = nxt;
    }
    if (t < maxo && rem > 0) need_slow = 1;
    if (lane == 0) flags[bc] = need_slow;
}

// ---- slow exact fallback (verified round-2 structure, flag-gated) ----
__device__ __forceinline__ int bucketf(float s) {
    int v = (int)__float_as_uint(s) - 0x3F000000;
    v >>= 15;
    return v < 0 ? 0 : (v > 255 ? 255 : v);
}

template <bool OUT64>
__global__ __launch_bounds__(NTHREADS) void nms_slow(
    const float* __restrict__ boxes,
    const float* __restrict__ scores,
    const int* __restrict__ p_maxout,
    const float* __restrict__ p_iou,
    const float* __restrict__ p_sthr,
    void* __restrict__ out_raw,
    const int* __restrict__ flags)
{
    __shared__ int    hist[NBUCK];
    __shared__ u64    key[SCAP];
    __shared__ float4 cbox[SCAP];
    __shared__ float4 selbox[NMS_MAX_OUT];
    __shared__ u64    s_wmax[NTHREADS / 64];
    __shared__ u64    s_best;
    __shared__ int    s_cnt, s_cutLo, s_cutHi, s_rem, s_state;

    const int tid = threadIdx.x;
    const int bc  = blockIdx.x;
    if (flags && flags[bc] == 0) return;
    const int b   = bc / NMS_C;
    const int c   = bc % NMS_C;

    const float score_thr = p_sthr[0];
    const float iou_thr   = p_iou[0];
    int maxo = p_maxout[0];
    if (maxo > NMS_MAX_OUT) maxo = NMS_MAX_OUT;
    if (maxo < 0) maxo = 0;

    int*       out32 = (int*)out_raw       + (size_t)bc * NMS_MAX_OUT * 3;
    long long* out64 = (long long*)out_raw + (size_t)bc * NMS_MAX_OUT * 3;
    for (int i = tid; i < NMS_MAX_OUT * 3; i += NTHREADS) {
        if (OUT64) out64[i] = -1LL; else out32[i] = -1;
    }

    const float*  sc      = scores + ((size_t)b * NMS_C + c) * NMS_N;
    const float4* sc4     = (const float4*)sc;
    const float4* boxes_b = (const float4*)(boxes + (size_t)b * NMS_N * 4);

    for (int i = tid; i < NBUCK; i += NTHREADS) hist[i] = 0;
    if (tid == 0) s_cnt = 0;
    __syncthreads();
    for (int i = tid; i < NMS_N / 4; i += NTHREADS) {
        float4 s4 = sc4[i];
        float ss[4] = {s4.x, s4.y, s4.z, s4.w};
        #pragma unroll
        for (int j = 0; j < 4; ++j)
            if (ss[j] > score_thr) atomicAdd(&hist[bucketf(ss[j])], 1);
    }
    __syncthreads();

    if (tid == 0) {
        int cum = 0, cut = NBUCK;
        for (int bk = NBUCK - 1; bk >= 0; --bk) {
            int h = hist[bk];
            if (cum > 0 && cum + h > SCAP) break;
            cum += h; cut = bk;
            if (cum >= T_MIN) break;
        }
        s_cutLo = cut; s_cutHi = NBUCK - 1;
        int rem = 0;
        for (int bk = 0; bk < cut; ++bk) rem += hist[bk];
        s_rem = rem;
    }
    __syncthreads();

    auto compact = [&](int lo, int hi) {
        for (int i = tid; i < NMS_N / 4; i += NTHREADS) {
            float4 s4 = sc4[i];
            float ss[4] = {s4.x, s4.y, s4.z, s4.w};
            #pragma unroll
            for (int j = 0; j < 4; ++j) {
                float s = ss[j];
                if (s > score_thr) {
                    int bk = bucketf(s);
                    if (bk >= lo && bk <= hi) {
                        int n = i * 4 + j;
                        int p = atomicAdd(&s_cnt, 1);
                        if (p < SCAP) {
                            key[p] = ((u64)__float_as_uint(s) << 24)
                                   | ((u64)(NMS_N - 1 - n) << 10)
                                   | (u64)p;
                            cbox[p] = boxes_b[n];
                        }
                    }
                }
            }
        }
    };
    compact(s_cutLo, s_cutHi);
    __syncthreads();

    int t = 0;
    while (t < maxo) {
        int m = s_cnt; if (m > SCAP) m = SCAP;
        u64 lmax = 0ull;
        for (int i = tid; i < m; i += NTHREADS) {
            u64 k = key[i];
            if (k > lmax) lmax = k;
        }
        #pragma unroll
        for (int off = 32; off > 0; off >>= 1) {
            u64 o = __shfl_down(lmax, off);
            if (o > lmax) lmax = o;
        }
        if ((tid & 63) == 0) s_wmax[tid >> 6] = lmax;
        __syncthreads();
        if (tid == 0) {
            u64 best = s_wmax[0];
            #pragma unroll
            for (int w = 1; w < NTHREADS / 64; ++w)
                if (s_wmax[w] > best) best = s_wmax[w];
            s_best = best;
            if (best) {
                int slot = (int)(best & 0x3FFull);
                int n    = NMS_N - 1 - (int)((best >> 10) & 0x3FFFull);
                key[slot] = 0ull;
                if (OUT64) {
                    out64[t * 3 + 0] = (long long)b;
                    out64[t * 3 + 1] = (long long)c;
                    out64[t * 3 + 2] = (long long)n;
                } else {
                    out32[t * 3 + 0] = b;
                    out32[t * 3 + 1] = c;
                    out32[t * 3 + 2] = n;
                }
                selbox[t] = cbox[slot];
                s_state = 0;
            } else if (s_rem == 0) {
                s_state = 2;
            } else {
                int hiB = s_cutLo - 1;
                int cum = 0, cut = hiB + 1;
                for (int bk = hiB; bk >= 0; --bk) {
                    int h = hist[bk];
                    if (cum > 0 && cum + h > SCAP) break;
                    cum += h; cut = bk;
                    if (cum >= T_MIN) break;
                }
                s_cutLo = cut; s_cutHi = hiB;
                int rem = 0;
                for (int bk = 0; bk < cut; ++bk) rem += hist[bk];
                s_rem = rem;
                s_cnt = 0;
                s_state = 1;
            }
        }
        __syncthreads();

        if (s_state == 2) break;

        if (s_state == 0) {
            const float4 A = selbox[t];
            const float areaA = __fmul_rn(__fsub_rn(A.z, A.x), __fsub_rn(A.w, A.y));
            int m0 = s_cnt; if (m0 > SCAP) m0 = SCAP;
            for (int i = tid; i < m0; i += NTHREADS) {
                u64 k = key[i];
                if (!k) continue;
                if (iou_exact(A, areaA, cbox[i]) > iou_thr) key[i] = 0ull;
            }
            __syncthreads();
            ++t;
        } else {
            compact(s_cutLo, s_cutHi);
            __syncthreads();
            int m2 = s_cnt; if (m2 > SCAP) m2 = SCAP;
            for (int i = tid; i < m2; i += NTHREADS) {
                u64 k = key[i];
                if (!k) continue;
                float4 Bx = cbox[i];
                for (int j = 0; j < t; ++j) {
                    float4 A = selbox[j];
                    float areaA = __fmul_rn(__fsub_rn(A.z, A.x), __fsub_rn(A.w, A.y));
                    if (iou_exact(A, areaA, Bx) > iou_thr) { key[i] = 0ull; break; }
                }
            }
            __syncthreads();
        }
    }
}

extern "C" void kernel_launch(void* const* d_in, const int* in_sizes, int n_in,
                              void* d_out, int out_size, void* d_ws, size_t ws_size,
                              hipStream_t stream) {
    const float* boxes  = (const float*)d_in[0];
    const float* scores = (const float*)d_in[1];
    const int*   p_maxo = (const int*)d_in[2];
    const float* p_iou  = (const float*)d_in[3];
    const float* p_sthr = (const float*)d_in[4];

    const dim3 block(NTHREADS);
    const bool out64 = (out_size == NLANES * NMS_MAX_OUT * 3 * 2);

    char* ws = (char*)d_ws;
    int*  flags  = (int*)(ws + WS_FLAGS);
    int*  cnts   = (int*)(ws + WS_CNTS);
    int*  totals = (int*)(ws + WS_TOTALS);
    u64*  keys   = (u64*)(ws + WS_KEYS);

    if (ws_size >= WS_NEED) {
        hipLaunchKernelGGL(nms_scan, dim3(NLANES * SPLIT), block, 0, stream,
                           scores, p_sthr, cnts, totals, keys);
        if (out64) {
            hipLaunchKernelGGL(nms_sortwalk<true>, dim3(NLANES), dim3(64), 0, stream,
                               boxes, p_maxo, p_iou, d_out, flags, cnts, totals, keys);
            hipLaunchKernelGGL(nms_slow<true>, dim3(NLANES), block, 0, stream,
                               boxes, scores, p_maxo, p_iou, p_sthr, d_out, flags);
        } else {
            hipLaunchKernelGGL(nms_sortwalk<false>, dim3(NLANES), dim3(64), 0, stream,
                               boxes, p_maxo, p_iou, d_out, flags, cnts, totals, keys);
            hipLaunchKernelGGL(nms_slow<false>, dim3(NLANES), block, 0, stream,
                               boxes, scores, p_maxo, p_iou, p_sthr, d_out, flags);
        }
    } else if (ws_size >= (size_t)NLANES * sizeof(int)) {
        if (out64) {
            hipLaunchKernelGGL(nms_fast_mono<true>, dim3(NLANES), block, 0, stream,
                               boxes, scores, p_maxo, p_iou, p_sthr, d_out, flags);
            hipLaunchKernelGGL(nms_slow<true>, dim3(NLANES), block, 0, stream,
                               boxes, scores, p_maxo, p_iou, p_sthr, d_out, flags);
        } else {
            hipLaunchKernelGGL(nms_fast_mono<false>, dim3(NLANES), block, 0, stream,
                               boxes, scores, p_maxo, p_iou, p_sthr, d_out, flags);
            hipLaunchKernelGGL(nms_slow<false>, dim3(NLANES), block, 0, stream,
                               boxes, scores, p_maxo, p_iou, p_sthr, d_out, flags);
        }
    } else {
        if (out64) {
            hipLaunchKernelGGL(nms_slow<true>, dim3(NLANES), block, 0, stream,
                               boxes, scores, p_maxo, p_iou, p_sthr, d_out, (const int*)nullptr);
        } else {
            hipLaunchKernelGGL(nms_slow<false>, dim3(NLANES), block, 0, stream,
                               boxes, scores, p_maxo, p_iou, p_sthr, d_out, (const int*)nullptr);
        }
    }
}

// Round 16
// 38.320 us; speedup vs baseline: 5.1978x; 1.0375x over previous
//
#include <hip/hip_runtime.h>
#include <stdint.h>

// ONNX NonMaxSuppression: B=8, N=16384, C=80, MAX_OUT=50
// TWO-launch pipeline:
//   nms_scan: 4 blocks per (b,c) stream scores, compact candidates >= OPT_THR
//             into private ws segments + non-atomic count/total (r13-proven).
//   nms_fused (256 thr): uniform prefix-sum of counts; if overflow -> run the
//             VERIFIED slow path inline (shared device function). Else wave 0
//             does global->reg key load, register bitonic sort, box gather,
//             LAZY sorted walk (r14/r15-proven); waves 1-3 park at one
//             barrier; if the walk exhausts with remainder, whole block runs
//             the slow path inline. No flags HBM round-trip, no 3rd launch.
// Fallbacks: monolithic kernel + gated slow (ws >= 2560B), else slow-for-all.

#define NMS_B 8
#define NMS_N 16384
#define NMS_C 80
#define NMS_MAX_OUT 50
#define NTHREADS 256
#define NLANES (NMS_B * NMS_C)

#define OPT_THR 0.98828125f  // = 1 - 192/16384 exactly; E[cnt]=192, sigma~13.8
#define FCAP 256
#define WMAX (FCAP / 64)     // 4 regs per lane in the register sort
#define SPLIT 4
#define SEG 120              // per-part capacity: E=48, sigma~6.9 -> +10 sigma
#define SCAN_N (NMS_N / SPLIT)

// slow (fallback) path
#define NBUCK 256
#define SCAP 1024
#define T_MIN 320

typedef unsigned long long u64;

// ws layout (flags kept for the mid-ws fallback path only)
#define WS_FLAGS  0
#define WS_CNTS   (NLANES * 4)
#define WS_TOTALS (WS_CNTS + NLANES * SPLIT * 4)
#define WS_KEYS   (WS_TOTALS + NLANES * SPLIT * 4)
#define WS_NEED   ((size_t)WS_KEYS + (size_t)NLANES * SPLIT * SEG * 8)

__device__ __forceinline__ float iou_exact(float4 A, float areaA, float4 Bx) {
    float x1 = fmaxf(A.x, Bx.x);
    float y1 = fmaxf(A.y, Bx.y);
    float x2 = fminf(A.z, Bx.z);
    float y2 = fminf(A.w, Bx.w);
    float dx = fmaxf(__fsub_rn(x2, x1), 0.0f);
    float dy = fmaxf(__fsub_rn(y2, y1), 0.0f);
    if (!(dx > 0.0f && dy > 0.0f)) return 0.0f;   // inter==0 -> iou==0 exactly
    float inter = __fmul_rn(dx, dy);
    float areaB = __fmul_rn(__fsub_rn(Bx.z, Bx.x), __fsub_rn(Bx.w, Bx.y));
    float uni   = __fsub_rn(__fadd_rn(areaA, areaB), inter);
    return __fdiv_rn(inter, fmaxf(uni, 1e-9f));
}

__device__ __forceinline__ u64 umax64(u64 a, u64 b) { return a > b ? a : b; }
__device__ __forceinline__ u64 umin64(u64 a, u64 b) { return a < b ? a : b; }

__device__ __forceinline__ int bucketf(float s) {
    int v = (int)__float_as_uint(s) - 0x3F000000;
    v >>= 15;
    return v < 0 ? 0 : (v > 255 ? 255 : v);
}

// ---------------- verified slow path (round-2 structure) as device fn ----------------
// Must be entered by ALL 256 threads of the block (contains __syncthreads).
template <bool OUT64>
__device__ __noinline__ void slow_body(
    const float* __restrict__ boxes,
    const float* __restrict__ scores,
    const int* __restrict__ p_maxout,
    const float* __restrict__ p_iou,
    const float* __restrict__ p_sthr,
    void* __restrict__ out_raw,
    int bc)
{
    __shared__ int    hist[NBUCK];
    __shared__ u64    key[SCAP];
    __shared__ float4 cbox[SCAP];
    __shared__ float4 selbox[NMS_MAX_OUT];
    __shared__ u64    s_wmax[NTHREADS / 64];
    __shared__ u64    s_best;
    __shared__ int    s_cnt, s_cutLo, s_cutHi, s_rem, s_state;

    const int tid = threadIdx.x;
    const int b   = bc / NMS_C;
    const int c   = bc % NMS_C;

    const float score_thr = p_sthr[0];
    const float iou_thr   = p_iou[0];
    int maxo = p_maxout[0];
    if (maxo > NMS_MAX_OUT) maxo = NMS_MAX_OUT;
    if (maxo < 0) maxo = 0;

    int*       out32 = (int*)out_raw       + (size_t)bc * NMS_MAX_OUT * 3;
    long long* out64 = (long long*)out_raw + (size_t)bc * NMS_MAX_OUT * 3;
    for (int i = tid; i < NMS_MAX_OUT * 3; i += NTHREADS) {
        if (OUT64) out64[i] = -1LL; else out32[i] = -1;
    }

    const float*  sc      = scores + ((size_t)b * NMS_C + c) * NMS_N;
    const float4* sc4     = (const float4*)sc;
    const float4* boxes_b = (const float4*)(boxes + (size_t)b * NMS_N * 4);

    for (int i = tid; i < NBUCK; i += NTHREADS) hist[i] = 0;
    if (tid == 0) s_cnt = 0;
    __syncthreads();
    for (int i = tid; i < NMS_N / 4; i += NTHREADS) {
        float4 s4 = sc4[i];
        float ss[4] = {s4.x, s4.y, s4.z, s4.w};
        #pragma unroll
        for (int j = 0; j < 4; ++j)
            if (ss[j] > score_thr) atomicAdd(&hist[bucketf(ss[j])], 1);
    }
    __syncthreads();

    if (tid == 0) {
        int cum = 0, cut = NBUCK;
        for (int bk = NBUCK - 1; bk >= 0; --bk) {
            int h = hist[bk];
            if (cum > 0 && cum + h > SCAP) break;
            cum += h; cut = bk;
            if (cum >= T_MIN) break;
        }
        s_cutLo = cut; s_cutHi = NBUCK - 1;
        int rem = 0;
        for (int bk = 0; bk < cut; ++bk) rem += hist[bk];
        s_rem = rem;
    }
    __syncthreads();

    auto compact = [&](int lo, int hi) {
        for (int i = tid; i < NMS_N / 4; i += NTHREADS) {
            float4 s4 = sc4[i];
            float ss[4] = {s4.x, s4.y, s4.z, s4.w};
            #pragma unroll
            for (int j = 0; j < 4; ++j) {
                float s = ss[j];
                if (s > score_thr) {
                    int bk = bucketf(s);
                    if (bk >= lo && bk <= hi) {
                        int n = i * 4 + j;
                        int p = atomicAdd(&s_cnt, 1);
                        if (p < SCAP) {
                            key[p] = ((u64)__float_as_uint(s) << 24)
                                   | ((u64)(NMS_N - 1 - n) << 10)
                                   | (u64)p;
                            cbox[p] = boxes_b[n];
                        }
                    }
                }
            }
        }
    };
    compact(s_cutLo, s_cutHi);
    __syncthreads();

    int t = 0;
    while (t < maxo) {
        int m = s_cnt; if (m > SCAP) m = SCAP;
        u64 lmax = 0ull;
        for (int i = tid; i < m; i += NTHREADS) {
            u64 k = key[i];
            if (k > lmax) lmax = k;
        }
        #pragma unroll
        for (int off = 32; off > 0; off >>= 1) {
            u64 o = __shfl_down(lmax, off);
            if (o > lmax) lmax = o;
        }
        if ((tid & 63) == 0) s_wmax[tid >> 6] = lmax;
        __syncthreads();
        if (tid == 0) {
            u64 best = s_wmax[0];
            #pragma unroll
            for (int w = 1; w < NTHREADS / 64; ++w)
                if (s_wmax[w] > best) best = s_wmax[w];
            s_best = best;
            if (best) {
                int slot = (int)(best & 0x3FFull);
                int n    = NMS_N - 1 - (int)((best >> 10) & 0x3FFFull);
                key[slot] = 0ull;
                if (OUT64) {
                    out64[t * 3 + 0] = (long long)b;
                    out64[t * 3 + 1] = (long long)c;
                    out64[t * 3 + 2] = (long long)n;
                } else {
                    out32[t * 3 + 0] = b;
                    out32[t * 3 + 1] = c;
                    out32[t * 3 + 2] = n;
                }
                selbox[t] = cbox[slot];
                s_state = 0;
            } else if (s_rem == 0) {
                s_state = 2;
            } else {
                int hiB = s_cutLo - 1;
                int cum = 0, cut = hiB + 1;
                for (int bk = hiB; bk >= 0; --bk) {
                    int h = hist[bk];
                    if (cum > 0 && cum + h > SCAP) break;
                    cum += h; cut = bk;
                    if (cum >= T_MIN) break;
                }
                s_cutLo = cut; s_cutHi = hiB;
                int rem = 0;
                for (int bk = 0; bk < cut; ++bk) rem += hist[bk];
                s_rem = rem;
                s_cnt = 0;
                s_state = 1;
            }
        }
        __syncthreads();

        if (s_state == 2) break;

        if (s_state == 0) {
            const float4 A = selbox[t];
            const float areaA = __fmul_rn(__fsub_rn(A.z, A.x), __fsub_rn(A.w, A.y));
            int m0 = s_cnt; if (m0 > SCAP) m0 = SCAP;
            for (int i = tid; i < m0; i += NTHREADS) {
                u64 k = key[i];
                if (!k) continue;
                if (iou_exact(A, areaA, cbox[i]) > iou_thr) key[i] = 0ull;
            }
            __syncthreads();
            ++t;
        } else {
            compact(s_cutLo, s_cutHi);
            __syncthreads();
            int m2 = s_cnt; if (m2 > SCAP) m2 = SCAP;
            for (int i = tid; i < m2; i += NTHREADS) {
                u64 k = key[i];
                if (!k) continue;
                float4 Bx = cbox[i];
                for (int j = 0; j < t; ++j) {
                    float4 A = selbox[j];
                    float areaA = __fmul_rn(__fsub_rn(A.z, A.x), __fsub_rn(A.w, A.y));
                    if (iou_exact(A, areaA, Bx) > iou_thr) { key[i] = 0ull; break; }
                }
            }
            __syncthreads();
        }
    }
}

// ---------------- phase 1: contention-free parallel scan ----------------
__global__ __launch_bounds__(NTHREADS) void nms_scan(
    const float* __restrict__ scores,
    const float* __restrict__ p_sthr,
    int* __restrict__ cnts,
    int* __restrict__ totals,
    u64* __restrict__ keys)
{
    __shared__ u64 lkey[SEG];
    __shared__ int lcnt, ltot;

    const int bid  = blockIdx.x;
    const int bc   = bid / SPLIT;
    const int part = bid % SPLIT;
    const int tid  = threadIdx.x;

    const float4* sc4 = (const float4*)(scores + (size_t)bc * NMS_N + part * SCAN_N);
    float4 av[4];
    #pragma unroll
    for (int u = 0; u < 4; ++u) av[u] = sc4[u * NTHREADS + tid];
    __builtin_amdgcn_sched_barrier(0);       // all 4 loads in flight

    if (tid == 0) { lcnt = 0; ltot = 0; }
    __syncthreads();

    const float sthr = p_sthr[0];
    int lt = 0;
    #pragma unroll
    for (int u = 0; u < 4; ++u) {
        const int i = u * NTHREADS + tid;
        float ss[4] = {av[u].x, av[u].y, av[u].z, av[u].w};
        #pragma unroll
        for (int j = 0; j < 4; ++j) {
            float s = ss[j];
            bool cand = (s > sthr);
            lt += cand ? 1 : 0;
            if (cand && s >= OPT_THR) {      // rare
                int n = part * SCAN_N + i * 4 + j;
                int p = atomicAdd(&lcnt, 1);
                if (p < SEG)
                    lkey[p] = ((u64)__float_as_uint(s) << 32)
                            | ((u64)(NMS_N - 1 - n) << 18);
            }
        }
    }
    #pragma unroll
    for (int off = 32; off > 0; off >>= 1) lt += __shfl_down(lt, off, 64);
    if ((tid & 63) == 0) atomicAdd(&ltot, lt);
    __syncthreads();

    const int cnt = lcnt;
    if (tid == 0) {
        cnts[bc * SPLIT + part]   = cnt;     // may exceed SEG -> handled later
        totals[bc * SPLIT + part] = ltot;
    }
    u64* kseg = keys + ((size_t)bc * SPLIT + part) * SEG;
    const int mm = (cnt < SEG) ? cnt : SEG;
    if (tid < mm) kseg[tid] = lkey[tid];
}

// ---------------- phase 2: fused sort + LAZY walk + inline slow ----------------
template <bool OUT64>
__global__ __launch_bounds__(NTHREADS) void nms_fused(
    const float* __restrict__ boxes,
    const float* __restrict__ scores,
    const int* __restrict__ p_maxout,
    const float* __restrict__ p_iou,
    const float* __restrict__ p_sthr,
    void* __restrict__ out_raw,
    const int* __restrict__ cnts,
    const int* __restrict__ totals,
    const u64* __restrict__ keys)
{
    __shared__ int    sn_[FCAP];
    __shared__ float4 sbox[FCAP];
    __shared__ int    s_need_slow;

    const int tid  = threadIdx.x;
    const int bc   = blockIdx.x;
    const int b    = bc / NMS_C;
    const int c    = bc % NMS_C;

    const float iou_thr = p_iou[0];
    int maxo = p_maxout[0];
    if (maxo > NMS_MAX_OUT) maxo = NMS_MAX_OUT;
    if (maxo < 0) maxo = 0;

    int*       out32 = (int*)out_raw       + (size_t)bc * NMS_MAX_OUT * 3;
    long long* out64 = (long long*)out_raw + (size_t)bc * NMS_MAX_OUT * 3;
    for (int i = tid; i < NMS_MAX_OUT * 3; i += NTHREADS) {
        if (OUT64) out64[i] = -1LL; else out32[i] = -1;
    }

    // uniform loads (same address across lanes -> broadcast)
    const int c0 = cnts[bc * SPLIT + 0], c1 = cnts[bc * SPLIT + 1];
    const int c2 = cnts[bc * SPLIT + 2], c3 = cnts[bc * SPLIT + 3];
    const int tt = totals[bc * SPLIT + 0] + totals[bc * SPLIT + 1]
                 + totals[bc * SPLIT + 2] + totals[bc * SPLIT + 3];
    const int o1 = c0, o2 = c0 + c1, o3 = c0 + c1 + c2;
    const int m  = o3 + c3;
    const bool bad = (c0 > SEG) | (c1 > SEG) | (c2 > SEG) | (c3 > SEG) | (m > FCAP);
    if (bad) {                               // uniform: whole block -> slow
        slow_body<OUT64>(boxes, scores, p_maxout, p_iou, p_sthr, out_raw, bc);
        return;
    }
    const int rem = tt - m;

    if (tid < 64) {
        const int lane = tid;

        // ---- keys straight global -> register (part-select per reg) ----
        const u64* kb = keys + (size_t)bc * SPLIT * SEG;
        u64 v[WMAX];
        #pragma unroll
        for (int q = 0; q < WMAX; ++q) {
            const int idx = q * 64 + lane;
            int p, base;
            if (idx < o1)      { p = 0; base = 0;  }
            else if (idx < o2) { p = 1; base = o1; }
            else if (idx < o3) { p = 2; base = o2; }
            else               { p = 3; base = o3; }
            v[q] = (idx < m) ? kb[(size_t)p * SEG + (idx - base)] : 0ull;
        }

        // ---- register bitonic sort (desc), 256 elems, i = q*64+lane ----
        #define STAGE_SHFL(J, D0, D1, D2, D3) {                                   \
            const bool low_ = ((lane & (J)) == 0);                                \
            { u64 o = __shfl_xor(v[0], (J), 64); bool d_ = (D0);                  \
              v[0] = (low_ == d_) ? umax64(v[0], o) : umin64(v[0], o); }          \
            { u64 o = __shfl_xor(v[1], (J), 64); bool d_ = (D1);                  \
              v[1] = (low_ == d_) ? umax64(v[1], o) : umin64(v[1], o); }          \
            { u64 o = __shfl_xor(v[2], (J), 64); bool d_ = (D2);                  \
              v[2] = (low_ == d_) ? umax64(v[2], o) : umin64(v[2], o); }          \
            { u64 o = __shfl_xor(v[3], (J), 64); bool d_ = (D3);                  \
              v[3] = (low_ == d_) ? umax64(v[3], o) : umin64(v[3], o); }          \
        }

        #pragma unroll
        for (int k = 2; k <= 32; k <<= 1) {
            #pragma unroll
            for (int j = k >> 1; j > 0; j >>= 1) {
                const bool dd = ((lane & k) == 0);
                STAGE_SHFL(j, dd, dd, dd, dd);
            }
        }
        #pragma unroll
        for (int j = 32; j > 0; j >>= 1) STAGE_SHFL(j, true, false, true, false);
        { u64 a = v[0], bb = v[1]; v[0] = umax64(a, bb); v[1] = umin64(a, bb); }
        { u64 a = v[2], bb = v[3]; v[2] = umin64(a, bb); v[3] = umax64(a, bb); }
        #pragma unroll
        for (int j = 32; j > 0; j >>= 1) STAGE_SHFL(j, true, true, false, false);
        { u64 a = v[0], bb = v[2]; v[0] = umax64(a, bb); v[2] = umin64(a, bb); }
        { u64 a = v[1], bb = v[3]; v[1] = umax64(a, bb); v[3] = umin64(a, bb); }
        { u64 a = v[0], bb = v[1]; v[0] = umax64(a, bb); v[1] = umin64(a, bb); }
        { u64 a = v[2], bb = v[3]; v[2] = umax64(a, bb); v[3] = umin64(a, bb); }
        #pragma unroll
        for (int j = 32; j > 0; j >>= 1) STAGE_SHFL(j, true, true, true, true);
        #undef STAGE_SHFL

        // ---- gather boxes by rank; publish n + box per rank to LDS ----
        const float4* boxes_b = (const float4*)(boxes + (size_t)b * NMS_N * 4);
        #pragma unroll
        for (int q = 0; q < WMAX; ++q) {
            const int r = q * 64 + lane;
            const int n = NMS_N - 1 - (int)((v[q] >> 18) & 0x3FFFull);  // pad-safe
            sn_[r] = n;
            sbox[r] = boxes_b[n];
        }
        // single wave: per-wave LDS is in-order; no barrier needed

        // ---- LAZY sorted walk: lane l holds pick-l's box ----
        float selx = 1e30f, sely = 1e30f, selz = -1e30f, selw = -1e30f, sela = 0.0f;
        int t = 0, r = 0;
        float4 cand = (m > 0) ? sbox[0] : make_float4(0.f, 0.f, 0.f, 0.f);

        while (t < maxo && r < m) {
            const int rn = (r + 1 < FCAP) ? (r + 1) : r;
            const float4 nxt = sbox[rn];     // prefetch next rank under the IoU

            const float areaC = __fmul_rn(__fsub_rn(cand.z, cand.x),
                                          __fsub_rn(cand.w, cand.y));
            float x1 = fmaxf(selx, cand.x);
            float y1 = fmaxf(sely, cand.y);
            float x2 = fminf(selz, cand.z);
            float y2 = fminf(selw, cand.w);
            float dx = fmaxf(__fsub_rn(x2, x1), 0.0f);
            float dy = fmaxf(__fsub_rn(y2, y1), 0.0f);
            bool sup = false;
            if (dx > 0.0f && dy > 0.0f) {    // inter==0 -> iou==0 exact skip
                float inter = __fmul_rn(dx, dy);
                float uni   = __fsub_rn(__fadd_rn(sela, areaC), inter);
                sup = __fdiv_rn(inter, fmaxf(uni, 1e-9f)) > iou_thr;
            }
            if (__ballot(sup) == 0ull) {     // no prior pick suppresses -> pick
                if (lane == 0) {
                    const int n = sn_[r];
                    if (OUT64) {
                        out64[t * 3 + 0] = (long long)b;
                        out64[t * 3 + 1] = (long long)c;
                        out64[t * 3 + 2] = (long long)n;
                    } else {
                        out32[t * 3 + 0] = b;
                        out32[t * 3 + 1] = c;
                        out32[t * 3 + 2] = n;
                    }
                }
                if (lane == t) {             // latch pick-t into this lane
                    selx = cand.x; sely = cand.y; selz = cand.z; selw = cand.w;
                    sela = areaC;
                }
                ++t;
            }
            ++r;
            cand = nxt;
        }
        if (lane == 0) s_need_slow = (t < maxo && rem > 0) ? 1 : 0;
    }
    __syncthreads();                         // waves 1..3 park here
    if (s_need_slow)
        slow_body<OUT64>(boxes, scores, p_maxout, p_iou, p_sthr, out_raw, bc);
}

// ---------------- monolithic fallback (mid-ws; r14/r15-verified) ----------------
template <bool OUT64>
__global__ __launch_bounds__(NTHREADS, 4) void nms_fast_mono(
    const float* __restrict__ boxes,
    const float* __restrict__ scores,
    const int* __restrict__ p_maxout,
    const float* __restrict__ p_iou,
    const float* __restrict__ p_sthr,
    void* __restrict__ out_raw,
    int* __restrict__ flags)
{
    __shared__ u64    skey[FCAP];
    __shared__ int    sn_[FCAP];
    __shared__ float4 sbox[FCAP];
    __shared__ int    s_cnt, s_total;

    const int tid = threadIdx.x;
    const int bc  = blockIdx.x;
    const int b   = bc / NMS_C;
    const int c   = bc % NMS_C;

    const float4* sc4     = (const float4*)(scores + ((size_t)b * NMS_C + c) * NMS_N);
    const float4* boxes_b = (const float4*)(boxes + (size_t)b * NMS_N * 4);

    float4 av[16];
    #pragma unroll
    for (int u = 0; u < 16; ++u) av[u] = sc4[u * NTHREADS + tid];
    __builtin_amdgcn_sched_barrier(0);

    const float score_thr = p_sthr[0];
    const float iou_thr   = p_iou[0];
    int maxo = p_maxout[0];
    if (maxo > NMS_MAX_OUT) maxo = NMS_MAX_OUT;
    if (maxo < 0) maxo = 0;

    int*       out32 = (int*)out_raw       + (size_t)bc * NMS_MAX_OUT * 3;
    long long* out64 = (long long*)out_raw + (size_t)bc * NMS_MAX_OUT * 3;
    for (int i = tid; i < NMS_MAX_OUT * 3; i += NTHREADS) {
        if (OUT64) out64[i] = -1LL; else out32[i] = -1;
    }

    if (tid == 0) { s_cnt = 0; s_total = 0; }
    __syncthreads();

    int local_total = 0;
    #pragma unroll
    for (int u = 0; u < 16; ++u) {
        const int i = u * NTHREADS + tid;
        float ss[4] = {av[u].x, av[u].y, av[u].z, av[u].w};
        #pragma unroll
        for (int j = 0; j < 4; ++j) {
            float s = ss[j];
            bool cand = (s > score_thr);
            local_total += cand ? 1 : 0;
            if (cand && s >= OPT_THR) {
                int n = i * 4 + j;
                int p = atomicAdd(&s_cnt, 1);
                if (p < FCAP) {
                    skey[p] = ((u64)__float_as_uint(s) << 32)
                            | ((u64)(NMS_N - 1 - n) << 18);
                }
            }
        }
    }
    atomicAdd(&s_total, local_total);
    __syncthreads();

    const int cn = s_cnt;
    const int m  = (cn < FCAP) ? cn : FCAP;
    if (cn > FCAP) {
        if (tid == 0) flags[bc] = 1;
        return;
    }
    if (tid >= 64) return;
    const int lane = tid;
    const int rem  = s_total - cn;

    u64 v[WMAX];
    #pragma unroll
    for (int q = 0; q < WMAX; ++q) {
        const int idx = q * 64 + lane;
        v[q] = (idx < m) ? skey[idx] : 0ull;
    }

    #define STAGE_SHFL(J, D0, D1, D2, D3) {                                       \
        const bool low_ = ((lane & (J)) == 0);                                    \
        { u64 o = __shfl_xor(v[0], (J), 64); bool d_ = (D0);                      \
          v[0] = (low_ == d_) ? umax64(v[0], o) : umin64(v[0], o); }              \
        { u64 o = __shfl_xor(v[1], (J), 64); bool d_ = (D1);                      \
          v[1] = (low_ == d_) ? umax64(v[1], o) : umin64(v[1], o); }              \
        { u64 o = __shfl_xor(v[2], (J), 64); bool d_ = (D2);                      \
          v[2] = (low_ == d_) ? umax64(v[2], o) : umin64(v[2], o); }              \
        { u64 o = __shfl_xor(v[3], (J), 64); bool d_ = (D3);                      \
          v[3] = (low_ == d_) ? umax64(v[3], o) : umin64(v[3], o); }              \
    }

    #pragma unroll
    for (int k = 2; k <= 32; k <<= 1) {
        #pragma unroll
        for (int j = k >> 1; j > 0; j >>= 1) {
            const bool dd = ((lane & k) == 0);
            STAGE_SHFL(j, dd, dd, dd, dd);
        }
    }
    #pragma unroll
    for (int j = 32; j > 0; j >>= 1) STAGE_SHFL(j, true, false, true, false);
    { u64 a = v[0], bb = v[1]; v[0] = umax64(a, bb); v[1] = umin64(a, bb); }
    { u64 a = v[2], bb = v[3]; v[2] = umin64(a, bb); v[3] = umax64(a, bb); }
    #pragma unroll
    for (int j = 32; j > 0; j >>= 1) STAGE_SHFL(j, true, true, false, false);
    { u64 a = v[0], bb = v[2]; v[0] = umax64(a, bb); v[2] = umin64(a, bb); }
    { u64 a = v[1], bb = v[3]; v[1] = umax64(a, bb); v[3] = umin64(a, bb); }
    { u64 a = v[0], bb = v[1]; v[0] = umax64(a, bb); v[1] = umin64(a, bb); }
    { u64 a = v[2], bb = v[3]; v[2] = umax64(a, bb); v[3] = umin64(a, bb); }
    #pragma unroll
    for (int j = 32; j > 0; j >>= 1) STAGE_SHFL(j, true, true, true, true);
    #undef STAGE_SHFL

    #pragma unroll
    for (int q = 0; q < WMAX; ++q) {
        const int r = q * 64 + lane;
        const int n = NMS_N - 1 - (int)((v[q] >> 18) & 0x3FFFull);
        sn_[r] = n;
        sbox[r] = boxes_b[n];
    }

    float selx = 1e30f, sely = 1e30f, selz = -1e30f, selw = -1e30f, sela = 0.0f;
    int t = 0, r = 0, need_slow = 0;
    float4 cand = (m > 0) ? sbox[0] : make_float4(0.f, 0.f, 0.f, 0.f);

    while (t < maxo && r < m) {
        const int rn = (r + 1 < FCAP) ? (r + 1) : r;
        const float4 nxt = sbox[rn];
        const float areaC = __fmul_rn(__fsub_rn(cand.z, cand.x),
                                      __fsub_rn(cand.w, cand.y));
        float x1 = fmaxf(selx, cand.x);
        float y1 = fmaxf(sely, cand.y);
        float x2 = fminf(selz, cand.z);
        float y2 = fminf(selw, cand.w);
        float dx = fmaxf(__fsub_rn(x2, x1), 0.0f);
        float dy = fmaxf(__fsub_rn(y2, y1), 0.0f);
        bool sup = false;
        if (dx > 0.0f && dy > 0.0f) {
            float inter = __fmul_rn(dx, dy);
            float uni   = __fsub_rn(__fadd_rn(sela, areaC), inter);
            sup = __fdiv_rn(inter, fmaxf(uni, 1e-9f)) > iou_thr;
        }
        if (__ballot(sup) == 0ull) {
            if (lane == 0) {
                const int n = sn_[r];
                if (OUT64) {
                    out64[t * 3 + 0] = (long long)b;
                    out64[t * 3 + 1] = (long long)c;
                    out64[t * 3 + 2] = (long long)n;
                } else {
                    out32[t * 3 + 0] = b;
                    out32[t * 3 + 1] = c;
                    out32[t * 3 + 2] = n;
                }
            }
            if (lane == t) {
                selx = cand.x; sely = cand.y; selz = cand.z; selw = cand.w;
                sela = areaC;
            }
            ++t;
        }
        ++r;
        cand = nxt;
    }
    if (t < maxo && rem > 0) need_slow = 1;
    if (lane == 0) flags[bc] = need_slow;
}

// ---- standalone gated slow kernel (for fallback launch configs) ----
template <bool OUT64>
__global__ __launch_bounds__(NTHREADS) void nms_slow(
    const float* __restrict__ boxes,
    const float* __restrict__ scores,
    const int* __restrict__ p_maxout,
    const float* __restrict__ p_iou,
    const float* __restrict__ p_sthr,
    void* __restrict__ out_raw,
    const int* __restrict__ flags)
{
    const int bc = blockIdx.x;
    if (flags && flags[bc] == 0) return;     // uniform exit before any barrier
    slow_body<OUT64>(boxes, scores, p_maxout, p_iou, p_sthr, out_raw, bc);
}

extern "C" void kernel_launch(void* const* d_in, const int* in_sizes, int n_in,
                              void* d_out, int out_size, void* d_ws, size_t ws_size,
                              hipStream_t stream) {
    const float* boxes  = (const float*)d_in[0];
    const float* scores = (const float*)d_in[1];
    const int*   p_maxo = (const int*)d_in[2];
    const float* p_iou  = (const float*)d_in[3];
    const float* p_sthr = (const float*)d_in[4];

    const dim3 block(NTHREADS);
    const bool out64 = (out_size == NLANES * NMS_MAX_OUT * 3 * 2);

    char* ws = (char*)d_ws;
    int*  flags  = (int*)(ws + WS_FLAGS);
    int*  cnts   = (int*)(ws + WS_CNTS);
    int*  totals = (int*)(ws + WS_TOTALS);
    u64*  keys   = (u64*)(ws + WS_KEYS);

    if (ws_size >= WS_NEED) {
        hipLaunchKernelGGL(nms_scan, dim3(NLANES * SPLIT), block, 0, stream,
                           scores, p_sthr, cnts, totals, keys);
        if (out64) {
            hipLaunchKernelGGL(nms_fused<true>, dim3(NLANES), block, 0, stream,
                               boxes, scores, p_maxo, p_iou, p_sthr, d_out,
                               cnts, totals, keys);
        } else {
            hipLaunchKernelGGL(nms_fused<false>, dim3(NLANES), block, 0, stream,
                               boxes, scores, p_maxo, p_iou, p_sthr, d_out,
                               cnts, totals, keys);
        }
    } else if (ws_size >= (size_t)NLANES * sizeof(int)) {
        if (out64) {
            hipLaunchKernelGGL(nms_fast_mono<true>, dim3(NLANES), block, 0, stream,
                               boxes, scores, p_maxo, p_iou, p_sthr, d_out, flags);
            hipLaunchKernelGGL(nms_slow<true>, dim3(NLANES), block, 0, stream,
                               boxes, scores, p_maxo, p_iou, p_sthr, d_out, flags);
        } else {
            hipLaunchKernelGGL(nms_fast_mono<false>, dim3(NLANES), block, 0, stream,
                               boxes, scores, p_maxo, p_iou, p_sthr, d_out, flags);
            hipLaunchKernelGGL(nms_slow<false>, dim3(NLANES), block, 0, stream,
                               boxes, scores, p_maxo, p_iou, p_sthr, d_out, flags);
        }
    } else {
        if (out64) {
            hipLaunchKernelGGL(nms_slow<true>, dim3(NLANES), block, 0, stream,
                               boxes, scores, p_maxo, p_iou, p_sthr, d_out, (const int*)nullptr);
        } else {
            hipLaunchKernelGGL(nms_slow<false>, dim3(NLANES), block, 0, stream,
                               boxes, scores, p_maxo, p_iou, p_sthr, d_out, (const int*)nullptr);
        }
    }
}